// Round 8
// baseline (1996.421 us; speedup 1.0000x reference)
//
#include <hip/hip_runtime.h>
#include <math.h>

#define BN_EPS 1e-5f

__device__ __forceinline__ float mishf(float x){
  float sp = fmaxf(x, 0.f) + log1pf(__expf(-fabsf(x)));
  float e  = __expf(-2.f * sp);
  return x * ((1.f - e) / (1.f + e));
}

__device__ __forceinline__ unsigned fenc(float f){
  unsigned u = __float_as_uint(f);
  return (u & 0x80000000u) ? ~u : (u | 0x80000000u);
}
__device__ __forceinline__ float fdec(unsigned e){
  unsigned u = (e & 0x80000000u) ? (e & 0x7fffffffu) : ~e;
  return __uint_as_float(u);
}

// stable top-10 insert: (value desc, index asc) == lax.top_k tie-break
__device__ __forceinline__ bool beats(float v, int i, float v2, int i2){
  return (v > v2) || (v == v2 && i < i2);
}
__device__ __forceinline__ void ins10(float (&lv)[10], int (&li)[10], float v, int i){
  if (!beats(v, i, lv[9], li[9])) return;
  #pragma unroll
  for (int p = 9; p >= 1; --p) {
    bool up   = beats(v, i, lv[p-1], li[p-1]);
    bool bp   = beats(v, i, lv[p],   li[p]);
    bool here = bp && !up;
    float nv = up ? lv[p-1] : (here ? v : lv[p]);
    int   ni = up ? li[p-1] : (here ? i : li[p]);
    lv[p] = nv; li[p] = ni;
  }
  if (beats(v, i, lv[0], li[0])) { lv[0] = v; li[0] = i; }
}

__global__ void k_diag(float* __restrict__ out, float v){ out[0] = v; }

// ---------- transpose x [B,3,N] -> xf [B*N,3] ----------
__global__ __launch_bounds__(256)
void k_cast(const float* __restrict__ x, float* __restrict__ xf){
  int i = blockIdx.x * 256 + threadIdx.x;      // 49152
  int n = i & 2047, c = (i >> 11) % 3, b = i / (3 * 2048);
  xf[(size_t)(b * 2048 + n) * 3 + c] = x[i];
}

__global__ __launch_bounds__(256)
void k_zero(unsigned* __restrict__ p){
  p[blockIdx.x * 256 + threadIdx.x] = 0u;      // 32 blocks -> 8192
}

// ---------- squared norm per point ----------
template<int C>
__global__ __launch_bounds__(256)
void k_norm(const float* __restrict__ src, int stride, int off,
            float* __restrict__ sq){
  int i = blockIdx.x * 256 + threadIdx.x;      // 16384
  const float* r = src + (size_t)i * stride + off;
  float s = 0.f;
  #pragma unroll
  for (int c = 0; c < C; ++c) s = fmaf(r[c], r[c], s);
  sq[i] = s;
}

// ---------- knn C=3: 32 points/block, 8 chunk-threads/point (kept from R7) ----------
__global__ __launch_bounds__(256)
void k_knn3(const float* __restrict__ src, int* __restrict__ idxout){
  constexpr int C = 3, PAD = 4;
  __shared__ float pts[128 * PAD];
  __shared__ float ss[128];
  __shared__ float mlv[32 * 8 * 10];
  __shared__ int   mli[32 * 8 * 10];
  const int t  = threadIdx.x;
  const int b  = blockIdx.x >> 6;
  const int p0 = (blockIdx.x & 63) * 32;
  const int p  = t >> 3, ch = t & 7;
  const float* srow = src + (size_t)(b * 2048 + p0 + p) * C;
  float own[C];
  #pragma unroll
  for (int c = 0; c < C; ++c) own[c] = srow[c];
  float sown = 0.f;
  #pragma unroll
  for (int c = 0; c < C; ++c) sown = fmaf(own[c], own[c], sown);
  float lv[10]; int li[10];
  #pragma unroll
  for (int j = 0; j < 10; ++j){ lv[j] = -INFINITY; li[j] = 0x7fffffff; }

  for (int m0 = 0; m0 < 2048; m0 += 128) {
    __syncthreads();
    for (int i = t; i < 128 * C; i += 256) {
      int mm = i / C, c = i % C;
      pts[mm * PAD + c] = src[(size_t)(b * 2048 + m0 + mm) * C + c];
    }
    __syncthreads();
    if (t < 128) {
      float s2 = 0.f;
      #pragma unroll
      for (int c = 0; c < C; ++c) s2 = fmaf(pts[t * PAD + c], pts[t * PAD + c], s2);
      ss[t] = s2;
    }
    __syncthreads();
    for (int mm = ch; mm < 128; mm += 8) {
      float dot = 0.f;
      #pragma unroll
      for (int c = 0; c < C; ++c) dot = fmaf(own[c], pts[mm * PAD + c], dot);
      ins10(lv, li, 2.f * dot - sown - ss[mm], m0 + mm);
    }
  }
  __syncthreads();
  #pragma unroll
  for (int j = 0; j < 10; ++j) { mlv[t * 10 + j] = lv[j]; mli[t * 10 + j] = li[j]; }
  __syncthreads();
  if (t < 32) {
    float fv[10]; int fi[10];
    #pragma unroll
    for (int j = 0; j < 10; ++j){ fv[j] = -INFINITY; fi[j] = 0x7fffffff; }
    for (int c2 = 0; c2 < 8; ++c2)
      for (int j = 0; j < 10; ++j)
        ins10(fv, fi, mlv[(t * 8 + c2) * 10 + j], mli[(t * 8 + c2) * 10 + j]);
    #pragma unroll
    for (int j = 0; j < 10; ++j)
      idxout[(size_t)(b * 2048 + p0 + t) * 10 + j] = fi[j];
  }
}

// ---------- knn C=64: GEMM-tiled distance matrix + fused top-10 ----------
// block = 64 rows x all 2048 candidates; 256 blocks (8 batches x 32).
__global__ __launch_bounds__(256)
void k_knn2(const float* __restrict__ src, int stride, int off,
            const float* __restrict__ sq, int* __restrict__ idxout){
  __shared__ float As[64][68];     // [ch][row]
  __shared__ float Bs[64][68];     // [ch][col]
  __shared__ float Sc[64][65];     // [row][col] scores (stride 65: scan conflict-free)
  __shared__ float ssB[64];
  __shared__ float mgv[64 * 4 * 10];
  __shared__ int   mgi[64 * 4 * 10];
  const int t  = threadIdx.x;
  const int b  = blockIdx.x >> 5;
  const int p0 = (blockIdx.x & 31) * 64;
  const int tx = t & 15, ty = t >> 4;
  const int row = t & 63, chk = t >> 6;        // scan mapping: 4 chunks/row

  for (int i = t; i < 4096; i += 256) {        // A-tile once per block
    int r_ = i >> 6, c = i & 63;
    As[c][r_] = src[(size_t)(b * 2048 + p0 + r_) * stride + off + c];
  }
  float sqA = sq[b * 2048 + p0 + row];
  float lv[10]; int li[10];
  #pragma unroll
  for (int j = 0; j < 10; ++j){ lv[j] = -INFINITY; li[j] = 0x7fffffff; }

  for (int m0 = 0; m0 < 2048; m0 += 64) {
    for (int i = t; i < 4096; i += 256) {
      int j_ = i >> 6, c = i & 63;
      Bs[c][j_] = src[(size_t)(b * 2048 + m0 + j_) * stride + off + c];
    }
    if (t < 64) ssB[t] = sq[b * 2048 + m0 + t];
    __syncthreads();

    float acc[4][4] = {};
    #pragma unroll 8
    for (int c = 0; c < 64; ++c) {
      float av[4], bv[4];
      #pragma unroll
      for (int q = 0; q < 4; ++q) { av[q] = As[c][tx * 4 + q]; bv[q] = Bs[c][ty * 4 + q]; }
      #pragma unroll
      for (int q = 0; q < 4; ++q)
        #pragma unroll
        for (int r = 0; r < 4; ++r)
          acc[q][r] = fmaf(av[q], bv[r], acc[q][r]);
    }
    #pragma unroll
    for (int q = 0; q < 4; ++q)
      #pragma unroll
      for (int r = 0; r < 4; ++r)
        Sc[tx * 4 + q][ty * 4 + r] = acc[q][r];
    __syncthreads();

    #pragma unroll
    for (int m2 = 0; m2 < 16; ++m2) {
      int mm = chk * 16 + m2;
      float key = 2.f * Sc[row][mm] - sqA - ssB[mm];
      ins10(lv, li, key, m0 + mm);
    }
    __syncthreads();
  }

  #pragma unroll
  for (int j = 0; j < 10; ++j) {
    mgv[(row * 4 + chk) * 10 + j] = lv[j];
    mgi[(row * 4 + chk) * 10 + j] = li[j];
  }
  __syncthreads();
  if (t < 64) {
    float fv[10]; int fi[10];
    #pragma unroll
    for (int j = 0; j < 10; ++j){ fv[j] = -INFINITY; fi[j] = 0x7fffffff; }
    for (int c2 = 0; c2 < 4; ++c2)
      for (int j = 0; j < 10; ++j)
        ins10(fv, fi, mgv[(t * 4 + c2) * 10 + j], mgi[(t * 4 + c2) * 10 + j]);
    #pragma unroll
    for (int j = 0; j < 10; ++j)
      idxout[(size_t)(b * 2048 + p0 + t) * 10 + j] = fi[j];
  }
}

// ---------- UV for stage 1 (C=3): elementwise ----------
__global__ __launch_bounds__(256)
void k_uv3(const float* __restrict__ xf, const float* __restrict__ w1,
           const float* __restrict__ gg, const float* __restrict__ vv,
           float* __restrict__ UV){
  int i = blockIdx.x * 256 + threadIdx.x;      // 16384*64 -> 4096 blocks
  int p = i >> 6, o = i & 63;
  float s = gg[o] / sqrtf(vv[o] + BN_EPS);
  float x0 = xf[(size_t)p * 3], x1 = xf[(size_t)p * 3 + 1], x2 = xf[(size_t)p * 3 + 2];
  const float* wr = w1 + o * 6;
  float u = s * (wr[0] * x0 + wr[1] * x1 + wr[2] * x2);
  float v = s * ((wr[3] - wr[0]) * x0 + (wr[4] - wr[1]) * x1 + (wr[5] - wr[2]) * x2);
  UV[(size_t)p * 128 + o] = u;
  UV[(size_t)p * 128 + 64 + o] = v;
}

// ---------- UV for stages 2/3 (C=64): tiled GEMM, s1 folded ----------
// grid (256, 2): y=0 -> U (Wd), y=1 -> V (Wc-Wd)
__global__ __launch_bounds__(256)
void k_uv(const float* __restrict__ A, int lda, int aoff,
          const float* __restrict__ w,       // [64][128]
          const float* __restrict__ gg, const float* __restrict__ vv,
          float* __restrict__ UV){
  __shared__ float As[16][68];
  __shared__ float Bs[16][68];
  __shared__ float ss[64];
  const int t = threadIdx.x;
  const int tx = t & 15, ty = t >> 4;
  const int m0 = blockIdx.x * 64;
  const int half = blockIdx.y;
  if (t < 64) ss[t] = gg[t] / sqrtf(vv[t] + BN_EPS);
  __syncthreads();
  float acc[4][4] = {};
  for (int k0 = 0; k0 < 64; k0 += 16) {
    for (int i = t; i < 1024; i += 256) {
      int m = i >> 4, k = i & 15;
      As[k][m] = A[(size_t)(m0 + m) * lda + aoff + k0 + k];
    }
    for (int i = t; i < 1024; i += 256) {
      int n = i >> 4, k = i & 15;
      int kk = k0 + k;
      float wv = half ? (w[n * 128 + 64 + kk] - w[n * 128 + kk]) : w[n * 128 + kk];
      Bs[k][n] = wv * ss[n];
    }
    __syncthreads();
    #pragma unroll
    for (int k = 0; k < 16; ++k) {
      float am[4], bm[4];
      #pragma unroll
      for (int q = 0; q < 4; ++q) { am[q] = As[k][tx * 4 + q]; bm[q] = Bs[k][ty * 4 + q]; }
      #pragma unroll
      for (int q = 0; q < 4; ++q)
        #pragma unroll
        for (int r = 0; r < 4; ++r)
          acc[q][r] = fmaf(am[q], bm[r], acc[q][r]);
    }
    __syncthreads();
  }
  #pragma unroll
  for (int q = 0; q < 4; ++q)
    #pragma unroll
    for (int r = 0; r < 4; ++r)
      UV[(size_t)(m0 + tx * 4 + q) * 128 + half * 64 + ty * 4 + r] = acc[q][r];
}

// ---------- edge stage with conv2: h1 = mish(U[j]+V[p]+o1) -> conv2 GEMM -> max_k ----------
// block = 16 points = 160 edges; grid 1024.
__global__ __launch_bounds__(256)
void k_edge2(const float* __restrict__ UV, const int* __restrict__ idx,
             const float* __restrict__ w2,   // [64][64]
             const float* __restrict__ g1, const float* __restrict__ b1,
             const float* __restrict__ m1, const float* __restrict__ v1,
             const float* __restrict__ g2, const float* __restrict__ b2,
             const float* __restrict__ m2, const float* __restrict__ v2,
             float* __restrict__ cat, int coff){
  __shared__ float Ha[64][161];   // [ch][edge] then reused as [out][edge]
  __shared__ float Ws[64][68];    // [k][out]
  __shared__ float o1s[64], s2s[64], o2s[64];
  __shared__ int   ejs[160];
  const int t = threadIdx.x;
  const int p0 = blockIdx.x * 16;
  const int batch = p0 >> 11;
  if (t < 160) ejs[t] = batch * 2048 + (idx[p0 * 10 + t] & 2047);
  if (t < 64) {
    float s1 = g1[t] / sqrtf(v1[t] + BN_EPS);
    o1s[t] = b1[t] - m1[t] * s1;
    float s2 = g2[t] / sqrtf(v2[t] + BN_EPS);
    s2s[t] = s2;
    o2s[t] = b2[t] - m2[t] * s2;
  }
  for (int i = t; i < 4096; i += 256) {
    int k = i & 63, n = i >> 6;
    Ws[k][n] = w2[n * 64 + k];
  }
  __syncthreads();

  // build h1 into Ha[ch][edge]
  for (int i = t; i < 10240; i += 256) {
    int e = i >> 6, c = i & 63;
    int p = p0 + e / 10;
    float hv = UV[(size_t)ejs[e] * 128 + c] + UV[(size_t)p * 128 + 64 + c] + o1s[c];
    Ha[c][e] = mishf(hv);
  }
  __syncthreads();

  // conv2 GEMM: 160 edges x 64 outs, K=64
  const int tx = t & 31, tq = t >> 5;          // 5 edges, 8 outs per thread
  float acc[5][8] = {};
  #pragma unroll 8
  for (int k = 0; k < 64; ++k) {
    float av[5], bv[8];
    #pragma unroll
    for (int i2 = 0; i2 < 5; ++i2) av[i2] = Ha[k][tx * 5 + i2];
    #pragma unroll
    for (int r = 0; r < 8; ++r) bv[r] = Ws[k][tq * 8 + r];
    #pragma unroll
    for (int i2 = 0; i2 < 5; ++i2)
      #pragma unroll
      for (int r = 0; r < 8; ++r)
        acc[i2][r] = fmaf(av[i2], bv[r], acc[i2][r]);
  }
  __syncthreads();                              // all reads of Ha done
  #pragma unroll
  for (int i2 = 0; i2 < 5; ++i2)
    #pragma unroll
    for (int r = 0; r < 8; ++r) {
      int o = tq * 8 + r;
      Ha[o][tx * 5 + i2] = mishf(acc[i2][r] * s2s[o] + o2s[o]);
    }
  __syncthreads();

  // max over k=10 -> cat
  for (int i = t; i < 1024; i += 256) {
    int p = i >> 6, o = i & 63;
    float mx = Ha[o][p * 10];
    #pragma unroll
    for (int k = 1; k < 10; ++k) mx = fmaxf(mx, Ha[o][p * 10 + k]);
    cat[(size_t)(p0 + p) * 192 + coff + o] = mx;
  }
}

// ---------- edge stage 3 (no conv2): out = max_k mish(U[j]+V[p]+o5) ----------
__global__ __launch_bounds__(256)
void k_edge3(const float* __restrict__ UV, const int* __restrict__ idx,
             const float* __restrict__ gg, const float* __restrict__ bb,
             const float* __restrict__ mn, const float* __restrict__ vv,
             float* __restrict__ cat){
  int i = blockIdx.x * 256 + threadIdx.x;      // 16384*64 -> 4096 blocks
  int p = i >> 6, o = i & 63;
  int batch = p >> 11;
  float s = gg[o] / sqrtf(vv[o] + BN_EPS);
  float of = bb[o] - mn[o] * s;
  float v_ = UV[(size_t)p * 128 + 64 + o] + of;
  float mx = -INFINITY;
  #pragma unroll
  for (int k = 0; k < 10; ++k) {
    int j = batch * 2048 + (idx[p * 10 + k] & 2047);
    mx = fmaxf(mx, mishf(UV[(size_t)j * 128 + o] + v_));
  }
  cat[(size_t)p * 192 + 128 + o] = mx;
}

// ---------- tiled fp32 GEMM head: C[M,*] = A[M,K] * W[N,K]^T ----------
#define EP_BNMISH      0
#define EP_MAXGLOB     1
#define EP_BIAS_BNMISH 2

template<int EPI>
__global__ __launch_bounds__(256)
void k_gemm(const float* __restrict__ A, int lda,
            const float* __restrict__ W, int ldw, int K,
            const float* __restrict__ gg, const float* __restrict__ bb,
            const float* __restrict__ mn, const float* __restrict__ vv,
            const float* __restrict__ bias,
            float* __restrict__ out, int ldo,
            unsigned* __restrict__ glob)
{
  __shared__ float As[16][68];
  __shared__ float Bs[16][68];
  const int t  = threadIdx.x;
  const int tx = t & 15, ty = t >> 4;
  const int m0 = blockIdx.x * 64, n0 = blockIdx.y * 64;
  float acc[4][4] = {};

  for (int k0 = 0; k0 < K; k0 += 16) {
    for (int i = t; i < 1024; i += 256) {
      int m = i >> 4, k = i & 15;
      As[k][m] = A[(size_t)(m0 + m) * lda + k0 + k];
    }
    for (int i = t; i < 1024; i += 256) {
      int nn = i >> 4, k = i & 15;
      Bs[k][nn] = W[(size_t)(n0 + nn) * ldw + k0 + k];
    }
    __syncthreads();
    #pragma unroll
    for (int k = 0; k < 16; ++k) {
      float am[4], bm[4];
      #pragma unroll
      for (int q = 0; q < 4; ++q) { am[q] = As[k][tx * 4 + q]; bm[q] = Bs[k][ty * 4 + q]; }
      #pragma unroll
      for (int i2 = 0; i2 < 4; ++i2)
        #pragma unroll
        for (int j = 0; j < 4; ++j)
          acc[i2][j] = fmaf(am[i2], bm[j], acc[i2][j]);
    }
    __syncthreads();
  }

  float sc[4], of[4];
  #pragma unroll
  for (int j = 0; j < 4; ++j) {
    int nn = n0 + ty * 4 + j;
    float s = gg[nn] / sqrtf(vv[nn] + BN_EPS);
    sc[j] = s;
    of[j] = bb[nn] - mn[nn] * s;
  }

  if (EPI == EP_MAXGLOB) {
    float mx[4] = {-INFINITY, -INFINITY, -INFINITY, -INFINITY};
    #pragma unroll
    for (int i2 = 0; i2 < 4; ++i2)
      #pragma unroll
      for (int j = 0; j < 4; ++j)
        mx[j] = fmaxf(mx[j], mishf(acc[i2][j] * sc[j] + of[j]));
    __syncthreads();
    float* red = &As[0][0];
    #pragma unroll
    for (int j = 0; j < 4; ++j) red[(ty * 4 + j) * 16 + tx] = mx[j];
    __syncthreads();
    if (t < 64) {
      float v = red[t * 16];
      #pragma unroll
      for (int r = 1; r < 16; ++r) v = fmaxf(v, red[t * 16 + r]);
      atomicMax(&glob[(m0 >> 11) * 1024 + n0 + t], fenc(v));
    }
  } else {
    #pragma unroll
    for (int i2 = 0; i2 < 4; ++i2) {
      int m = m0 + tx * 4 + i2;
      #pragma unroll
      for (int j = 0; j < 4; ++j) {
        int nn = n0 + ty * 4 + j;
        float v = acc[i2][j];
        if (EPI == EP_BIAS_BNMISH) v += bias[(m >> 11) * 512 + nn];
        out[(size_t)m * ldo + nn] = mishf(v * sc[j] + of[j]);
      }
    }
  }
}

// ---------- t7[b][o] = w7[o, :1024] . glob[b] ----------
__global__ __launch_bounds__(256)
void k_t7(const unsigned* __restrict__ glob, const float* __restrict__ w7,
          float* __restrict__ t7){
  int i = blockIdx.x * 256 + threadIdx.x;      // 4096
  int b = i >> 9, o = i & 511;
  float acc = 0.f;
  for (int c = 0; c < 1024; ++c)
    acc = fmaf(w7[(size_t)o * 1216 + c], fdec(glob[b * 1024 + c]), acc);
  t7[i] = acc;
}

// ---------- final conv ----------
__global__ __launch_bounds__(256)
void k_out(const float* __restrict__ h8, const float* __restrict__ w9,
           float* __restrict__ out)
{
  __shared__ float row[4][256];
  const int t = threadIdx.x;
  const int g = t >> 6, l = t & 63;
  const int p = blockIdx.x * 4 + g;            // 4096 blocks
  for (int c = l; c < 256; c += 64)
    row[g][c] = h8[(size_t)p * 256 + c];
  __syncthreads();
  if (l < 18) {
    float acc = 0.f;
    for (int c = 0; c < 256; ++c)
      acc = fmaf(row[g][c], w9[l * 256 + c], acc);
    int b = p >> 11, n = p & 2047;
    out[(size_t)b * 36864 + l * 2048 + n] = acc;
  }
}

extern "C" void kernel_launch(void* const* d_in, const int* in_sizes, int n_in,
                              void* d_out, int out_size, void* d_ws, size_t ws_size,
                              hipStream_t stream)
{
  // ---- workspace layout (63,881,216 B proven available) ----
  const size_t OFF_XF   = 0;                   //    196,608  [16384][3]
  const size_t OFF_IDX  = 262144;              //    655,360  [16384][10]
  const size_t OFF_CAT  = 917504;              // 12,582,912  [16384][192]
  const size_t OFF_GLOB = 13500416;            //     32,768  [8][1024]
  const size_t OFF_T7   = 13533184;            //     16,384  [8][512]
  const size_t OFF_H7   = 13549568;            // 33,554,432  [16384][512]; UV aliases first 8.4MB
  const size_t OFF_H8   = 47104000;            // 16,777,216  [16384][256]; sq aliases first 64KB
  const size_t NEED     = 63881216;

  static const int EXP[26] = {
    49152, 384, 4096, 8192, 4096, 8192, 196608, 622592, 131072, 4608,
    320, 320, 320, 320, 1024, 1024, 1024, 1024,
    512, 512, 512, 512, 256, 256, 256, 256 };
  if (n_in < 26) { k_diag<<<1,1,0,stream>>>((float*)d_out, 16384.f); return; }
  for (int i = 0; i < 26; ++i)
    if (in_sizes[i] != EXP[i]) {
      k_diag<<<1,1,0,stream>>>((float*)d_out, 4096.f + 128.f * i); return;
    }
  if (out_size != 294912) { k_diag<<<1,1,0,stream>>>((float*)d_out, 20480.f); return; }
  if (ws_size < NEED) {
    k_diag<<<1,1,0,stream>>>((float*)d_out, 24576.f + (float)(ws_size >> 20)); return;
  }

  const float* x  = (const float*)d_in[0];
  const float* w1 = (const float*)d_in[1];
  const float* w2 = (const float*)d_in[2];
  const float* w3 = (const float*)d_in[3];
  const float* w4 = (const float*)d_in[4];
  const float* w5 = (const float*)d_in[5];
  const float* w6 = (const float*)d_in[6];
  const float* w7 = (const float*)d_in[7];
  const float* w8 = (const float*)d_in[8];
  const float* w9 = (const float*)d_in[9];
  const float* g15 = (const float*)d_in[10];
  const float* b15 = (const float*)d_in[11];
  const float* m15 = (const float*)d_in[12];
  const float* v15 = (const float*)d_in[13];
  const float* g6 = (const float*)d_in[14];
  const float* b6 = (const float*)d_in[15];
  const float* m6 = (const float*)d_in[16];
  const float* v6 = (const float*)d_in[17];
  const float* g7 = (const float*)d_in[18];
  const float* b7 = (const float*)d_in[19];
  const float* m7 = (const float*)d_in[20];
  const float* v7 = (const float*)d_in[21];
  const float* g8 = (const float*)d_in[22];
  const float* b8 = (const float*)d_in[23];
  const float* m8 = (const float*)d_in[24];
  const float* v8 = (const float*)d_in[25];

  char* ws = (char*)d_ws;
  float*    xf   = (float*)(ws + OFF_XF);
  int*      idx  = (int*)(ws + OFF_IDX);
  float*    cat  = (float*)(ws + OFF_CAT);
  unsigned* glob = (unsigned*)(ws + OFF_GLOB);
  float*    t7   = (float*)(ws + OFF_T7);
  float*    h7   = (float*)(ws + OFF_H7);
  float*    UV   = (float*)(ws + OFF_H7);      // [16384][128], dead before h7 lives
  float*    h8   = (float*)(ws + OFF_H8);
  float*    sq   = (float*)(ws + OFF_H8);      // [16384], dead before h8 lives

  k_cast<<<192, 256, 0, stream>>>(x, xf);

  // ---- stage 1 ----
  k_knn3<<<512, 256, 0, stream>>>(xf, idx);
  k_uv3<<<4096, 256, 0, stream>>>(xf, w1, g15 + 0, v15 + 0, UV);
  k_edge2<<<1024, 256, 0, stream>>>(UV, idx, w2,
      g15 + 0,  b15 + 0,  m15 + 0,  v15 + 0,
      g15 + 64, b15 + 64, m15 + 64, v15 + 64, cat, 0);

  // ---- stage 2 ----
  k_norm<64><<<64, 256, 0, stream>>>(cat, 192, 0, sq);
  k_knn2<<<256, 256, 0, stream>>>(cat, 192, 0, sq, idx);
  dim3 guv(256, 2);
  k_uv<<<guv, 256, 0, stream>>>(cat, 192, 0, w3, g15 + 128, v15 + 128, UV);
  k_edge2<<<1024, 256, 0, stream>>>(UV, idx, w4,
      g15 + 128, b15 + 128, m15 + 128, v15 + 128,
      g15 + 192, b15 + 192, m15 + 192, v15 + 192, cat, 64);

  // ---- stage 3 ----
  k_norm<64><<<64, 256, 0, stream>>>(cat, 192, 64, sq);
  k_knn2<<<256, 256, 0, stream>>>(cat, 192, 64, sq, idx);
  k_uv<<<guv, 256, 0, stream>>>(cat, 192, 64, w5, g15 + 256, v15 + 256, UV);
  k_edge3<<<4096, 256, 0, stream>>>(UV, idx,
      g15 + 256, b15 + 256, m15 + 256, v15 + 256, cat);

  // ---- head ----
  k_zero<<<32, 256, 0, stream>>>(glob);
  dim3 g6g(256, 16);
  k_gemm<EP_MAXGLOB><<<g6g, 256, 0, stream>>>(
      cat, 192, w6, 192, 192, g6, b6, m6, v6, nullptr, nullptr, 0, glob);
  k_t7<<<16, 256, 0, stream>>>(glob, w7, t7);
  dim3 g7g(256, 8);
  k_gemm<EP_BIAS_BNMISH><<<g7g, 256, 0, stream>>>(
      cat, 192, w7 + 1024, 1216, 192, g7, b7, m7, v7, t7, h7, 512, nullptr);
  dim3 g8g(256, 4);
  k_gemm<EP_BNMISH><<<g8g, 256, 0, stream>>>(
      h7, 512, w8, 512, 512, g8, b8, m8, v8, nullptr, h8, 256, nullptr);
  k_out<<<4096, 256, 0, stream>>>(h8, w9, (float*)d_out);
}

// Round 9
// 1842.761 us; speedup vs baseline: 1.0834x; 1.0834x over previous
//
#include <hip/hip_runtime.h>
#include <math.h>

#define BN_EPS 1e-5f

__device__ __forceinline__ float mishf(float x){
  float sp = fmaxf(x, 0.f) + log1pf(__expf(-fabsf(x)));
  float e  = __expf(-2.f * sp);
  return x * ((1.f - e) / (1.f + e));
}

__device__ __forceinline__ unsigned fenc(float f){
  unsigned u = __float_as_uint(f);
  return (u & 0x80000000u) ? ~u : (u | 0x80000000u);
}
__device__ __forceinline__ float fdec(unsigned e){
  unsigned u = (e & 0x80000000u) ? (e & 0x7fffffffu) : ~e;
  return __uint_as_float(u);
}

// stable top-10 insert: (value desc, index asc) == lax.top_k tie-break
__device__ __forceinline__ bool beats(float v, int i, float v2, int i2){
  return (v > v2) || (v == v2 && i < i2);
}
__device__ __forceinline__ void ins10(float (&lv)[10], int (&li)[10], float v, int i){
  if (!beats(v, i, lv[9], li[9])) return;
  #pragma unroll
  for (int p = 9; p >= 1; --p) {
    bool up   = beats(v, i, lv[p-1], li[p-1]);
    bool bp   = beats(v, i, lv[p],   li[p]);
    bool here = bp && !up;
    float nv = up ? lv[p-1] : (here ? v : lv[p]);
    int   ni = up ? li[p-1] : (here ? i : li[p]);
    lv[p] = nv; li[p] = ni;
  }
  if (beats(v, i, lv[0], li[0])) { lv[0] = v; li[0] = i; }
}

__global__ void k_diag(float* __restrict__ out, float v){ out[0] = v; }

// ---------- transpose x [B,3,N] -> xf [B*N,3] ----------
__global__ __launch_bounds__(256)
void k_cast(const float* __restrict__ x, float* __restrict__ xf){
  int i = blockIdx.x * 256 + threadIdx.x;      // 49152
  int n = i & 2047, c = (i >> 11) % 3, b = i / (3 * 2048);
  xf[(size_t)(b * 2048 + n) * 3 + c] = x[i];
}

__global__ __launch_bounds__(256)
void k_zero(unsigned* __restrict__ p){
  p[blockIdx.x * 256 + threadIdx.x] = 0u;      // 32 blocks -> 8192
}

// ---------- squared norm per point ----------
template<int C>
__global__ __launch_bounds__(256)
void k_norm(const float* __restrict__ src, int stride, int off,
            float* __restrict__ sq){
  int i = blockIdx.x * 256 + threadIdx.x;      // 16384
  const float* r = src + (size_t)i * stride + off;
  float s = 0.f;
  #pragma unroll
  for (int c = 0; c < C; ++c) s = fmaf(r[c], r[c], s);
  sq[i] = s;
}

// ---------- knn C=3: 32 points/block, 8 chunk-threads/point ----------
__global__ __launch_bounds__(256)
void k_knn3(const float* __restrict__ src, int* __restrict__ idxout){
  constexpr int C = 3, PAD = 4;
  __shared__ float pts[128 * PAD];
  __shared__ float ss[128];
  __shared__ float mlv[32 * 8 * 10];
  __shared__ int   mli[32 * 8 * 10];
  const int t  = threadIdx.x;
  const int b  = blockIdx.x >> 6;
  const int p0 = (blockIdx.x & 63) * 32;
  const int p  = t >> 3, ch = t & 7;
  const float* srow = src + (size_t)(b * 2048 + p0 + p) * C;
  float own[C];
  #pragma unroll
  for (int c = 0; c < C; ++c) own[c] = srow[c];
  float sown = 0.f;
  #pragma unroll
  for (int c = 0; c < C; ++c) sown = fmaf(own[c], own[c], sown);
  float lv[10]; int li[10];
  #pragma unroll
  for (int j = 0; j < 10; ++j){ lv[j] = -INFINITY; li[j] = 0x7fffffff; }

  for (int m0 = 0; m0 < 2048; m0 += 128) {
    __syncthreads();
    for (int i = t; i < 128 * C; i += 256) {
      int mm = i / C, c = i % C;
      pts[mm * PAD + c] = src[(size_t)(b * 2048 + m0 + mm) * C + c];
    }
    __syncthreads();
    if (t < 128) {
      float s2 = 0.f;
      #pragma unroll
      for (int c = 0; c < C; ++c) s2 = fmaf(pts[t * PAD + c], pts[t * PAD + c], s2);
      ss[t] = s2;
    }
    __syncthreads();
    for (int mm = ch; mm < 128; mm += 8) {
      float dot = 0.f;
      #pragma unroll
      for (int c = 0; c < C; ++c) dot = fmaf(own[c], pts[mm * PAD + c], dot);
      ins10(lv, li, 2.f * dot - sown - ss[mm], m0 + mm);
    }
  }
  __syncthreads();
  #pragma unroll
  for (int j = 0; j < 10; ++j) { mlv[t * 10 + j] = lv[j]; mli[t * 10 + j] = li[j]; }
  __syncthreads();
  if (t < 32) {
    float fv[10]; int fi[10];
    #pragma unroll
    for (int j = 0; j < 10; ++j){ fv[j] = -INFINITY; fi[j] = 0x7fffffff; }
    for (int c2 = 0; c2 < 8; ++c2)
      for (int j = 0; j < 10; ++j)
        ins10(fv, fi, mlv[(t * 8 + c2) * 10 + j], mli[(t * 8 + c2) * 10 + j]);
    #pragma unroll
    for (int j = 0; j < 10; ++j)
      idxout[(size_t)(b * 2048 + p0 + t) * 10 + j] = fi[j];
  }
}

// ---------- knn C=64 v2: GEMM-tiled distances + fused top-10 ----------
// 64 rows/block, 256 blocks. LDS 51.7KB -> 3 blocks/CU. Sc swizzled (2-way banks).
__global__ __launch_bounds__(256)
void k_knn2(const float* __restrict__ src, int stride, int off,
            const float* __restrict__ sq, int* __restrict__ idxout){
  __shared__ float As[64][68];   // [ch][row]; f4-aligned rows (272B)
  __shared__ float Bs[64][68];   // [cand][ch]; natural layout, f4 fill
  __shared__ float Sc[64 * 65];  // [row][col sw.]: col' = (col + (row>>2 & 3)) & 63
  __shared__ float ssB[64];
  const int t  = threadIdx.x;
  const int b  = blockIdx.x >> 5;
  const int p0 = (blockIdx.x & 31) * 64;
  const int tx = t & 15, ty = t >> 4;
  const int row = t & 63, chk = t >> 6;

  // A tile (once): 64 rows x 64 ch, transposed store (one-time conflict cost ok)
  #pragma unroll
  for (int pass = 0; pass < 4; ++pass) {
    int i = pass * 256 + t;
    int r_ = i >> 4, c4 = (i & 15) * 4;
    float4 v = *(const float4*)&src[(size_t)(b * 2048 + p0 + r_) * stride + off + c4];
    As[c4    ][r_] = v.x;
    As[c4 + 1][r_] = v.y;
    As[c4 + 2][r_] = v.z;
    As[c4 + 3][r_] = v.w;
  }
  float sqA = sq[b * 2048 + p0 + row];
  float lv[10]; int li[10];
  #pragma unroll
  for (int j = 0; j < 10; ++j){ lv[j] = -INFINITY; li[j] = 0x7fffffff; }

  for (int m0 = 0; m0 < 2048; m0 += 64) {
    // B tile: natural [cand][ch], float4 straight from global
    #pragma unroll
    for (int pass = 0; pass < 4; ++pass) {
      int i = pass * 256 + t;
      int j_ = i >> 4, c4 = (i & 15) * 4;
      *(float4*)&Bs[j_][c4] =
          *(const float4*)&src[(size_t)(b * 2048 + m0 + j_) * stride + off + c4];
    }
    if (t < 64) ssB[t] = sq[b * 2048 + m0 + t];
    __syncthreads();

    float acc[4][4] = {};
    #pragma unroll
    for (int c = 0; c < 64; ++c) {
      float4 a4 = *(const float4*)&As[c][tx * 4];
      float av[4] = {a4.x, a4.y, a4.z, a4.w};
      float bv[4];
      #pragma unroll
      for (int r = 0; r < 4; ++r) bv[r] = Bs[ty * 4 + r][c];
      #pragma unroll
      for (int q = 0; q < 4; ++q)
        #pragma unroll
        for (int r = 0; r < 4; ++r)
          acc[q][r] = fmaf(av[q], bv[r], acc[q][r]);
    }
    // scores -> Sc with additive bank swizzle
    #pragma unroll
    for (int q = 0; q < 4; ++q) {
      int r_ = tx * 4 + q;
      int f  = tx & 3;                       // (r_>>2)&3
      #pragma unroll
      for (int r2 = 0; r2 < 4; ++r2)
        Sc[r_ * 65 + ((ty * 4 + r2 + f) & 63)] = acc[q][r2];
    }
    __syncthreads();
    {
      int f = (row >> 2) & 3;
      #pragma unroll
      for (int m2 = 0; m2 < 16; ++m2) {
        int mm = chk * 16 + m2;
        float key = 2.f * Sc[row * 65 + ((mm + f) & 63)] - sqA - ssB[mm];
        ins10(lv, li, key, m0 + mm);
      }
    }
    __syncthreads();
  }

  // merge 4 chunk-lists per row; alias dead As/Bs as merge buffers
  float* mgv = &As[0][0];                    // 2560 floats < 4352
  int*   mgi = (int*)&Bs[0][0];
  #pragma unroll
  for (int j = 0; j < 10; ++j) {
    mgv[(row * 4 + chk) * 10 + j] = lv[j];
    mgi[(row * 4 + chk) * 10 + j] = li[j];
  }
  __syncthreads();
  if (t < 64) {
    float fv[10]; int fi[10];
    #pragma unroll
    for (int j = 0; j < 10; ++j){ fv[j] = -INFINITY; fi[j] = 0x7fffffff; }
    for (int c2 = 0; c2 < 4; ++c2)
      for (int j = 0; j < 10; ++j)
        ins10(fv, fi, mgv[(t * 4 + c2) * 10 + j], mgi[(t * 4 + c2) * 10 + j]);
    #pragma unroll
    for (int j = 0; j < 10; ++j)
      idxout[(size_t)(b * 2048 + p0 + t) * 10 + j] = fi[j];
  }
}

// ---------- UV for stage 1 (C=3): elementwise ----------
__global__ __launch_bounds__(256)
void k_uv3(const float* __restrict__ xf, const float* __restrict__ w1,
           const float* __restrict__ gg, const float* __restrict__ vv,
           float* __restrict__ UV){
  int i = blockIdx.x * 256 + threadIdx.x;      // 4096 blocks
  int p = i >> 6, o = i & 63;
  float s = gg[o] / sqrtf(vv[o] + BN_EPS);
  float x0 = xf[(size_t)p * 3], x1 = xf[(size_t)p * 3 + 1], x2 = xf[(size_t)p * 3 + 2];
  const float* wr = w1 + o * 6;
  float u = s * (wr[0] * x0 + wr[1] * x1 + wr[2] * x2);
  float v = s * ((wr[3] - wr[0]) * x0 + (wr[4] - wr[1]) * x1 + (wr[5] - wr[2]) * x2);
  UV[(size_t)p * 128 + o] = u;
  UV[(size_t)p * 128 + 64 + o] = v;
}

// ---------- UV for stages 2/3 (C=64): tiled GEMM, s1 folded ----------
__global__ __launch_bounds__(256)
void k_uv(const float* __restrict__ A, int lda, int aoff,
          const float* __restrict__ w,       // [64][128]
          const float* __restrict__ gg, const float* __restrict__ vv,
          float* __restrict__ UV){
  __shared__ float As[16][68];
  __shared__ float Bs[16][68];
  __shared__ float ss[64];
  const int t = threadIdx.x;
  const int tx = t & 15, ty = t >> 4;
  const int m0 = blockIdx.x * 64;
  const int half = blockIdx.y;
  if (t < 64) ss[t] = gg[t] / sqrtf(vv[t] + BN_EPS);
  __syncthreads();
  float acc[4][4] = {};
  for (int k0 = 0; k0 < 64; k0 += 16) {
    for (int i = t; i < 1024; i += 256) {
      int m = i >> 4, k = i & 15;
      As[k][m] = A[(size_t)(m0 + m) * lda + aoff + k0 + k];
    }
    for (int i = t; i < 1024; i += 256) {
      int n = i >> 4, k = i & 15;
      int kk = k0 + k;
      float wv = half ? (w[n * 128 + 64 + kk] - w[n * 128 + kk]) : w[n * 128 + kk];
      Bs[k][n] = wv * ss[n];
    }
    __syncthreads();
    #pragma unroll
    for (int k = 0; k < 16; ++k) {
      float4 a4 = *(const float4*)&As[k][tx * 4];
      float4 b4 = *(const float4*)&Bs[k][ty * 4];
      float am[4] = {a4.x, a4.y, a4.z, a4.w};
      float bm[4] = {b4.x, b4.y, b4.z, b4.w};
      #pragma unroll
      for (int q = 0; q < 4; ++q)
        #pragma unroll
        for (int r = 0; r < 4; ++r)
          acc[q][r] = fmaf(am[q], bm[r], acc[q][r]);
    }
    __syncthreads();
  }
  #pragma unroll
  for (int q = 0; q < 4; ++q)
    #pragma unroll
    for (int r = 0; r < 4; ++r)
      UV[(size_t)(m0 + tx * 4 + q) * 128 + half * 64 + ty * 4 + r] = acc[q][r];
}

// ---------- edge stage with conv2 ----------
__global__ __launch_bounds__(256)
void k_edge2(const float* __restrict__ UV, const int* __restrict__ idx,
             const float* __restrict__ w2,   // [64][64]
             const float* __restrict__ g1, const float* __restrict__ b1,
             const float* __restrict__ m1, const float* __restrict__ v1,
             const float* __restrict__ g2, const float* __restrict__ b2,
             const float* __restrict__ m2, const float* __restrict__ v2,
             float* __restrict__ cat, int coff){
  __shared__ float Ha[64][161];
  __shared__ float Ws[64][68];
  __shared__ float o1s[64], s2s[64], o2s[64];
  __shared__ int   ejs[160];
  const int t = threadIdx.x;
  const int p0 = blockIdx.x * 16;
  const int batch = p0 >> 11;
  if (t < 160) ejs[t] = batch * 2048 + (idx[p0 * 10 + t] & 2047);
  if (t < 64) {
    float s1 = g1[t] / sqrtf(v1[t] + BN_EPS);
    o1s[t] = b1[t] - m1[t] * s1;
    float s2 = g2[t] / sqrtf(v2[t] + BN_EPS);
    s2s[t] = s2;
    o2s[t] = b2[t] - m2[t] * s2;
  }
  for (int i = t; i < 4096; i += 256) {
    int k = i & 63, n = i >> 6;
    Ws[k][n] = w2[n * 64 + k];
  }
  __syncthreads();

  for (int i = t; i < 10240; i += 256) {
    int e = i >> 6, c = i & 63;
    int p = p0 + e / 10;
    float hv = UV[(size_t)ejs[e] * 128 + c] + UV[(size_t)p * 128 + 64 + c] + o1s[c];
    Ha[c][e] = mishf(hv);
  }
  __syncthreads();

  const int tx = t & 31, tq = t >> 5;
  float acc[5][8] = {};
  #pragma unroll 8
  for (int k = 0; k < 64; ++k) {
    float av[5], bv[8];
    #pragma unroll
    for (int i2 = 0; i2 < 5; ++i2) av[i2] = Ha[k][tx * 5 + i2];
    #pragma unroll
    for (int r = 0; r < 8; ++r) bv[r] = Ws[k][tq * 8 + r];
    #pragma unroll
    for (int i2 = 0; i2 < 5; ++i2)
      #pragma unroll
      for (int r = 0; r < 8; ++r)
        acc[i2][r] = fmaf(av[i2], bv[r], acc[i2][r]);
  }
  __syncthreads();
  #pragma unroll
  for (int i2 = 0; i2 < 5; ++i2)
    #pragma unroll
    for (int r = 0; r < 8; ++r) {
      int o = tq * 8 + r;
      Ha[o][tx * 5 + i2] = mishf(acc[i2][r] * s2s[o] + o2s[o]);
    }
  __syncthreads();

  for (int i = t; i < 1024; i += 256) {
    int p = i >> 6, o = i & 63;
    float mx = Ha[o][p * 10];
    #pragma unroll
    for (int k = 1; k < 10; ++k) mx = fmaxf(mx, Ha[o][p * 10 + k]);
    cat[(size_t)(p0 + p) * 192 + coff + o] = mx;
  }
}

// ---------- edge stage 3 (no conv2) ----------
__global__ __launch_bounds__(256)
void k_edge3(const float* __restrict__ UV, const int* __restrict__ idx,
             const float* __restrict__ gg, const float* __restrict__ bb,
             const float* __restrict__ mn, const float* __restrict__ vv,
             float* __restrict__ cat){
  int i = blockIdx.x * 256 + threadIdx.x;      // 4096 blocks
  int p = i >> 6, o = i & 63;
  int batch = p >> 11;
  float s = gg[o] / sqrtf(vv[o] + BN_EPS);
  float of = bb[o] - mn[o] * s;
  float v_ = UV[(size_t)p * 128 + 64 + o] + of;
  float mx = -INFINITY;
  #pragma unroll
  for (int k = 0; k < 10; ++k) {
    int j = batch * 2048 + (idx[p * 10 + k] & 2047);
    mx = fmaxf(mx, mishf(UV[(size_t)j * 128 + o] + v_));
  }
  cat[(size_t)p * 192 + 128 + o] = mx;
}

// ---------- tiled fp32 GEMM head: C[M,*] = A[M,K] * W[N,K]^T, f4 loads ----------
#define EP_BNMISH      0
#define EP_MAXGLOB     1
#define EP_BIAS_BNMISH 2

template<int EPI>
__global__ __launch_bounds__(256)
void k_gemm(const float* __restrict__ A, int lda,
            const float* __restrict__ W, int ldw, int K,
            const float* __restrict__ gg, const float* __restrict__ bb,
            const float* __restrict__ mn, const float* __restrict__ vv,
            const float* __restrict__ bias,
            float* __restrict__ out, int ldo,
            unsigned* __restrict__ glob)
{
  __shared__ float As[16][68];
  __shared__ float Bs[16][68];
  const int t  = threadIdx.x;
  const int tx = t & 15, ty = t >> 4;
  const int m0 = blockIdx.x * 64, n0 = blockIdx.y * 64;
  const int lm = t >> 2, lk = (t & 3) * 4;     // one f4 per thread per operand
  float acc[4][4] = {};

  for (int k0 = 0; k0 < K; k0 += 16) {
    float4 a4 = *(const float4*)&A[(size_t)(m0 + lm) * lda + k0 + lk];
    float4 b4 = *(const float4*)&W[(size_t)(n0 + lm) * ldw + k0 + lk];
    As[lk][lm] = a4.x; As[lk+1][lm] = a4.y; As[lk+2][lm] = a4.z; As[lk+3][lm] = a4.w;
    Bs[lk][lm] = b4.x; Bs[lk+1][lm] = b4.y; Bs[lk+2][lm] = b4.z; Bs[lk+3][lm] = b4.w;
    __syncthreads();
    #pragma unroll
    for (int k = 0; k < 16; ++k) {
      float4 av4 = *(const float4*)&As[k][tx * 4];
      float4 bv4 = *(const float4*)&Bs[k][ty * 4];
      float am[4] = {av4.x, av4.y, av4.z, av4.w};
      float bm[4] = {bv4.x, bv4.y, bv4.z, bv4.w};
      #pragma unroll
      for (int i2 = 0; i2 < 4; ++i2)
        #pragma unroll
        for (int j = 0; j < 4; ++j)
          acc[i2][j] = fmaf(am[i2], bm[j], acc[i2][j]);
    }
    __syncthreads();
  }

  float sc[4], of[4];
  #pragma unroll
  for (int j = 0; j < 4; ++j) {
    int nn = n0 + ty * 4 + j;
    float s = gg[nn] / sqrtf(vv[nn] + BN_EPS);
    sc[j] = s;
    of[j] = bb[nn] - mn[nn] * s;
  }

  if (EPI == EP_MAXGLOB) {
    float mx[4] = {-INFINITY, -INFINITY, -INFINITY, -INFINITY};
    #pragma unroll
    for (int i2 = 0; i2 < 4; ++i2)
      #pragma unroll
      for (int j = 0; j < 4; ++j)
        mx[j] = fmaxf(mx[j], mishf(acc[i2][j] * sc[j] + of[j]));
    __syncthreads();
    float* red = &As[0][0];
    #pragma unroll
    for (int j = 0; j < 4; ++j) red[(ty * 4 + j) * 16 + tx] = mx[j];
    __syncthreads();
    if (t < 64) {
      float v = red[t * 16];
      #pragma unroll
      for (int r = 1; r < 16; ++r) v = fmaxf(v, red[t * 16 + r]);
      atomicMax(&glob[(m0 >> 11) * 1024 + n0 + t], fenc(v));
    }
  } else {
    #pragma unroll
    for (int i2 = 0; i2 < 4; ++i2) {
      int m = m0 + tx * 4 + i2;
      #pragma unroll
      for (int j = 0; j < 4; ++j) {
        int nn = n0 + ty * 4 + j;
        float v = acc[i2][j];
        if (EPI == EP_BIAS_BNMISH) v += bias[(m >> 11) * 512 + nn];
        out[(size_t)m * ldo + nn] = mishf(v * sc[j] + of[j]);
      }
    }
  }
}

// ---------- t7[b][o] = w7[o, :1024] . glob[b] ----------
__global__ __launch_bounds__(256)
void k_t7(const unsigned* __restrict__ glob, const float* __restrict__ w7,
          float* __restrict__ t7){
  int i = blockIdx.x * 256 + threadIdx.x;      // 4096
  int b = i >> 9, o = i & 511;
  float acc = 0.f;
  for (int c = 0; c < 1024; ++c)
    acc = fmaf(w7[(size_t)o * 1216 + c], fdec(glob[b * 1024 + c]), acc);
  t7[i] = acc;
}

// ---------- final conv ----------
__global__ __launch_bounds__(256)
void k_out(const float* __restrict__ h8, const float* __restrict__ w9,
           float* __restrict__ out)
{
  __shared__ float row[4][256];
  const int t = threadIdx.x;
  const int g = t >> 6, l = t & 63;
  const int p = blockIdx.x * 4 + g;            // 4096 blocks
  for (int c = l; c < 256; c += 64)
    row[g][c] = h8[(size_t)p * 256 + c];
  __syncthreads();
  if (l < 18) {
    float acc = 0.f;
    for (int c = 0; c < 256; ++c)
      acc = fmaf(row[g][c], w9[l * 256 + c], acc);
    int b = p >> 11, n = p & 2047;
    out[(size_t)b * 36864 + l * 2048 + n] = acc;
  }
}

extern "C" void kernel_launch(void* const* d_in, const int* in_sizes, int n_in,
                              void* d_out, int out_size, void* d_ws, size_t ws_size,
                              hipStream_t stream)
{
  const size_t OFF_XF   = 0;
  const size_t OFF_IDX  = 262144;
  const size_t OFF_CAT  = 917504;
  const size_t OFF_GLOB = 13500416;
  const size_t OFF_T7   = 13533184;
  const size_t OFF_H7   = 13549568;            // h7; UV aliases first 8.4MB
  const size_t OFF_H8   = 47104000;            // h8; sq aliases first 64KB
  const size_t NEED     = 63881216;

  static const int EXP[26] = {
    49152, 384, 4096, 8192, 4096, 8192, 196608, 622592, 131072, 4608,
    320, 320, 320, 320, 1024, 1024, 1024, 1024,
    512, 512, 512, 512, 256, 256, 256, 256 };
  if (n_in < 26) { k_diag<<<1,1,0,stream>>>((float*)d_out, 16384.f); return; }
  for (int i = 0; i < 26; ++i)
    if (in_sizes[i] != EXP[i]) {
      k_diag<<<1,1,0,stream>>>((float*)d_out, 4096.f + 128.f * i); return;
    }
  if (out_size != 294912) { k_diag<<<1,1,0,stream>>>((float*)d_out, 20480.f); return; }
  if (ws_size < NEED) {
    k_diag<<<1,1,0,stream>>>((float*)d_out, 24576.f + (float)(ws_size >> 20)); return;
  }

  const float* x  = (const float*)d_in[0];
  const float* w1 = (const float*)d_in[1];
  const float* w2 = (const float*)d_in[2];
  const float* w3 = (const float*)d_in[3];
  const float* w4 = (const float*)d_in[4];
  const float* w5 = (const float*)d_in[5];
  const float* w6 = (const float*)d_in[6];
  const float* w7 = (const float*)d_in[7];
  const float* w8 = (const float*)d_in[8];
  const float* w9 = (const float*)d_in[9];
  const float* g15 = (const float*)d_in[10];
  const float* b15 = (const float*)d_in[11];
  const float* m15 = (const float*)d_in[12];
  const float* v15 = (const float*)d_in[13];
  const float* g6 = (const float*)d_in[14];
  const float* b6 = (const float*)d_in[15];
  const float* m6 = (const float*)d_in[16];
  const float* v6 = (const float*)d_in[17];
  const float* g7 = (const float*)d_in[18];
  const float* b7 = (const float*)d_in[19];
  const float* m7 = (const float*)d_in[20];
  const float* v7 = (const float*)d_in[21];
  const float* g8 = (const float*)d_in[22];
  const float* b8 = (const float*)d_in[23];
  const float* m8 = (const float*)d_in[24];
  const float* v8 = (const float*)d_in[25];

  char* ws = (char*)d_ws;
  float*    xf   = (float*)(ws + OFF_XF);
  int*      idx  = (int*)(ws + OFF_IDX);
  float*    cat  = (float*)(ws + OFF_CAT);
  unsigned* glob = (unsigned*)(ws + OFF_GLOB);
  float*    t7   = (float*)(ws + OFF_T7);
  float*    h7   = (float*)(ws + OFF_H7);
  float*    UV   = (float*)(ws + OFF_H7);
  float*    h8   = (float*)(ws + OFF_H8);
  float*    sq   = (float*)(ws + OFF_H8);

  k_cast<<<192, 256, 0, stream>>>(x, xf);

  // ---- stage 1 ----
  k_knn3<<<512, 256, 0, stream>>>(xf, idx);
  k_uv3<<<4096, 256, 0, stream>>>(xf, w1, g15 + 0, v15 + 0, UV);
  k_edge2<<<1024, 256, 0, stream>>>(UV, idx, w2,
      g15 + 0,  b15 + 0,  m15 + 0,  v15 + 0,
      g15 + 64, b15 + 64, m15 + 64, v15 + 64, cat, 0);

  // ---- stage 2 ----
  k_norm<64><<<64, 256, 0, stream>>>(cat, 192, 0, sq);
  k_knn2<<<256, 256, 0, stream>>>(cat, 192, 0, sq, idx);
  dim3 guv(256, 2);
  k_uv<<<guv, 256, 0, stream>>>(cat, 192, 0, w3, g15 + 128, v15 + 128, UV);
  k_edge2<<<1024, 256, 0, stream>>>(UV, idx, w4,
      g15 + 128, b15 + 128, m15 + 128, v15 + 128,
      g15 + 192, b15 + 192, m15 + 192, v15 + 192, cat, 64);

  // ---- stage 3 ----
  k_norm<64><<<64, 256, 0, stream>>>(cat, 192, 64, sq);
  k_knn2<<<256, 256, 0, stream>>>(cat, 192, 64, sq, idx);
  k_uv<<<guv, 256, 0, stream>>>(cat, 192, 64, w5, g15 + 256, v15 + 256, UV);
  k_edge3<<<4096, 256, 0, stream>>>(UV, idx,
      g15 + 256, b15 + 256, m15 + 256, v15 + 256, cat);

  // ---- head ----
  k_zero<<<32, 256, 0, stream>>>(glob);
  dim3 g6g(256, 16);
  k_gemm<EP_MAXGLOB><<<g6g, 256, 0, stream>>>(
      cat, 192, w6, 192, 192, g6, b6, m6, v6, nullptr, nullptr, 0, glob);
  k_t7<<<16, 256, 0, stream>>>(glob, w7, t7);
  dim3 g7g(256, 8);
  k_gemm<EP_BIAS_BNMISH><<<g7g, 256, 0, stream>>>(
      cat, 192, w7 + 1024, 1216, 192, g7, b7, m7, v7, t7, h7, 512, nullptr);
  dim3 g8g(256, 4);
  k_gemm<EP_BNMISH><<<g8g, 256, 0, stream>>>(
      h7, 512, w8, 512, 512, g8, b8, m8, v8, nullptr, h8, 256, nullptr);
  k_out<<<4096, 256, 0, stream>>>(h8, w9, (float*)d_out);
}

// Round 10
// 1564.540 us; speedup vs baseline: 1.2760x; 1.1778x over previous
//
#include <hip/hip_runtime.h>
#include <math.h>

#define BN_EPS 1e-5f

__device__ __forceinline__ float mishf(float x){
  float sp = fmaxf(x, 0.f) + log1pf(__expf(-fabsf(x)));
  float e  = __expf(-2.f * sp);
  return x * ((1.f - e) / (1.f + e));
}

__device__ __forceinline__ unsigned fenc(float f){
  unsigned u = __float_as_uint(f);
  return (u & 0x80000000u) ? ~u : (u | 0x80000000u);
}
__device__ __forceinline__ float fdec(unsigned e){
  unsigned u = (e & 0x80000000u) ? (e & 0x7fffffffu) : ~e;
  return __uint_as_float(u);
}

// stable top-10 insert: (value desc, index asc) == lax.top_k tie-break
__device__ __forceinline__ bool beats(float v, int i, float v2, int i2){
  return (v > v2) || (v == v2 && i < i2);
}
__device__ __forceinline__ void ins10(float (&lv)[10], int (&li)[10], float v, int i){
  if (!beats(v, i, lv[9], li[9])) return;
  #pragma unroll
  for (int p = 9; p >= 1; --p) {
    bool up   = beats(v, i, lv[p-1], li[p-1]);
    bool bp   = beats(v, i, lv[p],   li[p]);
    bool here = bp && !up;
    float nv = up ? lv[p-1] : (here ? v : lv[p]);
    int   ni = up ? li[p-1] : (here ? i : li[p]);
    lv[p] = nv; li[p] = ni;
  }
  if (beats(v, i, lv[0], li[0])) { lv[0] = v; li[0] = i; }
}

__global__ void k_diag(float* __restrict__ out, float v){ out[0] = v; }

// ---------- transpose x [B,3,N] -> xf [B*N,3] ----------
__global__ __launch_bounds__(256)
void k_cast(const float* __restrict__ x, float* __restrict__ xf){
  int i = blockIdx.x * 256 + threadIdx.x;      // 49152
  int n = i & 2047, c = (i >> 11) % 3, b = i / (3 * 2048);
  xf[(size_t)(b * 2048 + n) * 3 + c] = x[i];
}

__global__ __launch_bounds__(256)
void k_zero(unsigned* __restrict__ p){
  p[blockIdx.x * 256 + threadIdx.x] = 0u;      // 32 blocks -> 8192
}

// ---------- squared norm per point ----------
template<int C>
__global__ __launch_bounds__(256)
void k_norm(const float* __restrict__ src, int stride, int off,
            float* __restrict__ sq){
  int i = blockIdx.x * 256 + threadIdx.x;      // 16384
  const float* r = src + (size_t)i * stride + off;
  float s = 0.f;
  #pragma unroll
  for (int c = 0; c < C; ++c) s = fmaf(r[c], r[c], s);
  sq[i] = s;
}

// ---------- knn C=3: 32 points/block, 8 chunk-threads/point ----------
__global__ __launch_bounds__(256)
void k_knn3(const float* __restrict__ src, int* __restrict__ idxout){
  constexpr int C = 3, PAD = 4;
  __shared__ float pts[128 * PAD];
  __shared__ float ss[128];
  __shared__ float mlv[32 * 8 * 10];
  __shared__ int   mli[32 * 8 * 10];
  const int t  = threadIdx.x;
  const int b  = blockIdx.x >> 6;
  const int p0 = (blockIdx.x & 63) * 32;
  const int p  = t >> 3, ch = t & 7;
  const float* srow = src + (size_t)(b * 2048 + p0 + p) * C;
  float own[C];
  #pragma unroll
  for (int c = 0; c < C; ++c) own[c] = srow[c];
  float sown = 0.f;
  #pragma unroll
  for (int c = 0; c < C; ++c) sown = fmaf(own[c], own[c], sown);
  float lv[10]; int li[10];
  #pragma unroll
  for (int j = 0; j < 10; ++j){ lv[j] = -INFINITY; li[j] = 0x7fffffff; }

  for (int m0 = 0; m0 < 2048; m0 += 128) {
    __syncthreads();
    for (int i = t; i < 128 * C; i += 256) {
      int mm = i / C, c = i % C;
      pts[mm * PAD + c] = src[(size_t)(b * 2048 + m0 + mm) * C + c];
    }
    __syncthreads();
    if (t < 128) {
      float s2 = 0.f;
      #pragma unroll
      for (int c = 0; c < C; ++c) s2 = fmaf(pts[t * PAD + c], pts[t * PAD + c], s2);
      ss[t] = s2;
    }
    __syncthreads();
    for (int mm = ch; mm < 128; mm += 8) {
      float dot = 0.f;
      #pragma unroll
      for (int c = 0; c < C; ++c) dot = fmaf(own[c], pts[mm * PAD + c], dot);
      ins10(lv, li, 2.f * dot - sown - ss[mm], m0 + mm);
    }
  }
  __syncthreads();
  #pragma unroll
  for (int j = 0; j < 10; ++j) { mlv[t * 10 + j] = lv[j]; mli[t * 10 + j] = li[j]; }
  __syncthreads();
  if (t < 32) {
    float fv[10]; int fi[10];
    #pragma unroll
    for (int j = 0; j < 10; ++j){ fv[j] = -INFINITY; fi[j] = 0x7fffffff; }
    for (int c2 = 0; c2 < 8; ++c2)
      for (int j = 0; j < 10; ++j)
        ins10(fv, fi, mlv[(t * 8 + c2) * 10 + j], mli[(t * 8 + c2) * 10 + j]);
    #pragma unroll
    for (int j = 0; j < 10; ++j)
      idxout[(size_t)(b * 2048 + p0 + t) * 10 + j] = fi[j];
  }
}

// ---------- knn C=64, PARTIAL: 64 rows x 512 cands per block, grid 1024 ----------
// bx: cc = bx&3 (cand chunk), rg = (bx>>2)&31, b = bx>>7.
__global__ __launch_bounds__(256)
void k_knn2p(const float* __restrict__ src, int stride, int off,
             const float* __restrict__ sq,
             float* __restrict__ pv, int* __restrict__ pi){
  __shared__ float As[64][68];   // [ch][row]
  __shared__ float Bs[64][68];   // [cand][ch]
  __shared__ float Sc[64 * 65];  // [row][col swizzled]
  __shared__ float ssB[64];
  const int t  = threadIdx.x;
  const int bx = blockIdx.x;
  const int cc = bx & 3;
  const int rg = (bx >> 2) & 31;
  const int b  = bx >> 7;
  const int p0 = rg * 64;
  const int c0 = cc * 512;
  const int tx = t & 15, ty = t >> 4;
  const int row = t & 63, chk = t >> 6;

  #pragma unroll
  for (int pass = 0; pass < 4; ++pass) {
    int i = pass * 256 + t;
    int r_ = i >> 4, c4 = (i & 15) * 4;
    float4 v = *(const float4*)&src[(size_t)(b * 2048 + p0 + r_) * stride + off + c4];
    As[c4    ][r_] = v.x;
    As[c4 + 1][r_] = v.y;
    As[c4 + 2][r_] = v.z;
    As[c4 + 3][r_] = v.w;
  }
  float sqA = sq[b * 2048 + p0 + row];
  float lv[10]; int li[10];
  #pragma unroll
  for (int j = 0; j < 10; ++j){ lv[j] = -INFINITY; li[j] = 0x7fffffff; }

  for (int m0 = c0; m0 < c0 + 512; m0 += 64) {
    #pragma unroll
    for (int pass = 0; pass < 4; ++pass) {
      int i = pass * 256 + t;
      int j_ = i >> 4, c4 = (i & 15) * 4;
      *(float4*)&Bs[j_][c4] =
          *(const float4*)&src[(size_t)(b * 2048 + m0 + j_) * stride + off + c4];
    }
    if (t < 64) ssB[t] = sq[b * 2048 + m0 + t];
    __syncthreads();

    float acc[4][4] = {};
    #pragma unroll
    for (int c = 0; c < 64; ++c) {
      float4 a4 = *(const float4*)&As[c][tx * 4];
      float av[4] = {a4.x, a4.y, a4.z, a4.w};
      float bv[4];
      #pragma unroll
      for (int r = 0; r < 4; ++r) bv[r] = Bs[ty * 4 + r][c];
      #pragma unroll
      for (int q = 0; q < 4; ++q)
        #pragma unroll
        for (int r = 0; r < 4; ++r)
          acc[q][r] = fmaf(av[q], bv[r], acc[q][r]);
    }
    #pragma unroll
    for (int q = 0; q < 4; ++q) {
      int r_ = tx * 4 + q;
      int f  = tx & 3;
      #pragma unroll
      for (int r2 = 0; r2 < 4; ++r2)
        Sc[r_ * 65 + ((ty * 4 + r2 + f) & 63)] = acc[q][r2];
    }
    __syncthreads();
    {
      int f = (row >> 2) & 3;
      #pragma unroll
      for (int m2 = 0; m2 < 16; ++m2) {
        int mm = chk * 16 + m2;
        float key = 2.f * Sc[row * 65 + ((mm + f) & 63)] - sqA - ssB[mm];
        ins10(lv, li, key, m0 + mm);
      }
    }
    __syncthreads();
  }

  // merge 4 chunk-lists per row; alias dead As/Bs
  float* mgv = &As[0][0];
  int*   mgi = (int*)&Bs[0][0];
  #pragma unroll
  for (int j = 0; j < 10; ++j) {
    mgv[(row * 4 + chk) * 10 + j] = lv[j];
    mgi[(row * 4 + chk) * 10 + j] = li[j];
  }
  __syncthreads();
  if (t < 64) {
    float fv[10]; int fi[10];
    #pragma unroll
    for (int j = 0; j < 10; ++j){ fv[j] = -INFINITY; fi[j] = 0x7fffffff; }
    for (int c2 = 0; c2 < 4; ++c2)
      for (int j = 0; j < 10; ++j)
        ins10(fv, fi, mgv[(t * 4 + c2) * 10 + j], mgi[(t * 4 + c2) * 10 + j]);
    size_t base = (size_t)(b * 2048 + p0 + t) * 40 + cc * 10;
    #pragma unroll
    for (int j = 0; j < 10; ++j) { pv[base + j] = fv[j]; pi[base + j] = fi[j]; }
  }
}

// ---------- merge 4 partial top-10 lists -> final idx ----------
__global__ __launch_bounds__(256)
void k_kmerge(const float* __restrict__ pv, const int* __restrict__ pi,
              int* __restrict__ idxout){
  int row = blockIdx.x * 256 + threadIdx.x;    // 16384
  float fv[10]; int fi[10];
  #pragma unroll
  for (int j = 0; j < 10; ++j){ fv[j] = -INFINITY; fi[j] = 0x7fffffff; }
  size_t base = (size_t)row * 40;
  for (int e = 0; e < 40; ++e)
    ins10(fv, fi, pv[base + e], pi[base + e]);
  #pragma unroll
  for (int j = 0; j < 10; ++j) idxout[(size_t)row * 10 + j] = fi[j];
}

// ---------- UV for stage 1 (C=3): elementwise ----------
__global__ __launch_bounds__(256)
void k_uv3(const float* __restrict__ xf, const float* __restrict__ w1,
           const float* __restrict__ gg, const float* __restrict__ vv,
           float* __restrict__ UV){
  int i = blockIdx.x * 256 + threadIdx.x;      // 4096 blocks
  int p = i >> 6, o = i & 63;
  float s = gg[o] / sqrtf(vv[o] + BN_EPS);
  float x0 = xf[(size_t)p * 3], x1 = xf[(size_t)p * 3 + 1], x2 = xf[(size_t)p * 3 + 2];
  const float* wr = w1 + o * 6;
  float u = s * (wr[0] * x0 + wr[1] * x1 + wr[2] * x2);
  float v = s * ((wr[3] - wr[0]) * x0 + (wr[4] - wr[1]) * x1 + (wr[5] - wr[2]) * x2);
  UV[(size_t)p * 128 + o] = u;
  UV[(size_t)p * 128 + 64 + o] = v;
}

// ---------- UV for stages 2/3 (C=64): tiled GEMM, s1 folded ----------
__global__ __launch_bounds__(256)
void k_uv(const float* __restrict__ A, int lda, int aoff,
          const float* __restrict__ w,       // [64][128]
          const float* __restrict__ gg, const float* __restrict__ vv,
          float* __restrict__ UV){
  __shared__ float As[16][68];
  __shared__ float Bs[16][68];
  __shared__ float ss[64];
  const int t = threadIdx.x;
  const int tx = t & 15, ty = t >> 4;
  const int m0 = blockIdx.x * 64;
  const int half = blockIdx.y;
  if (t < 64) ss[t] = gg[t] / sqrtf(vv[t] + BN_EPS);
  __syncthreads();
  float acc[4][4] = {};
  for (int k0 = 0; k0 < 64; k0 += 16) {
    for (int i = t; i < 1024; i += 256) {
      int m = i >> 4, k = i & 15;
      As[k][m] = A[(size_t)(m0 + m) * lda + aoff + k0 + k];
    }
    for (int i = t; i < 1024; i += 256) {
      int n = i >> 4, k = i & 15;
      int kk = k0 + k;
      float wv = half ? (w[n * 128 + 64 + kk] - w[n * 128 + kk]) : w[n * 128 + kk];
      Bs[k][n] = wv * ss[n];
    }
    __syncthreads();
    #pragma unroll
    for (int k = 0; k < 16; ++k) {
      float4 a4 = *(const float4*)&As[k][tx * 4];
      float4 b4 = *(const float4*)&Bs[k][ty * 4];
      float am[4] = {a4.x, a4.y, a4.z, a4.w};
      float bm[4] = {b4.x, b4.y, b4.z, b4.w};
      #pragma unroll
      for (int q = 0; q < 4; ++q)
        #pragma unroll
        for (int r = 0; r < 4; ++r)
          acc[q][r] = fmaf(am[q], bm[r], acc[q][r]);
    }
    __syncthreads();
  }
  #pragma unroll
  for (int q = 0; q < 4; ++q)
    #pragma unroll
    for (int r = 0; r < 4; ++r)
      UV[(size_t)(m0 + tx * 4 + q) * 128 + half * 64 + ty * 4 + r] = acc[q][r];
}

// ---------- edge stage with conv2 ----------
__global__ __launch_bounds__(256)
void k_edge2(const float* __restrict__ UV, const int* __restrict__ idx,
             const float* __restrict__ w2,   // [64][64]
             const float* __restrict__ g1, const float* __restrict__ b1,
             const float* __restrict__ m1, const float* __restrict__ v1,
             const float* __restrict__ g2, const float* __restrict__ b2,
             const float* __restrict__ m2, const float* __restrict__ v2,
             float* __restrict__ cat, int coff){
  __shared__ float Ha[64][161];
  __shared__ float Ws[64][68];
  __shared__ float o1s[64], s2s[64], o2s[64];
  __shared__ int   ejs[160];
  const int t = threadIdx.x;
  const int p0 = blockIdx.x * 16;
  const int batch = p0 >> 11;
  if (t < 160) ejs[t] = batch * 2048 + (idx[p0 * 10 + t] & 2047);
  if (t < 64) {
    float s1 = g1[t] / sqrtf(v1[t] + BN_EPS);
    o1s[t] = b1[t] - m1[t] * s1;
    float s2 = g2[t] / sqrtf(v2[t] + BN_EPS);
    s2s[t] = s2;
    o2s[t] = b2[t] - m2[t] * s2;
  }
  for (int i = t; i < 4096; i += 256) {
    int k = i & 63, n = i >> 6;
    Ws[k][n] = w2[n * 64 + k];
  }
  __syncthreads();

  for (int i = t; i < 10240; i += 256) {
    int e = i >> 6, c = i & 63;
    int p = p0 + e / 10;
    float hv = UV[(size_t)ejs[e] * 128 + c] + UV[(size_t)p * 128 + 64 + c] + o1s[c];
    Ha[c][e] = mishf(hv);
  }
  __syncthreads();

  const int tx = t & 31, tq = t >> 5;
  float acc[5][8] = {};
  #pragma unroll 8
  for (int k = 0; k < 64; ++k) {
    float av[5], bv[8];
    #pragma unroll
    for (int i2 = 0; i2 < 5; ++i2) av[i2] = Ha[k][tx * 5 + i2];
    #pragma unroll
    for (int r = 0; r < 8; ++r) bv[r] = Ws[k][tq * 8 + r];
    #pragma unroll
    for (int i2 = 0; i2 < 5; ++i2)
      #pragma unroll
      for (int r = 0; r < 8; ++r)
        acc[i2][r] = fmaf(av[i2], bv[r], acc[i2][r]);
  }
  __syncthreads();
  #pragma unroll
  for (int i2 = 0; i2 < 5; ++i2)
    #pragma unroll
    for (int r = 0; r < 8; ++r) {
      int o = tq * 8 + r;
      Ha[o][tx * 5 + i2] = mishf(acc[i2][r] * s2s[o] + o2s[o]);
    }
  __syncthreads();

  for (int i = t; i < 1024; i += 256) {
    int p = i >> 6, o = i & 63;
    float mx = Ha[o][p * 10];
    #pragma unroll
    for (int k = 1; k < 10; ++k) mx = fmaxf(mx, Ha[o][p * 10 + k]);
    cat[(size_t)(p0 + p) * 192 + coff + o] = mx;
  }
}

// ---------- edge stage 3 (no conv2) ----------
__global__ __launch_bounds__(256)
void k_edge3(const float* __restrict__ UV, const int* __restrict__ idx,
             const float* __restrict__ gg, const float* __restrict__ bb,
             const float* __restrict__ mn, const float* __restrict__ vv,
             float* __restrict__ cat){
  int i = blockIdx.x * 256 + threadIdx.x;      // 4096 blocks
  int p = i >> 6, o = i & 63;
  int batch = p >> 11;
  float s = gg[o] / sqrtf(vv[o] + BN_EPS);
  float of = bb[o] - mn[o] * s;
  float v_ = UV[(size_t)p * 128 + 64 + o] + of;
  float mx = -INFINITY;
  #pragma unroll
  for (int k = 0; k < 10; ++k) {
    int j = batch * 2048 + (idx[p * 10 + k] & 2047);
    mx = fmaxf(mx, mishf(UV[(size_t)j * 128 + o] + v_));
  }
  cat[(size_t)p * 192 + 128 + o] = mx;
}

// ---------- tiled fp32 GEMM head ----------
#define EP_BNMISH      0
#define EP_MAXGLOB     1
#define EP_BIAS_BNMISH 2

template<int EPI>
__global__ __launch_bounds__(256)
void k_gemm(const float* __restrict__ A, int lda,
            const float* __restrict__ W, int ldw, int K,
            const float* __restrict__ gg, const float* __restrict__ bb,
            const float* __restrict__ mn, const float* __restrict__ vv,
            const float* __restrict__ bias,
            float* __restrict__ out, int ldo,
            unsigned* __restrict__ glob)
{
  __shared__ float As[16][68];
  __shared__ float Bs[16][68];
  const int t  = threadIdx.x;
  const int tx = t & 15, ty = t >> 4;
  const int m0 = blockIdx.x * 64, n0 = blockIdx.y * 64;
  const int lm = t >> 2, lk = (t & 3) * 4;
  float acc[4][4] = {};

  for (int k0 = 0; k0 < K; k0 += 16) {
    float4 a4 = *(const float4*)&A[(size_t)(m0 + lm) * lda + k0 + lk];
    float4 b4 = *(const float4*)&W[(size_t)(n0 + lm) * ldw + k0 + lk];
    As[lk][lm] = a4.x; As[lk+1][lm] = a4.y; As[lk+2][lm] = a4.z; As[lk+3][lm] = a4.w;
    Bs[lk][lm] = b4.x; Bs[lk+1][lm] = b4.y; Bs[lk+2][lm] = b4.z; Bs[lk+3][lm] = b4.w;
    __syncthreads();
    #pragma unroll
    for (int k = 0; k < 16; ++k) {
      float4 av4 = *(const float4*)&As[k][tx * 4];
      float4 bv4 = *(const float4*)&Bs[k][ty * 4];
      float am[4] = {av4.x, av4.y, av4.z, av4.w};
      float bm[4] = {bv4.x, bv4.y, bv4.z, bv4.w};
      #pragma unroll
      for (int i2 = 0; i2 < 4; ++i2)
        #pragma unroll
        for (int j = 0; j < 4; ++j)
          acc[i2][j] = fmaf(am[i2], bm[j], acc[i2][j]);
    }
    __syncthreads();
  }

  float sc[4], of[4];
  #pragma unroll
  for (int j = 0; j < 4; ++j) {
    int nn = n0 + ty * 4 + j;
    float s = gg[nn] / sqrtf(vv[nn] + BN_EPS);
    sc[j] = s;
    of[j] = bb[nn] - mn[nn] * s;
  }

  if (EPI == EP_MAXGLOB) {
    float mx[4] = {-INFINITY, -INFINITY, -INFINITY, -INFINITY};
    #pragma unroll
    for (int i2 = 0; i2 < 4; ++i2)
      #pragma unroll
      for (int j = 0; j < 4; ++j)
        mx[j] = fmaxf(mx[j], mishf(acc[i2][j] * sc[j] + of[j]));
    __syncthreads();
    float* red = &As[0][0];
    #pragma unroll
    for (int j = 0; j < 4; ++j) red[(ty * 4 + j) * 16 + tx] = mx[j];
    __syncthreads();
    if (t < 64) {
      float v = red[t * 16];
      #pragma unroll
      for (int r = 1; r < 16; ++r) v = fmaxf(v, red[t * 16 + r]);
      atomicMax(&glob[(m0 >> 11) * 1024 + n0 + t], fenc(v));
    }
  } else {
    #pragma unroll
    for (int i2 = 0; i2 < 4; ++i2) {
      int m = m0 + tx * 4 + i2;
      #pragma unroll
      for (int j = 0; j < 4; ++j) {
        int nn = n0 + ty * 4 + j;
        float v = acc[i2][j];
        if (EPI == EP_BIAS_BNMISH) v += bias[(m >> 11) * 512 + nn];
        out[(size_t)m * ldo + nn] = mishf(v * sc[j] + of[j]);
      }
    }
  }
}

// ---------- t7[b][o] = w7[o, :1024] . glob[b] ----------
__global__ __launch_bounds__(256)
void k_t7(const unsigned* __restrict__ glob, const float* __restrict__ w7,
          float* __restrict__ t7){
  int i = blockIdx.x * 256 + threadIdx.x;      // 4096
  int b = i >> 9, o = i & 511;
  float acc = 0.f;
  for (int c = 0; c < 1024; ++c)
    acc = fmaf(w7[(size_t)o * 1216 + c], fdec(glob[b * 1024 + c]), acc);
  t7[i] = acc;
}

// ---------- final conv ----------
__global__ __launch_bounds__(256)
void k_out(const float* __restrict__ h8, const float* __restrict__ w9,
           float* __restrict__ out)
{
  __shared__ float row[4][256];
  const int t = threadIdx.x;
  const int g = t >> 6, l = t & 63;
  const int p = blockIdx.x * 4 + g;            // 4096 blocks
  for (int c = l; c < 256; c += 64)
    row[g][c] = h8[(size_t)p * 256 + c];
  __syncthreads();
  if (l < 18) {
    float acc = 0.f;
    for (int c = 0; c < 256; ++c)
      acc = fmaf(row[g][c], w9[l * 256 + c], acc);
    int b = p >> 11, n = p & 2047;
    out[(size_t)b * 36864 + l * 2048 + n] = acc;
  }
}

extern "C" void kernel_launch(void* const* d_in, const int* in_sizes, int n_in,
                              void* d_out, int out_size, void* d_ws, size_t ws_size,
                              hipStream_t stream)
{
  const size_t OFF_XF   = 0;
  const size_t OFF_IDX  = 262144;
  const size_t OFF_CAT  = 917504;
  const size_t OFF_GLOB = 13500416;
  const size_t OFF_T7   = 13533184;
  const size_t OFF_H7   = 13549568;            // h7; UV aliases first 8.4MB
  const size_t OFF_H8   = 47104000;            // h8; sq/pv/pi alias (knn phase)
  const size_t NEED     = 63881216;

  static const int EXP[26] = {
    49152, 384, 4096, 8192, 4096, 8192, 196608, 622592, 131072, 4608,
    320, 320, 320, 320, 1024, 1024, 1024, 1024,
    512, 512, 512, 512, 256, 256, 256, 256 };
  if (n_in < 26) { k_diag<<<1,1,0,stream>>>((float*)d_out, 16384.f); return; }
  for (int i = 0; i < 26; ++i)
    if (in_sizes[i] != EXP[i]) {
      k_diag<<<1,1,0,stream>>>((float*)d_out, 4096.f + 128.f * i); return;
    }
  if (out_size != 294912) { k_diag<<<1,1,0,stream>>>((float*)d_out, 20480.f); return; }
  if (ws_size < NEED) {
    k_diag<<<1,1,0,stream>>>((float*)d_out, 24576.f + (float)(ws_size >> 20)); return;
  }

  const float* x  = (const float*)d_in[0];
  const float* w1 = (const float*)d_in[1];
  const float* w2 = (const float*)d_in[2];
  const float* w3 = (const float*)d_in[3];
  const float* w4 = (const float*)d_in[4];
  const float* w5 = (const float*)d_in[5];
  const float* w6 = (const float*)d_in[6];
  const float* w7 = (const float*)d_in[7];
  const float* w8 = (const float*)d_in[8];
  const float* w9 = (const float*)d_in[9];
  const float* g15 = (const float*)d_in[10];
  const float* b15 = (const float*)d_in[11];
  const float* m15 = (const float*)d_in[12];
  const float* v15 = (const float*)d_in[13];
  const float* g6 = (const float*)d_in[14];
  const float* b6 = (const float*)d_in[15];
  const float* m6 = (const float*)d_in[16];
  const float* v6 = (const float*)d_in[17];
  const float* g7 = (const float*)d_in[18];
  const float* b7 = (const float*)d_in[19];
  const float* m7 = (const float*)d_in[20];
  const float* v7 = (const float*)d_in[21];
  const float* g8 = (const float*)d_in[22];
  const float* b8 = (const float*)d_in[23];
  const float* m8 = (const float*)d_in[24];
  const float* v8 = (const float*)d_in[25];

  char* ws = (char*)d_ws;
  float*    xf   = (float*)(ws + OFF_XF);
  int*      idx  = (int*)(ws + OFF_IDX);
  float*    cat  = (float*)(ws + OFF_CAT);
  unsigned* glob = (unsigned*)(ws + OFF_GLOB);
  float*    t7   = (float*)(ws + OFF_T7);
  float*    h7   = (float*)(ws + OFF_H7);
  float*    UV   = (float*)(ws + OFF_H7);
  float*    h8   = (float*)(ws + OFF_H8);
  float*    sq   = (float*)(ws + OFF_H8);                  //    65,536 [16384]
  float*    pv   = (float*)(ws + OFF_H8 + 65536);          // 2,621,440 [16384][40]
  int*      pi   = (int*)(ws + OFF_H8 + 65536 + 2621440);  // 2,621,440 [16384][40]

  k_cast<<<192, 256, 0, stream>>>(x, xf);

  // ---- stage 1 ----
  k_knn3<<<512, 256, 0, stream>>>(xf, idx);
  k_uv3<<<4096, 256, 0, stream>>>(xf, w1, g15 + 0, v15 + 0, UV);
  k_edge2<<<1024, 256, 0, stream>>>(UV, idx, w2,
      g15 + 0,  b15 + 0,  m15 + 0,  v15 + 0,
      g15 + 64, b15 + 64, m15 + 64, v15 + 64, cat, 0);

  // ---- stage 2 ----
  k_norm<64><<<64, 256, 0, stream>>>(cat, 192, 0, sq);
  k_knn2p<<<1024, 256, 0, stream>>>(cat, 192, 0, sq, pv, pi);
  k_kmerge<<<64, 256, 0, stream>>>(pv, pi, idx);
  dim3 guv(256, 2);
  k_uv<<<guv, 256, 0, stream>>>(cat, 192, 0, w3, g15 + 128, v15 + 128, UV);
  k_edge2<<<1024, 256, 0, stream>>>(UV, idx, w4,
      g15 + 128, b15 + 128, m15 + 128, v15 + 128,
      g15 + 192, b15 + 192, m15 + 192, v15 + 192, cat, 64);

  // ---- stage 3 ----
  k_norm<64><<<64, 256, 0, stream>>>(cat, 192, 64, sq);
  k_knn2p<<<1024, 256, 0, stream>>>(cat, 192, 64, sq, pv, pi);
  k_kmerge<<<64, 256, 0, stream>>>(pv, pi, idx);
  k_uv<<<guv, 256, 0, stream>>>(cat, 192, 64, w5, g15 + 256, v15 + 256, UV);
  k_edge3<<<4096, 256, 0, stream>>>(UV, idx,
      g15 + 256, b15 + 256, m15 + 256, v15 + 256, cat);

  // ---- head ----
  k_zero<<<32, 256, 0, stream>>>(glob);
  dim3 g6g(256, 16);
  k_gemm<EP_MAXGLOB><<<g6g, 256, 0, stream>>>(
      cat, 192, w6, 192, 192, g6, b6, m6, v6, nullptr, nullptr, 0, glob);
  k_t7<<<16, 256, 0, stream>>>(glob, w7, t7);
  dim3 g7g(256, 8);
  k_gemm<EP_BIAS_BNMISH><<<g7g, 256, 0, stream>>>(
      cat, 192, w7 + 1024, 1216, 192, g7, b7, m7, v7, t7, h7, 512, nullptr);
  dim3 g8g(256, 4);
  k_gemm<EP_BNMISH><<<g8g, 256, 0, stream>>>(
      h7, 512, w8, 512, 512, g8, b8, m8, v8, nullptr, h8, 256, nullptr);
  k_out<<<4096, 256, 0, stream>>>(h8, w9, (float*)d_out);
}

// Round 11
// 1189.479 us; speedup vs baseline: 1.6784x; 1.3153x over previous
//
#include <hip/hip_runtime.h>
#include <math.h>

#define BN_EPS 1e-5f
typedef unsigned long long u64;

__device__ __forceinline__ float mishf(float x){
  float sp = fmaxf(x, 0.f) + log1pf(__expf(-fabsf(x)));
  float e  = __expf(-2.f * sp);
  return x * ((1.f - e) / (1.f + e));
}

__device__ __forceinline__ unsigned fenc(float f){
  unsigned u = __float_as_uint(f);
  return (u & 0x80000000u) ? ~u : (u | 0x80000000u);
}
__device__ __forceinline__ float fdec(unsigned e){
  unsigned u = (e & 0x80000000u) ? (e & 0x7fffffffu) : ~e;
  return __uint_as_float(u);
}

// packed key: (value desc, index asc) == lax.top_k order as single u64 compare
__device__ __forceinline__ u64 mkkey(float v, int i){
  return ((u64)fenc(v) << 32) | (unsigned)(~i);
}
__device__ __forceinline__ int keyidx(u64 k){ return (int)(~(unsigned)k); }

// sorted-desc top-10 insert on u64 keys; all reads of L are pre-update values
__device__ __forceinline__ void ins10k(u64 (&L)[10], u64 k){
  if (k <= L[9]) return;
  #pragma unroll
  for (int p = 9; p >= 1; --p)
    L[p] = (k > L[p-1]) ? L[p-1] : ((k > L[p]) ? k : L[p]);
  L[0] = (k > L[0]) ? k : L[0];
}
#define KSENT mkkey(-INFINITY, 0x7fffffff)

__global__ void k_diag(float* __restrict__ out, float v){ out[0] = v; }

// ---------- transpose x [B,3,N] -> xf [B*N,3] ----------
__global__ __launch_bounds__(256)
void k_cast(const float* __restrict__ x, float* __restrict__ xf){
  int i = blockIdx.x * 256 + threadIdx.x;      // 49152
  int n = i & 2047, c = (i >> 11) % 3, b = i / (3 * 2048);
  xf[(size_t)(b * 2048 + n) * 3 + c] = x[i];
}

__global__ __launch_bounds__(256)
void k_zero(unsigned* __restrict__ p){
  p[blockIdx.x * 256 + threadIdx.x] = 0u;      // 32 blocks -> 8192
}

// ---------- squared norm per point ----------
template<int C>
__global__ __launch_bounds__(256)
void k_norm(const float* __restrict__ src, int stride, int off,
            float* __restrict__ sq){
  int i = blockIdx.x * 256 + threadIdx.x;      // 16384
  const float* r = src + (size_t)i * stride + off;
  float s = 0.f;
  #pragma unroll
  for (int c = 0; c < C; ++c) s = fmaf(r[c], r[c], s);
  sq[i] = s;
}

// ---------- knn C=3: 32 points/block, 8 chunk-threads/point ----------
__global__ __launch_bounds__(256)
void k_knn3(const float* __restrict__ src, int* __restrict__ idxout){
  constexpr int C = 3, PAD = 4;
  __shared__ float pts[128 * PAD];
  __shared__ float ss[128];
  __shared__ unsigned mH[32 * 8 * 10];
  __shared__ unsigned mL[32 * 8 * 10];
  const int t  = threadIdx.x;
  const int b  = blockIdx.x >> 6;
  const int p0 = (blockIdx.x & 63) * 32;
  const int p  = t >> 3, ch = t & 7;
  const float* srow = src + (size_t)(b * 2048 + p0 + p) * C;
  float own[C];
  #pragma unroll
  for (int c = 0; c < C; ++c) own[c] = srow[c];
  float sown = 0.f;
  #pragma unroll
  for (int c = 0; c < C; ++c) sown = fmaf(own[c], own[c], sown);
  u64 L[10];
  #pragma unroll
  for (int j = 0; j < 10; ++j) L[j] = KSENT;

  for (int m0 = 0; m0 < 2048; m0 += 128) {
    __syncthreads();
    for (int i = t; i < 128 * C; i += 256) {
      int mm = i / C, c = i % C;
      pts[mm * PAD + c] = src[(size_t)(b * 2048 + m0 + mm) * C + c];
    }
    __syncthreads();
    if (t < 128) {
      float s2 = 0.f;
      #pragma unroll
      for (int c = 0; c < C; ++c) s2 = fmaf(pts[t * PAD + c], pts[t * PAD + c], s2);
      ss[t] = s2;
    }
    __syncthreads();
    for (int mm = ch; mm < 128; mm += 8) {
      float dot = 0.f;
      #pragma unroll
      for (int c = 0; c < C; ++c) dot = fmaf(own[c], pts[mm * PAD + c], dot);
      ins10k(L, mkkey(2.f * dot - sown - ss[mm], m0 + mm));
    }
  }
  __syncthreads();
  #pragma unroll
  for (int j = 0; j < 10; ++j) {
    mH[t * 10 + j] = (unsigned)(L[j] >> 32);
    mL[t * 10 + j] = (unsigned)L[j];
  }
  __syncthreads();
  if (t < 32) {
    u64 F[10];
    #pragma unroll
    for (int j = 0; j < 10; ++j) F[j] = KSENT;
    for (int c2 = 0; c2 < 8; ++c2)
      for (int j = 0; j < 10; ++j) {
        int s = (t * 8 + c2) * 10 + j;
        ins10k(F, ((u64)mH[s] << 32) | mL[s]);
      }
    #pragma unroll
    for (int j = 0; j < 10; ++j)
      idxout[(size_t)(b * 2048 + p0 + t) * 10 + j] = keyidx(F[j]);
  }
}

// ---------- knn C=64 partial: 64 rows x 512 cands/block, grid 1024 ----------
// LDS 34.9KB (Sc aliased into Bs) -> 4 blocks/CU; f4 A+B reads -> VALU-bound GEMM.
__global__ __launch_bounds__(256)
void k_knn2p(const float* __restrict__ src, int stride, int off,
             const float* __restrict__ sq, u64* __restrict__ pk){
  __shared__ float As[64][68];   // [ch][row]
  __shared__ float Bs[64][68];   // [cand][ch]; aliased as Sc (stride 65) + mgL
  __shared__ float ssB[64];
  float* ScB = &Bs[0][0];
  const int t  = threadIdx.x;
  const int bx = blockIdx.x;
  const int cc = bx & 3;
  const int rg = (bx >> 2) & 31;
  const int b  = bx >> 7;
  const int p0 = rg * 64;
  const int c0 = cc * 512;
  const int tx = t & 15, ty = t >> 4;
  const int row = t & 63, chk = t >> 6;

  #pragma unroll
  for (int pass = 0; pass < 4; ++pass) {
    int i = pass * 256 + t;
    int r_ = i >> 4, c4 = (i & 15) * 4;
    float4 v = *(const float4*)&src[(size_t)(b * 2048 + p0 + r_) * stride + off + c4];
    As[c4    ][r_] = v.x;
    As[c4 + 1][r_] = v.y;
    As[c4 + 2][r_] = v.z;
    As[c4 + 3][r_] = v.w;
  }
  float sqA = sq[b * 2048 + p0 + row];
  u64 L[10];
  #pragma unroll
  for (int j = 0; j < 10; ++j) L[j] = KSENT;

  for (int m0 = c0; m0 < c0 + 512; m0 += 64) {
    #pragma unroll
    for (int pass = 0; pass < 4; ++pass) {
      int i = pass * 256 + t;
      int j_ = i >> 4, c4 = (i & 15) * 4;
      *(float4*)&Bs[j_][c4] =
          *(const float4*)&src[(size_t)(b * 2048 + m0 + j_) * stride + off + c4];
    }
    if (t < 64) ssB[t] = sq[b * 2048 + m0 + t];
    __syncthreads();

    float acc[4][4] = {};
    #pragma unroll
    for (int c = 0; c < 64; c += 4) {
      float4 b4[4], a4[4];
      #pragma unroll
      for (int r = 0; r < 4; ++r) b4[r] = *(const float4*)&Bs[ty * 4 + r][c];
      #pragma unroll
      for (int i2 = 0; i2 < 4; ++i2) a4[i2] = *(const float4*)&As[c + i2][tx * 4];
      float aa[4][4], bb[4][4];
      #pragma unroll
      for (int i2 = 0; i2 < 4; ++i2) {
        aa[i2][0] = a4[i2].x; aa[i2][1] = a4[i2].y;
        aa[i2][2] = a4[i2].z; aa[i2][3] = a4[i2].w;
      }
      #pragma unroll
      for (int r = 0; r < 4; ++r) {
        bb[r][0] = b4[r].x; bb[r][1] = b4[r].y;
        bb[r][2] = b4[r].z; bb[r][3] = b4[r].w;
      }
      #pragma unroll
      for (int i2 = 0; i2 < 4; ++i2)
        #pragma unroll
        for (int q = 0; q < 4; ++q)
          #pragma unroll
          for (int r = 0; r < 4; ++r)
            acc[q][r] = fmaf(aa[i2][q], bb[r][i2], acc[q][r]);
    }
    __syncthreads();                       // GEMM reads of Bs done
    #pragma unroll
    for (int q = 0; q < 4; ++q) {
      int r_ = tx * 4 + q;
      int f  = tx & 3;
      #pragma unroll
      for (int r2 = 0; r2 < 4; ++r2)
        ScB[r_ * 65 + ((ty * 4 + r2 + f) & 63)] = acc[q][r2];
    }
    __syncthreads();
    {
      int f = (row >> 2) & 3;
      #pragma unroll
      for (int m2 = 0; m2 < 16; ++m2) {
        int mm = chk * 16 + m2;
        float key = 2.f * ScB[row * 65 + ((mm + f) & 63)] - sqA - ssB[mm];
        ins10k(L, mkkey(key, m0 + mm));
      }
    }
    __syncthreads();                       // Sc reads done before next B fill
  }

  unsigned* mgH = (unsigned*)&As[0][0];
  unsigned* mgL = (unsigned*)&Bs[0][0];
  #pragma unroll
  for (int j = 0; j < 10; ++j) {
    mgH[(row * 4 + chk) * 10 + j] = (unsigned)(L[j] >> 32);
    mgL[(row * 4 + chk) * 10 + j] = (unsigned)L[j];
  }
  __syncthreads();
  if (t < 64) {
    u64 F[10];
    #pragma unroll
    for (int j = 0; j < 10; ++j) F[j] = KSENT;
    for (int c2 = 0; c2 < 4; ++c2)
      for (int j = 0; j < 10; ++j) {
        int s = (t * 4 + c2) * 10 + j;
        ins10k(F, ((u64)mgH[s] << 32) | mgL[s]);
      }
    size_t base = (size_t)(b * 2048 + p0 + t) * 40 + cc * 10;
    #pragma unroll
    for (int j = 0; j < 10; ++j) pk[base + j] = F[j];
  }
}

// ---------- merge 4 partial top-10 key lists -> final idx ----------
__global__ __launch_bounds__(256)
void k_kmerge(const u64* __restrict__ pk, int* __restrict__ idxout){
  int row = blockIdx.x * 256 + threadIdx.x;    // 16384
  u64 F[10];
  #pragma unroll
  for (int j = 0; j < 10; ++j) F[j] = KSENT;
  size_t base = (size_t)row * 40;
  for (int e = 0; e < 40; ++e) ins10k(F, pk[base + e]);
  #pragma unroll
  for (int j = 0; j < 10; ++j) idxout[(size_t)row * 10 + j] = keyidx(F[j]);
}

// ---------- UV for stage 1 (C=3): elementwise ----------
__global__ __launch_bounds__(256)
void k_uv3(const float* __restrict__ xf, const float* __restrict__ w1,
           const float* __restrict__ gg, const float* __restrict__ vv,
           float* __restrict__ UV){
  int i = blockIdx.x * 256 + threadIdx.x;      // 4096 blocks
  int p = i >> 6, o = i & 63;
  float s = gg[o] / sqrtf(vv[o] + BN_EPS);
  float x0 = xf[(size_t)p * 3], x1 = xf[(size_t)p * 3 + 1], x2 = xf[(size_t)p * 3 + 2];
  const float* wr = w1 + o * 6;
  float u = s * (wr[0] * x0 + wr[1] * x1 + wr[2] * x2);
  float v = s * ((wr[3] - wr[0]) * x0 + (wr[4] - wr[1]) * x1 + (wr[5] - wr[2]) * x2);
  UV[(size_t)p * 128 + o] = u;
  UV[(size_t)p * 128 + 64 + o] = v;
}

// ---------- UV for stages 2/3 (C=64): tiled GEMM, s1 folded ----------
__global__ __launch_bounds__(256)
void k_uv(const float* __restrict__ A, int lda, int aoff,
          const float* __restrict__ w,       // [64][128]
          const float* __restrict__ gg, const float* __restrict__ vv,
          float* __restrict__ UV){
  __shared__ float As[16][68];
  __shared__ float Bs[16][68];
  __shared__ float ss[64];
  const int t = threadIdx.x;
  const int tx = t & 15, ty = t >> 4;
  const int m0 = blockIdx.x * 64;
  const int half = blockIdx.y;
  if (t < 64) ss[t] = gg[t] / sqrtf(vv[t] + BN_EPS);
  __syncthreads();
  float acc[4][4] = {};
  for (int k0 = 0; k0 < 64; k0 += 16) {
    for (int i = t; i < 1024; i += 256) {
      int m = i >> 4, k = i & 15;
      As[k][m] = A[(size_t)(m0 + m) * lda + aoff + k0 + k];
    }
    for (int i = t; i < 1024; i += 256) {
      int n = i >> 4, k = i & 15;
      int kk = k0 + k;
      float wv = half ? (w[n * 128 + 64 + kk] - w[n * 128 + kk]) : w[n * 128 + kk];
      Bs[k][n] = wv * ss[n];
    }
    __syncthreads();
    #pragma unroll
    for (int k = 0; k < 16; ++k) {
      float4 a4 = *(const float4*)&As[k][tx * 4];
      float4 b4 = *(const float4*)&Bs[k][ty * 4];
      float am[4] = {a4.x, a4.y, a4.z, a4.w};
      float bm[4] = {b4.x, b4.y, b4.z, b4.w};
      #pragma unroll
      for (int q = 0; q < 4; ++q)
        #pragma unroll
        for (int r = 0; r < 4; ++r)
          acc[q][r] = fmaf(am[q], bm[r], acc[q][r]);
    }
    __syncthreads();
  }
  #pragma unroll
  for (int q = 0; q < 4; ++q)
    #pragma unroll
    for (int r = 0; r < 4; ++r)
      UV[(size_t)(m0 + tx * 4 + q) * 128 + half * 64 + ty * 4 + r] = acc[q][r];
}

// ---------- edge stage with conv2 ----------
__global__ __launch_bounds__(256)
void k_edge2(const float* __restrict__ UV, const int* __restrict__ idx,
             const float* __restrict__ w2,   // [64][64]
             const float* __restrict__ g1, const float* __restrict__ b1,
             const float* __restrict__ m1, const float* __restrict__ v1,
             const float* __restrict__ g2, const float* __restrict__ b2,
             const float* __restrict__ m2, const float* __restrict__ v2,
             float* __restrict__ cat, int coff){
  __shared__ float Ha[64][161];
  __shared__ float Ws[64][68];
  __shared__ float o1s[64], s2s[64], o2s[64];
  __shared__ int   ejs[160];
  const int t = threadIdx.x;
  const int p0 = blockIdx.x * 16;
  const int batch = p0 >> 11;
  if (t < 160) ejs[t] = batch * 2048 + (idx[p0 * 10 + t] & 2047);
  if (t < 64) {
    float s1 = g1[t] / sqrtf(v1[t] + BN_EPS);
    o1s[t] = b1[t] - m1[t] * s1;
    float s2 = g2[t] / sqrtf(v2[t] + BN_EPS);
    s2s[t] = s2;
    o2s[t] = b2[t] - m2[t] * s2;
  }
  for (int i = t; i < 4096; i += 256) {
    int k = i & 63, n = i >> 6;
    Ws[k][n] = w2[n * 64 + k];
  }
  __syncthreads();

  for (int i = t; i < 10240; i += 256) {
    int e = i >> 6, c = i & 63;
    int p = p0 + e / 10;
    float hv = UV[(size_t)ejs[e] * 128 + c] + UV[(size_t)p * 128 + 64 + c] + o1s[c];
    Ha[c][e] = mishf(hv);
  }
  __syncthreads();

  const int tx = t & 31, tq = t >> 5;
  float acc[5][8] = {};
  #pragma unroll 8
  for (int k = 0; k < 64; ++k) {
    float av[5];
    #pragma unroll
    for (int i2 = 0; i2 < 5; ++i2) av[i2] = Ha[k][tx * 5 + i2];
    float4 bq0 = *(const float4*)&Ws[k][tq * 8];
    float4 bq1 = *(const float4*)&Ws[k][tq * 8 + 4];
    float bv[8] = {bq0.x, bq0.y, bq0.z, bq0.w, bq1.x, bq1.y, bq1.z, bq1.w};
    #pragma unroll
    for (int i2 = 0; i2 < 5; ++i2)
      #pragma unroll
      for (int r = 0; r < 8; ++r)
        acc[i2][r] = fmaf(av[i2], bv[r], acc[i2][r]);
  }
  __syncthreads();
  #pragma unroll
  for (int i2 = 0; i2 < 5; ++i2)
    #pragma unroll
    for (int r = 0; r < 8; ++r) {
      int o = tq * 8 + r;
      Ha[o][tx * 5 + i2] = mishf(acc[i2][r] * s2s[o] + o2s[o]);
    }
  __syncthreads();

  for (int i = t; i < 1024; i += 256) {
    int p = i >> 6, o = i & 63;
    float mx = Ha[o][p * 10];
    #pragma unroll
    for (int k = 1; k < 10; ++k) mx = fmaxf(mx, Ha[o][p * 10 + k]);
    cat[(size_t)(p0 + p) * 192 + coff + o] = mx;
  }
}

// ---------- edge stage 3 (no conv2) ----------
__global__ __launch_bounds__(256)
void k_edge3(const float* __restrict__ UV, const int* __restrict__ idx,
             const float* __restrict__ gg, const float* __restrict__ bb,
             const float* __restrict__ mn, const float* __restrict__ vv,
             float* __restrict__ cat){
  int i = blockIdx.x * 256 + threadIdx.x;      // 4096 blocks
  int p = i >> 6, o = i & 63;
  int batch = p >> 11;
  float s = gg[o] / sqrtf(vv[o] + BN_EPS);
  float of = bb[o] - mn[o] * s;
  float v_ = UV[(size_t)p * 128 + 64 + o] + of;
  float mx = -INFINITY;
  #pragma unroll
  for (int k = 0; k < 10; ++k) {
    int j = batch * 2048 + (idx[p * 10 + k] & 2047);
    mx = fmaxf(mx, mishf(UV[(size_t)j * 128 + o] + v_));
  }
  cat[(size_t)p * 192 + 128 + o] = mx;
}

// ---------- tiled fp32 GEMM head ----------
#define EP_BNMISH      0
#define EP_MAXGLOB     1
#define EP_BIAS_BNMISH 2

template<int EPI>
__global__ __launch_bounds__(256)
void k_gemm(const float* __restrict__ A, int lda,
            const float* __restrict__ W, int ldw, int K,
            const float* __restrict__ gg, const float* __restrict__ bb,
            const float* __restrict__ mn, const float* __restrict__ vv,
            const float* __restrict__ bias,
            float* __restrict__ out, int ldo,
            unsigned* __restrict__ glob)
{
  __shared__ float As[16][68];
  __shared__ float Bs[16][68];
  const int t  = threadIdx.x;
  const int tx = t & 15, ty = t >> 4;
  const int m0 = blockIdx.x * 64, n0 = blockIdx.y * 64;
  const int lm = t >> 2, lk = (t & 3) * 4;
  float acc[4][4] = {};

  for (int k0 = 0; k0 < K; k0 += 16) {
    float4 a4 = *(const float4*)&A[(size_t)(m0 + lm) * lda + k0 + lk];
    float4 b4 = *(const float4*)&W[(size_t)(n0 + lm) * ldw + k0 + lk];
    As[lk][lm] = a4.x; As[lk+1][lm] = a4.y; As[lk+2][lm] = a4.z; As[lk+3][lm] = a4.w;
    Bs[lk][lm] = b4.x; Bs[lk+1][lm] = b4.y; Bs[lk+2][lm] = b4.z; Bs[lk+3][lm] = b4.w;
    __syncthreads();
    #pragma unroll
    for (int k = 0; k < 16; ++k) {
      float4 av4 = *(const float4*)&As[k][tx * 4];
      float4 bv4 = *(const float4*)&Bs[k][ty * 4];
      float am[4] = {av4.x, av4.y, av4.z, av4.w};
      float bm[4] = {bv4.x, bv4.y, bv4.z, bv4.w};
      #pragma unroll
      for (int i2 = 0; i2 < 4; ++i2)
        #pragma unroll
        for (int j = 0; j < 4; ++j)
          acc[i2][j] = fmaf(am[i2], bm[j], acc[i2][j]);
    }
    __syncthreads();
  }

  float sc[4], of[4];
  #pragma unroll
  for (int j = 0; j < 4; ++j) {
    int nn = n0 + ty * 4 + j;
    float s = gg[nn] / sqrtf(vv[nn] + BN_EPS);
    sc[j] = s;
    of[j] = bb[nn] - mn[nn] * s;
  }

  if (EPI == EP_MAXGLOB) {
    float mx[4] = {-INFINITY, -INFINITY, -INFINITY, -INFINITY};
    #pragma unroll
    for (int i2 = 0; i2 < 4; ++i2)
      #pragma unroll
      for (int j = 0; j < 4; ++j)
        mx[j] = fmaxf(mx[j], mishf(acc[i2][j] * sc[j] + of[j]));
    __syncthreads();
    float* red = &As[0][0];
    #pragma unroll
    for (int j = 0; j < 4; ++j) red[(ty * 4 + j) * 16 + tx] = mx[j];
    __syncthreads();
    if (t < 64) {
      float v = red[t * 16];
      #pragma unroll
      for (int r = 1; r < 16; ++r) v = fmaxf(v, red[t * 16 + r]);
      atomicMax(&glob[(m0 >> 11) * 1024 + n0 + t], fenc(v));
    }
  } else {
    #pragma unroll
    for (int i2 = 0; i2 < 4; ++i2) {
      int m = m0 + tx * 4 + i2;
      #pragma unroll
      for (int j = 0; j < 4; ++j) {
        int nn = n0 + ty * 4 + j;
        float v = acc[i2][j];
        if (EPI == EP_BIAS_BNMISH) v += bias[(m >> 11) * 512 + nn];
        out[(size_t)m * ldo + nn] = mishf(v * sc[j] + of[j]);
      }
    }
  }
}

// ---------- t7[b][o] = w7[o, :1024] . glob[b] ----------
__global__ __launch_bounds__(256)
void k_t7(const unsigned* __restrict__ glob, const float* __restrict__ w7,
          float* __restrict__ t7){
  int i = blockIdx.x * 256 + threadIdx.x;      // 4096
  int b = i >> 9, o = i & 511;
  float acc = 0.f;
  for (int c = 0; c < 1024; ++c)
    acc = fmaf(w7[(size_t)o * 1216 + c], fdec(glob[b * 1024 + c]), acc);
  t7[i] = acc;
}

// ---------- final conv ----------
__global__ __launch_bounds__(256)
void k_out(const float* __restrict__ h8, const float* __restrict__ w9,
           float* __restrict__ out)
{
  __shared__ float row[4][256];
  const int t = threadIdx.x;
  const int g = t >> 6, l = t & 63;
  const int p = blockIdx.x * 4 + g;            // 4096 blocks
  for (int c = l; c < 256; c += 64)
    row[g][c] = h8[(size_t)p * 256 + c];
  __syncthreads();
  if (l < 18) {
    float acc = 0.f;
    for (int c = 0; c < 256; ++c)
      acc = fmaf(row[g][c], w9[l * 256 + c], acc);
    int b = p >> 11, n = p & 2047;
    out[(size_t)b * 36864 + l * 2048 + n] = acc;
  }
}

extern "C" void kernel_launch(void* const* d_in, const int* in_sizes, int n_in,
                              void* d_out, int out_size, void* d_ws, size_t ws_size,
                              hipStream_t stream)
{
  const size_t OFF_XF   = 0;
  const size_t OFF_IDX  = 262144;
  const size_t OFF_CAT  = 917504;
  const size_t OFF_GLOB = 13500416;
  const size_t OFF_T7   = 13533184;
  const size_t OFF_H7   = 13549568;            // h7; UV aliases first 8.4MB
  const size_t OFF_H8   = 47104000;            // h8; sq/pk alias (knn phase)
  const size_t NEED     = 63881216;

  static const int EXP[26] = {
    49152, 384, 4096, 8192, 4096, 8192, 196608, 622592, 131072, 4608,
    320, 320, 320, 320, 1024, 1024, 1024, 1024,
    512, 512, 512, 512, 256, 256, 256, 256 };
  if (n_in < 26) { k_diag<<<1,1,0,stream>>>((float*)d_out, 16384.f); return; }
  for (int i = 0; i < 26; ++i)
    if (in_sizes[i] != EXP[i]) {
      k_diag<<<1,1,0,stream>>>((float*)d_out, 4096.f + 128.f * i); return;
    }
  if (out_size != 294912) { k_diag<<<1,1,0,stream>>>((float*)d_out, 20480.f); return; }
  if (ws_size < NEED) {
    k_diag<<<1,1,0,stream>>>((float*)d_out, 24576.f + (float)(ws_size >> 20)); return;
  }

  const float* x  = (const float*)d_in[0];
  const float* w1 = (const float*)d_in[1];
  const float* w2 = (const float*)d_in[2];
  const float* w3 = (const float*)d_in[3];
  const float* w4 = (const float*)d_in[4];
  const float* w5 = (const float*)d_in[5];
  const float* w6 = (const float*)d_in[6];
  const float* w7 = (const float*)d_in[7];
  const float* w8 = (const float*)d_in[8];
  const float* w9 = (const float*)d_in[9];
  const float* g15 = (const float*)d_in[10];
  const float* b15 = (const float*)d_in[11];
  const float* m15 = (const float*)d_in[12];
  const float* v15 = (const float*)d_in[13];
  const float* g6 = (const float*)d_in[14];
  const float* b6 = (const float*)d_in[15];
  const float* m6 = (const float*)d_in[16];
  const float* v6 = (const float*)d_in[17];
  const float* g7 = (const float*)d_in[18];
  const float* b7 = (const float*)d_in[19];
  const float* m7 = (const float*)d_in[20];
  const float* v7 = (const float*)d_in[21];
  const float* g8 = (const float*)d_in[22];
  const float* b8 = (const float*)d_in[23];
  const float* m8 = (const float*)d_in[24];
  const float* v8 = (const float*)d_in[25];

  char* ws = (char*)d_ws;
  float*    xf   = (float*)(ws + OFF_XF);
  int*      idx  = (int*)(ws + OFF_IDX);
  float*    cat  = (float*)(ws + OFF_CAT);
  unsigned* glob = (unsigned*)(ws + OFF_GLOB);
  float*    t7   = (float*)(ws + OFF_T7);
  float*    h7   = (float*)(ws + OFF_H7);
  float*    UV   = (float*)(ws + OFF_H7);
  float*    h8   = (float*)(ws + OFF_H8);
  float*    sq   = (float*)(ws + OFF_H8);              //    65,536 [16384]
  u64*      pk   = (u64*)(ws + OFF_H8 + 65536);        // 5,242,880 [16384][40]

  k_cast<<<192, 256, 0, stream>>>(x, xf);

  // ---- stage 1 ----
  k_knn3<<<512, 256, 0, stream>>>(xf, idx);
  k_uv3<<<4096, 256, 0, stream>>>(xf, w1, g15 + 0, v15 + 0, UV);
  k_edge2<<<1024, 256, 0, stream>>>(UV, idx, w2,
      g15 + 0,  b15 + 0,  m15 + 0,  v15 + 0,
      g15 + 64, b15 + 64, m15 + 64, v15 + 64, cat, 0);

  // ---- stage 2 ----
  k_norm<64><<<64, 256, 0, stream>>>(cat, 192, 0, sq);
  k_knn2p<<<1024, 256, 0, stream>>>(cat, 192, 0, sq, pk);
  k_kmerge<<<64, 256, 0, stream>>>(pk, idx);
  dim3 guv(256, 2);
  k_uv<<<guv, 256, 0, stream>>>(cat, 192, 0, w3, g15 + 128, v15 + 128, UV);
  k_edge2<<<1024, 256, 0, stream>>>(UV, idx, w4,
      g15 + 128, b15 + 128, m15 + 128, v15 + 128,
      g15 + 192, b15 + 192, m15 + 192, v15 + 192, cat, 64);

  // ---- stage 3 ----
  k_norm<64><<<64, 256, 0, stream>>>(cat, 192, 64, sq);
  k_knn2p<<<1024, 256, 0, stream>>>(cat, 192, 64, sq, pk);
  k_kmerge<<<64, 256, 0, stream>>>(pk, idx);
  k_uv<<<guv, 256, 0, stream>>>(cat, 192, 64, w5, g15 + 256, v15 + 256, UV);
  k_edge3<<<4096, 256, 0, stream>>>(UV, idx,
      g15 + 256, b15 + 256, m15 + 256, v15 + 256, cat);

  // ---- head ----
  k_zero<<<32, 256, 0, stream>>>(glob);
  dim3 g6g(256, 16);
  k_gemm<EP_MAXGLOB><<<g6g, 256, 0, stream>>>(
      cat, 192, w6, 192, 192, g6, b6, m6, v6, nullptr, nullptr, 0, glob);
  k_t7<<<16, 256, 0, stream>>>(glob, w7, t7);
  dim3 g7g(256, 8);
  k_gemm<EP_BIAS_BNMISH><<<g7g, 256, 0, stream>>>(
      cat, 192, w7 + 1024, 1216, 192, g7, b7, m7, v7, t7, h7, 512, nullptr);
  dim3 g8g(256, 4);
  k_gemm<EP_BNMISH><<<g8g, 256, 0, stream>>>(
      h7, 512, w8, 512, 512, g8, b8, m8, v8, nullptr, h8, 256, nullptr);
  k_out<<<4096, 256, 0, stream>>>(h8, w9, (float*)d_out);
}

// Round 12
// 903.282 us; speedup vs baseline: 2.2102x; 1.3168x over previous
//
#include <hip/hip_runtime.h>
#include <math.h>

#define BN_EPS 1e-5f
typedef unsigned long long u64;

// mish(x) = x*tanh(ln(1+e^x)) = x*w/(w+2), w = u(u+2), u = e^x.
// Clamp x<=20: at 20, ratio deviates ~1e-17. One v_exp + fma + div.
__device__ __forceinline__ float mishf(float x){
  float u = __expf(fminf(x, 20.f));
  float w = u * (u + 2.f);
  return x * w / (w + 2.f);
}

__device__ __forceinline__ unsigned fenc(float f){
  unsigned u = __float_as_uint(f);
  return (u & 0x80000000u) ? ~u : (u | 0x80000000u);
}
__device__ __forceinline__ float fdec(unsigned e){
  unsigned u = (e & 0x80000000u) ? (e & 0x7fffffffu) : ~e;
  return __uint_as_float(u);
}

// packed key: (value desc, index asc) == lax.top_k order as single u64 compare
__device__ __forceinline__ u64 mkkey(float v, int i){
  return ((u64)fenc(v) << 32) | (unsigned)(~i);
}
__device__ __forceinline__ int keyidx(u64 k){ return (int)(~(unsigned)k); }

__device__ __forceinline__ void ins10k(u64 (&L)[10], u64 k){
  if (k <= L[9]) return;
  #pragma unroll
  for (int p = 9; p >= 1; --p)
    L[p] = (k > L[p-1]) ? L[p-1] : ((k > L[p]) ? k : L[p]);
  L[0] = (k > L[0]) ? k : L[0];
}
#define KSENT mkkey(-INFINITY, 0x7fffffff)

__global__ void k_diag(float* __restrict__ out, float v){ out[0] = v; }

// ---------- transpose x [B,3,N] -> xf [B*N,3] ----------
__global__ __launch_bounds__(256)
void k_cast(const float* __restrict__ x, float* __restrict__ xf){
  int i = blockIdx.x * 256 + threadIdx.x;      // 49152
  int n = i & 2047, c = (i >> 11) % 3, b = i / (3 * 2048);
  xf[(size_t)(b * 2048 + n) * 3 + c] = x[i];
}

__global__ __launch_bounds__(256)
void k_zero(unsigned* __restrict__ p){
  p[blockIdx.x * 256 + threadIdx.x] = 0u;      // 32 blocks -> 8192
}

// ---------- squared norm per point ----------
template<int C>
__global__ __launch_bounds__(256)
void k_norm(const float* __restrict__ src, int stride, int off,
            float* __restrict__ sq){
  int i = blockIdx.x * 256 + threadIdx.x;      // 16384
  const float* r = src + (size_t)i * stride + off;
  float s = 0.f;
  #pragma unroll
  for (int c = 0; c < C; ++c) s = fmaf(r[c], r[c], s);
  sq[i] = s;
}

// ---------- knn C=3: 32 points/block, 8 chunk-threads/point ----------
__global__ __launch_bounds__(256)
void k_knn3(const float* __restrict__ src, int* __restrict__ idxout){
  constexpr int C = 3, PAD = 4;
  __shared__ float pts[128 * PAD];
  __shared__ float ss[128];
  __shared__ unsigned mH[32 * 8 * 10];
  __shared__ unsigned mL[32 * 8 * 10];
  const int t  = threadIdx.x;
  const int b  = blockIdx.x >> 6;
  const int p0 = (blockIdx.x & 63) * 32;
  const int p  = t >> 3, ch = t & 7;
  const float* srow = src + (size_t)(b * 2048 + p0 + p) * C;
  float own[C];
  #pragma unroll
  for (int c = 0; c < C; ++c) own[c] = srow[c];
  float sown = 0.f;
  #pragma unroll
  for (int c = 0; c < C; ++c) sown = fmaf(own[c], own[c], sown);
  u64 L[10];
  #pragma unroll
  for (int j = 0; j < 10; ++j) L[j] = KSENT;

  for (int m0 = 0; m0 < 2048; m0 += 128) {
    __syncthreads();
    for (int i = t; i < 128 * C; i += 256) {
      int mm = i / C, c = i % C;
      pts[mm * PAD + c] = src[(size_t)(b * 2048 + m0 + mm) * C + c];
    }
    __syncthreads();
    if (t < 128) {
      float s2 = 0.f;
      #pragma unroll
      for (int c = 0; c < C; ++c) s2 = fmaf(pts[t * PAD + c], pts[t * PAD + c], s2);
      ss[t] = s2;
    }
    __syncthreads();
    for (int mm = ch; mm < 128; mm += 8) {
      float dot = 0.f;
      #pragma unroll
      for (int c = 0; c < C; ++c) dot = fmaf(own[c], pts[mm * PAD + c], dot);
      ins10k(L, mkkey(2.f * dot - sown - ss[mm], m0 + mm));
    }
  }
  __syncthreads();
  #pragma unroll
  for (int j = 0; j < 10; ++j) {
    mH[t * 10 + j] = (unsigned)(L[j] >> 32);
    mL[t * 10 + j] = (unsigned)L[j];
  }
  __syncthreads();
  if (t < 32) {
    u64 F[10];
    #pragma unroll
    for (int j = 0; j < 10; ++j) F[j] = KSENT;
    for (int c2 = 0; c2 < 8; ++c2)
      for (int j = 0; j < 10; ++j) {
        int s = (t * 8 + c2) * 10 + j;
        ins10k(F, ((u64)mH[s] << 32) | mL[s]);
      }
    #pragma unroll
    for (int j = 0; j < 10; ++j)
      idxout[(size_t)(b * 2048 + p0 + t) * 10 + j] = keyidx(F[j]);
  }
}

// ---------- knn C=64 partial: 64 rows x 512 cands/block, grid 1024 ----------
__global__ __launch_bounds__(256)
void k_knn2p(const float* __restrict__ src, int stride, int off,
             const float* __restrict__ sq, u64* __restrict__ pk){
  __shared__ float As[64][68];   // [ch][row]
  __shared__ float Bs[64][68];   // [cand][ch]; aliased as Sc + mgL
  __shared__ float ssB[64];
  float* ScB = &Bs[0][0];
  const int t  = threadIdx.x;
  const int bx = blockIdx.x;
  const int cc = bx & 3;
  const int rg = (bx >> 2) & 31;
  const int b  = bx >> 7;
  const int p0 = rg * 64;
  const int c0 = cc * 512;
  const int tx = t & 15, ty = t >> 4;
  const int row = t & 63, chk = t >> 6;

  #pragma unroll
  for (int pass = 0; pass < 4; ++pass) {
    int i = pass * 256 + t;
    int r_ = i >> 4, c4 = (i & 15) * 4;
    float4 v = *(const float4*)&src[(size_t)(b * 2048 + p0 + r_) * stride + off + c4];
    As[c4    ][r_] = v.x;
    As[c4 + 1][r_] = v.y;
    As[c4 + 2][r_] = v.z;
    As[c4 + 3][r_] = v.w;
  }
  float sqA = sq[b * 2048 + p0 + row];
  u64 L[10];
  #pragma unroll
  for (int j = 0; j < 10; ++j) L[j] = KSENT;

  for (int m0 = c0; m0 < c0 + 512; m0 += 64) {
    #pragma unroll
    for (int pass = 0; pass < 4; ++pass) {
      int i = pass * 256 + t;
      int j_ = i >> 4, c4 = (i & 15) * 4;
      *(float4*)&Bs[j_][c4] =
          *(const float4*)&src[(size_t)(b * 2048 + m0 + j_) * stride + off + c4];
    }
    if (t < 64) ssB[t] = sq[b * 2048 + m0 + t];
    __syncthreads();

    float acc[4][4] = {};
    #pragma unroll
    for (int c = 0; c < 64; c += 4) {
      float4 b4[4], a4[4];
      #pragma unroll
      for (int r = 0; r < 4; ++r) b4[r] = *(const float4*)&Bs[ty * 4 + r][c];
      #pragma unroll
      for (int i2 = 0; i2 < 4; ++i2) a4[i2] = *(const float4*)&As[c + i2][tx * 4];
      float aa[4][4], bb[4][4];
      #pragma unroll
      for (int i2 = 0; i2 < 4; ++i2) {
        aa[i2][0] = a4[i2].x; aa[i2][1] = a4[i2].y;
        aa[i2][2] = a4[i2].z; aa[i2][3] = a4[i2].w;
      }
      #pragma unroll
      for (int r = 0; r < 4; ++r) {
        bb[r][0] = b4[r].x; bb[r][1] = b4[r].y;
        bb[r][2] = b4[r].z; bb[r][3] = b4[r].w;
      }
      #pragma unroll
      for (int i2 = 0; i2 < 4; ++i2)
        #pragma unroll
        for (int q = 0; q < 4; ++q)
          #pragma unroll
          for (int r = 0; r < 4; ++r)
            acc[q][r] = fmaf(aa[i2][q], bb[r][i2], acc[q][r]);
    }
    __syncthreads();
    #pragma unroll
    for (int q = 0; q < 4; ++q) {
      int r_ = tx * 4 + q;
      int f  = tx & 3;
      #pragma unroll
      for (int r2 = 0; r2 < 4; ++r2)
        ScB[r_ * 65 + ((ty * 4 + r2 + f) & 63)] = acc[q][r2];
    }
    __syncthreads();
    {
      int f = (row >> 2) & 3;
      #pragma unroll
      for (int m2 = 0; m2 < 16; ++m2) {
        int mm = chk * 16 + m2;
        float key = 2.f * ScB[row * 65 + ((mm + f) & 63)] - sqA - ssB[mm];
        ins10k(L, mkkey(key, m0 + mm));
      }
    }
    __syncthreads();
  }

  unsigned* mgH = (unsigned*)&As[0][0];
  unsigned* mgL = (unsigned*)&Bs[0][0];
  #pragma unroll
  for (int j = 0; j < 10; ++j) {
    mgH[(row * 4 + chk) * 10 + j] = (unsigned)(L[j] >> 32);
    mgL[(row * 4 + chk) * 10 + j] = (unsigned)L[j];
  }
  __syncthreads();
  if (t < 64) {
    u64 F[10];
    #pragma unroll
    for (int j = 0; j < 10; ++j) F[j] = KSENT;
    for (int c2 = 0; c2 < 4; ++c2)
      for (int j = 0; j < 10; ++j) {
        int s = (t * 4 + c2) * 10 + j;
        ins10k(F, ((u64)mgH[s] << 32) | mgL[s]);
      }
    size_t base = (size_t)(b * 2048 + p0 + t) * 40 + cc * 10;
    #pragma unroll
    for (int j = 0; j < 10; ++j) pk[base + j] = F[j];
  }
}

// ---------- merge 4 partial top-10 key lists -> final idx ----------
__global__ __launch_bounds__(256)
void k_kmerge(const u64* __restrict__ pk, int* __restrict__ idxout){
  int row = blockIdx.x * 256 + threadIdx.x;    // 16384
  u64 F[10];
  #pragma unroll
  for (int j = 0; j < 10; ++j) F[j] = KSENT;
  size_t base = (size_t)row * 40;
  for (int e = 0; e < 40; ++e) ins10k(F, pk[base + e]);
  #pragma unroll
  for (int j = 0; j < 10; ++j) idxout[(size_t)row * 10 + j] = keyidx(F[j]);
}

// ---------- UV for stage 1 (C=3): elementwise ----------
__global__ __launch_bounds__(256)
void k_uv3(const float* __restrict__ xf, const float* __restrict__ w1,
           const float* __restrict__ gg, const float* __restrict__ vv,
           float* __restrict__ UV){
  int i = blockIdx.x * 256 + threadIdx.x;      // 4096 blocks
  int p = i >> 6, o = i & 63;
  float s = gg[o] / sqrtf(vv[o] + BN_EPS);
  float x0 = xf[(size_t)p * 3], x1 = xf[(size_t)p * 3 + 1], x2 = xf[(size_t)p * 3 + 2];
  const float* wr = w1 + o * 6;
  float u = s * (wr[0] * x0 + wr[1] * x1 + wr[2] * x2);
  float v = s * ((wr[3] - wr[0]) * x0 + (wr[4] - wr[1]) * x1 + (wr[5] - wr[2]) * x2);
  UV[(size_t)p * 128 + o] = u;
  UV[(size_t)p * 128 + 64 + o] = v;
}

// ---------- UV for stages 2/3 (C=64): tiled GEMM, s1 folded ----------
__global__ __launch_bounds__(256)
void k_uv(const float* __restrict__ A, int lda, int aoff,
          const float* __restrict__ w,       // [64][128]
          const float* __restrict__ gg, const float* __restrict__ vv,
          float* __restrict__ UV){
  __shared__ float As[16][68];
  __shared__ float Bs[16][68];
  __shared__ float ss[64];
  const int t = threadIdx.x;
  const int tx = t & 15, ty = t >> 4;
  const int m0 = blockIdx.x * 64;
  const int half = blockIdx.y;
  if (t < 64) ss[t] = gg[t] / sqrtf(vv[t] + BN_EPS);
  __syncthreads();
  float acc[4][4] = {};
  for (int k0 = 0; k0 < 64; k0 += 16) {
    for (int i = t; i < 1024; i += 256) {
      int m = i >> 4, k = i & 15;
      As[k][m] = A[(size_t)(m0 + m) * lda + aoff + k0 + k];
    }
    for (int i = t; i < 1024; i += 256) {
      int n = i >> 4, k = i & 15;
      int kk = k0 + k;
      float wv = half ? (w[n * 128 + 64 + kk] - w[n * 128 + kk]) : w[n * 128 + kk];
      Bs[k][n] = wv * ss[n];
    }
    __syncthreads();
    #pragma unroll
    for (int k = 0; k < 16; ++k) {
      float4 a4 = *(const float4*)&As[k][tx * 4];
      float4 b4 = *(const float4*)&Bs[k][ty * 4];
      float am[4] = {a4.x, a4.y, a4.z, a4.w};
      float bm[4] = {b4.x, b4.y, b4.z, b4.w};
      #pragma unroll
      for (int q = 0; q < 4; ++q)
        #pragma unroll
        for (int r = 0; r < 4; ++r)
          acc[q][r] = fmaf(am[q], bm[r], acc[q][r]);
    }
    __syncthreads();
  }
  #pragma unroll
  for (int q = 0; q < 4; ++q)
    #pragma unroll
    for (int r = 0; r < 4; ++r)
      UV[(size_t)(m0 + tx * 4 + q) * 128 + half * 64 + ty * 4 + r] = acc[q][r];
}

// ---------- edge stage with conv2: 8 points/block, grid 2048, LDS ~39KB ----------
__global__ __launch_bounds__(256)
void k_edge2(const float* __restrict__ UV, const int* __restrict__ idx,
             const float* __restrict__ w2,   // [64][64]
             const float* __restrict__ g1, const float* __restrict__ b1,
             const float* __restrict__ m1, const float* __restrict__ v1,
             const float* __restrict__ g2, const float* __restrict__ b2,
             const float* __restrict__ m2, const float* __restrict__ v2,
             float* __restrict__ cat, int coff){
  __shared__ float Ha[64][81];    // [ch][edge] then reused as [out][edge]
  __shared__ float Ws[64][68];    // [k][out]
  __shared__ float o1s[64], s2s[64], o2s[64];
  __shared__ int   ejs[80];
  const int t = threadIdx.x;
  const int p0 = blockIdx.x * 8;  // 2048 blocks
  const int batch = p0 >> 11;
  if (t < 80) ejs[t] = batch * 2048 + (idx[p0 * 10 + t] & 2047);
  if (t < 64) {
    float s1 = g1[t] / sqrtf(v1[t] + BN_EPS);
    o1s[t] = b1[t] - m1[t] * s1;
    float s2 = g2[t] / sqrtf(v2[t] + BN_EPS);
    s2s[t] = s2;
    o2s[t] = b2[t] - m2[t] * s2;
  }
  for (int i = t; i < 4096; i += 256) {
    int k = i & 63, n = i >> 6;
    Ws[k][n] = w2[n * 64 + k];
  }
  __syncthreads();

  // h1: 80 edges x 64 ch
  for (int i = t; i < 5120; i += 256) {
    int e = i >> 6, c = i & 63;
    int p = p0 + e / 10;
    float hv = UV[(size_t)ejs[e] * 128 + c] + UV[(size_t)p * 128 + 64 + c] + o1s[c];
    Ha[c][e] = mishf(hv);
  }
  __syncthreads();

  // conv2 GEMM: 80 edges x 64 outs, K=64; tx->5 edges, ty->4 outs
  const int tx = t & 15, ty = t >> 4;
  float acc[5][4] = {};
  #pragma unroll 8
  for (int k = 0; k < 64; ++k) {
    float av[5];
    #pragma unroll
    for (int i2 = 0; i2 < 5; ++i2) av[i2] = Ha[k][tx * 5 + i2];
    float4 b4 = *(const float4*)&Ws[k][ty * 4];
    float bv[4] = {b4.x, b4.y, b4.z, b4.w};
    #pragma unroll
    for (int i2 = 0; i2 < 5; ++i2)
      #pragma unroll
      for (int r = 0; r < 4; ++r)
        acc[i2][r] = fmaf(av[i2], bv[r], acc[i2][r]);
  }
  __syncthreads();
  #pragma unroll
  for (int i2 = 0; i2 < 5; ++i2)
    #pragma unroll
    for (int r = 0; r < 4; ++r) {
      int o = ty * 4 + r;
      Ha[o][tx * 5 + i2] = mishf(acc[i2][r] * s2s[o] + o2s[o]);
    }
  __syncthreads();

  // max over k=10 -> cat (8 points x 64 outs)
  for (int i = t; i < 512; i += 256) {
    int p = i >> 6, o = i & 63;
    float mx = Ha[o][p * 10];
    #pragma unroll
    for (int k = 1; k < 10; ++k) mx = fmaxf(mx, Ha[o][p * 10 + k]);
    cat[(size_t)(p0 + p) * 192 + coff + o] = mx;
  }
}

// ---------- edge stage 3 (no conv2) ----------
__global__ __launch_bounds__(256)
void k_edge3(const float* __restrict__ UV, const int* __restrict__ idx,
             const float* __restrict__ gg, const float* __restrict__ bb,
             const float* __restrict__ mn, const float* __restrict__ vv,
             float* __restrict__ cat){
  int i = blockIdx.x * 256 + threadIdx.x;      // 4096 blocks
  int p = i >> 6, o = i & 63;
  int batch = p >> 11;
  float s = gg[o] / sqrtf(vv[o] + BN_EPS);
  float of = bb[o] - mn[o] * s;
  float v_ = UV[(size_t)p * 128 + 64 + o] + of;
  float mx = -INFINITY;
  #pragma unroll
  for (int k = 0; k < 10; ++k) {
    int j = batch * 2048 + (idx[p * 10 + k] & 2047);
    mx = fmaxf(mx, mishf(UV[(size_t)j * 128 + o] + v_));
  }
  cat[(size_t)p * 192 + 128 + o] = mx;
}

// ---------- tiled fp32 GEMM head ----------
#define EP_BNMISH      0
#define EP_MAXGLOB     1
#define EP_BIAS_BNMISH 2

template<int EPI>
__global__ __launch_bounds__(256)
void k_gemm(const float* __restrict__ A, int lda,
            const float* __restrict__ W, int ldw, int K,
            const float* __restrict__ gg, const float* __restrict__ bb,
            const float* __restrict__ mn, const float* __restrict__ vv,
            const float* __restrict__ bias,
            float* __restrict__ out, int ldo,
            unsigned* __restrict__ glob)
{
  __shared__ float As[16][68];
  __shared__ float Bs[16][68];
  const int t  = threadIdx.x;
  const int tx = t & 15, ty = t >> 4;
  const int m0 = blockIdx.x * 64, n0 = blockIdx.y * 64;
  const int lm = t >> 2, lk = (t & 3) * 4;
  float acc[4][4] = {};

  for (int k0 = 0; k0 < K; k0 += 16) {
    float4 a4 = *(const float4*)&A[(size_t)(m0 + lm) * lda + k0 + lk];
    float4 b4 = *(const float4*)&W[(size_t)(n0 + lm) * ldw + k0 + lk];
    As[lk][lm] = a4.x; As[lk+1][lm] = a4.y; As[lk+2][lm] = a4.z; As[lk+3][lm] = a4.w;
    Bs[lk][lm] = b4.x; Bs[lk+1][lm] = b4.y; Bs[lk+2][lm] = b4.z; Bs[lk+3][lm] = b4.w;
    __syncthreads();
    #pragma unroll
    for (int k = 0; k < 16; ++k) {
      float4 av4 = *(const float4*)&As[k][tx * 4];
      float4 bv4 = *(const float4*)&Bs[k][ty * 4];
      float am[4] = {av4.x, av4.y, av4.z, av4.w};
      float bm[4] = {bv4.x, bv4.y, bv4.z, bv4.w};
      #pragma unroll
      for (int i2 = 0; i2 < 4; ++i2)
        #pragma unroll
        for (int j = 0; j < 4; ++j)
          acc[i2][j] = fmaf(am[i2], bm[j], acc[i2][j]);
    }
    __syncthreads();
  }

  float sc[4], of[4];
  #pragma unroll
  for (int j = 0; j < 4; ++j) {
    int nn = n0 + ty * 4 + j;
    float s = gg[nn] / sqrtf(vv[nn] + BN_EPS);
    sc[j] = s;
    of[j] = bb[nn] - mn[nn] * s;
  }

  if (EPI == EP_MAXGLOB) {
    float mx[4] = {-INFINITY, -INFINITY, -INFINITY, -INFINITY};
    #pragma unroll
    for (int i2 = 0; i2 < 4; ++i2)
      #pragma unroll
      for (int j = 0; j < 4; ++j)
        mx[j] = fmaxf(mx[j], mishf(acc[i2][j] * sc[j] + of[j]));
    __syncthreads();
    float* red = &As[0][0];
    #pragma unroll
    for (int j = 0; j < 4; ++j) red[(ty * 4 + j) * 16 + tx] = mx[j];
    __syncthreads();
    if (t < 64) {
      float v = red[t * 16];
      #pragma unroll
      for (int r = 1; r < 16; ++r) v = fmaxf(v, red[t * 16 + r]);
      atomicMax(&glob[(m0 >> 11) * 1024 + n0 + t], fenc(v));
    }
  } else {
    #pragma unroll
    for (int i2 = 0; i2 < 4; ++i2) {
      int m = m0 + tx * 4 + i2;
      #pragma unroll
      for (int j = 0; j < 4; ++j) {
        int nn = n0 + ty * 4 + j;
        float v = acc[i2][j];
        if (EPI == EP_BIAS_BNMISH) v += bias[(m >> 11) * 512 + nn];
        out[(size_t)m * ldo + nn] = mishf(v * sc[j] + of[j]);
      }
    }
  }
}

// ---------- t7[b][o] = w7[o, :1024] . glob[b] ----------
__global__ __launch_bounds__(256)
void k_t7(const unsigned* __restrict__ glob, const float* __restrict__ w7,
          float* __restrict__ t7){
  int i = blockIdx.x * 256 + threadIdx.x;      // 4096
  int b = i >> 9, o = i & 511;
  float acc = 0.f;
  for (int c = 0; c < 1024; ++c)
    acc = fmaf(w7[(size_t)o * 1216 + c], fdec(glob[b * 1024 + c]), acc);
  t7[i] = acc;
}

// ---------- final conv ----------
__global__ __launch_bounds__(256)
void k_out(const float* __restrict__ h8, const float* __restrict__ w9,
           float* __restrict__ out)
{
  __shared__ float row[4][256];
  const int t = threadIdx.x;
  const int g = t >> 6, l = t & 63;
  const int p = blockIdx.x * 4 + g;            // 4096 blocks
  for (int c = l; c < 256; c += 64)
    row[g][c] = h8[(size_t)p * 256 + c];
  __syncthreads();
  if (l < 18) {
    float acc = 0.f;
    for (int c = 0; c < 256; ++c)
      acc = fmaf(row[g][c], w9[l * 256 + c], acc);
    int b = p >> 11, n = p & 2047;
    out[(size_t)b * 36864 + l * 2048 + n] = acc;
  }
}

extern "C" void kernel_launch(void* const* d_in, const int* in_sizes, int n_in,
                              void* d_out, int out_size, void* d_ws, size_t ws_size,
                              hipStream_t stream)
{
  const size_t OFF_XF   = 0;
  const size_t OFF_IDX  = 262144;
  const size_t OFF_CAT  = 917504;
  const size_t OFF_GLOB = 13500416;
  const size_t OFF_T7   = 13533184;
  const size_t OFF_H7   = 13549568;            // h7; UV aliases first 8.4MB
  const size_t OFF_H8   = 47104000;            // h8; sq/pk alias (knn phase)
  const size_t NEED     = 63881216;

  static const int EXP[26] = {
    49152, 384, 4096, 8192, 4096, 8192, 196608, 622592, 131072, 4608,
    320, 320, 320, 320, 1024, 1024, 1024, 1024,
    512, 512, 512, 512, 256, 256, 256, 256 };
  if (n_in < 26) { k_diag<<<1,1,0,stream>>>((float*)d_out, 16384.f); return; }
  for (int i = 0; i < 26; ++i)
    if (in_sizes[i] != EXP[i]) {
      k_diag<<<1,1,0,stream>>>((float*)d_out, 4096.f + 128.f * i); return;
    }
  if (out_size != 294912) { k_diag<<<1,1,0,stream>>>((float*)d_out, 20480.f); return; }
  if (ws_size < NEED) {
    k_diag<<<1,1,0,stream>>>((float*)d_out, 24576.f + (float)(ws_size >> 20)); return;
  }

  const float* x  = (const float*)d_in[0];
  const float* w1 = (const float*)d_in[1];
  const float* w2 = (const float*)d_in[2];
  const float* w3 = (const float*)d_in[3];
  const float* w4 = (const float*)d_in[4];
  const float* w5 = (const float*)d_in[5];
  const float* w6 = (const float*)d_in[6];
  const float* w7 = (const float*)d_in[7];
  const float* w8 = (const float*)d_in[8];
  const float* w9 = (const float*)d_in[9];
  const float* g15 = (const float*)d_in[10];
  const float* b15 = (const float*)d_in[11];
  const float* m15 = (const float*)d_in[12];
  const float* v15 = (const float*)d_in[13];
  const float* g6 = (const float*)d_in[14];
  const float* b6 = (const float*)d_in[15];
  const float* m6 = (const float*)d_in[16];
  const float* v6 = (const float*)d_in[17];
  const float* g7 = (const float*)d_in[18];
  const float* b7 = (const float*)d_in[19];
  const float* m7 = (const float*)d_in[20];
  const float* v7 = (const float*)d_in[21];
  const float* g8 = (const float*)d_in[22];
  const float* b8 = (const float*)d_in[23];
  const float* m8 = (const float*)d_in[24];
  const float* v8 = (const float*)d_in[25];

  char* ws = (char*)d_ws;
  float*    xf   = (float*)(ws + OFF_XF);
  int*      idx  = (int*)(ws + OFF_IDX);
  float*    cat  = (float*)(ws + OFF_CAT);
  unsigned* glob = (unsigned*)(ws + OFF_GLOB);
  float*    t7   = (float*)(ws + OFF_T7);
  float*    h7   = (float*)(ws + OFF_H7);
  float*    UV   = (float*)(ws + OFF_H7);
  float*    h8   = (float*)(ws + OFF_H8);
  float*    sq   = (float*)(ws + OFF_H8);              //    65,536 [16384]
  u64*      pk   = (u64*)(ws + OFF_H8 + 65536);        // 5,242,880 [16384][40]

  k_cast<<<192, 256, 0, stream>>>(x, xf);

  // ---- stage 1 ----
  k_knn3<<<512, 256, 0, stream>>>(xf, idx);
  k_uv3<<<4096, 256, 0, stream>>>(xf, w1, g15 + 0, v15 + 0, UV);
  k_edge2<<<2048, 256, 0, stream>>>(UV, idx, w2,
      g15 + 0,  b15 + 0,  m15 + 0,  v15 + 0,
      g15 + 64, b15 + 64, m15 + 64, v15 + 64, cat, 0);

  // ---- stage 2 ----
  k_norm<64><<<64, 256, 0, stream>>>(cat, 192, 0, sq);
  k_knn2p<<<1024, 256, 0, stream>>>(cat, 192, 0, sq, pk);
  k_kmerge<<<64, 256, 0, stream>>>(pk, idx);
  dim3 guv(256, 2);
  k_uv<<<guv, 256, 0, stream>>>(cat, 192, 0, w3, g15 + 128, v15 + 128, UV);
  k_edge2<<<2048, 256, 0, stream>>>(UV, idx, w4,
      g15 + 128, b15 + 128, m15 + 128, v15 + 128,
      g15 + 192, b15 + 192, m15 + 192, v15 + 192, cat, 64);

  // ---- stage 3 ----
  k_norm<64><<<64, 256, 0, stream>>>(cat, 192, 64, sq);
  k_knn2p<<<1024, 256, 0, stream>>>(cat, 192, 64, sq, pk);
  k_kmerge<<<64, 256, 0, stream>>>(pk, idx);
  k_uv<<<guv, 256, 0, stream>>>(cat, 192, 64, w5, g15 + 256, v15 + 256, UV);
  k_edge3<<<4096, 256, 0, stream>>>(UV, idx,
      g15 + 256, b15 + 256, m15 + 256, v15 + 256, cat);

  // ---- head ----
  k_zero<<<32, 256, 0, stream>>>(glob);
  dim3 g6g(256, 16);
  k_gemm<EP_MAXGLOB><<<g6g, 256, 0, stream>>>(
      cat, 192, w6, 192, 192, g6, b6, m6, v6, nullptr, nullptr, 0, glob);
  k_t7<<<16, 256, 0, stream>>>(glob, w7, t7);
  dim3 g7g(256, 8);
  k_gemm<EP_BIAS_BNMISH><<<g7g, 256, 0, stream>>>(
      cat, 192, w7 + 1024, 1216, 192, g7, b7, m7, v7, t7, h7, 512, nullptr);
  dim3 g8g(256, 4);
  k_gemm<EP_BNMISH><<<g8g, 256, 0, stream>>>(
      h7, 512, w8, 512, 512, g8, b8, m8, v8, nullptr, h8, 256, nullptr);
  k_out<<<4096, 256, 0, stream>>>(h8, w9, (float*)d_out);
}

// Round 13
// 869.948 us; speedup vs baseline: 2.2949x; 1.0383x over previous
//
#include <hip/hip_runtime.h>
#include <math.h>

#define BN_EPS 1e-5f
typedef unsigned long long u64;
typedef __attribute__((ext_vector_type(8))) short bf16x8;
typedef __attribute__((ext_vector_type(4))) float f32x4;

// mish(x) = x*tanh(ln(1+e^x)) = x*w/(w+2), w = u(u+2), u = e^x (clamped).
__device__ __forceinline__ float mishf(float x){
  float u = __expf(fminf(x, 20.f));
  float w = u * (u + 2.f);
  return x * w / (w + 2.f);
}

__device__ __forceinline__ unsigned fenc(float f){
  unsigned u = __float_as_uint(f);
  return (u & 0x80000000u) ? ~u : (u | 0x80000000u);
}
__device__ __forceinline__ float fdec(unsigned e){
  unsigned u = (e & 0x80000000u) ? (e & 0x7fffffffu) : ~e;
  return __uint_as_float(u);
}

// bf16x3 split: a = hi + lo (+O(2^-17 a)); rne via bit trick
__device__ __forceinline__ void bfsplit(float a, unsigned short &h, unsigned short &l){
  unsigned u = __float_as_uint(a);
  unsigned hb = (u + 0x7FFFu + ((u >> 16) & 1u)) >> 16;
  h = (unsigned short)hb;
  float hf = __uint_as_float(hb << 16);
  float r = a - hf;
  unsigned v = __float_as_uint(r);
  l = (unsigned short)((v + 0x7FFFu + ((v >> 16) & 1u)) >> 16);
}

// packed key: (value desc, index asc) == lax.top_k order as single u64 compare
__device__ __forceinline__ u64 mkkey(float v, int i){
  return ((u64)fenc(v) << 32) | (unsigned)(~i);
}
__device__ __forceinline__ int keyidx(u64 k){ return (int)(~(unsigned)k); }

__device__ __forceinline__ void ins10k(u64 (&L)[10], u64 k){
  if (k <= L[9]) return;
  #pragma unroll
  for (int p = 9; p >= 1; --p)
    L[p] = (k > L[p-1]) ? L[p-1] : ((k > L[p]) ? k : L[p]);
  L[0] = (k > L[0]) ? k : L[0];
}
#define KSENT mkkey(-INFINITY, 0x7fffffff)

__global__ void k_diag(float* __restrict__ out, float v){ out[0] = v; }

// ---------- transpose x [B,3,N] -> xf [B*N,3] ----------
__global__ __launch_bounds__(256)
void k_cast(const float* __restrict__ x, float* __restrict__ xf){
  int i = blockIdx.x * 256 + threadIdx.x;      // 49152
  int n = i & 2047, c = (i >> 11) % 3, b = i / (3 * 2048);
  xf[(size_t)(b * 2048 + n) * 3 + c] = x[i];
}

__global__ __launch_bounds__(256)
void k_zero(unsigned* __restrict__ p){
  p[blockIdx.x * 256 + threadIdx.x] = 0u;      // 32 blocks -> 8192
}

// ---------- squared norm per point ----------
template<int C>
__global__ __launch_bounds__(256)
void k_norm(const float* __restrict__ src, int stride, int off,
            float* __restrict__ sq){
  int i = blockIdx.x * 256 + threadIdx.x;      // 16384
  const float* r = src + (size_t)i * stride + off;
  float s = 0.f;
  #pragma unroll
  for (int c = 0; c < C; ++c) s = fmaf(r[c], r[c], s);
  sq[i] = s;
}

// ---------- knn C=3: 32 points/block, 8 chunk-threads/point ----------
__global__ __launch_bounds__(256)
void k_knn3(const float* __restrict__ src, int* __restrict__ idxout){
  constexpr int C = 3, PAD = 4;
  __shared__ float pts[128 * PAD];
  __shared__ float ss[128];
  __shared__ unsigned mH[32 * 8 * 10];
  __shared__ unsigned mL[32 * 8 * 10];
  const int t  = threadIdx.x;
  const int b  = blockIdx.x >> 6;
  const int p0 = (blockIdx.x & 63) * 32;
  const int p  = t >> 3, ch = t & 7;
  const float* srow = src + (size_t)(b * 2048 + p0 + p) * C;
  float own[C];
  #pragma unroll
  for (int c = 0; c < C; ++c) own[c] = srow[c];
  float sown = 0.f;
  #pragma unroll
  for (int c = 0; c < C; ++c) sown = fmaf(own[c], own[c], sown);
  u64 L[10];
  #pragma unroll
  for (int j = 0; j < 10; ++j) L[j] = KSENT;

  for (int m0 = 0; m0 < 2048; m0 += 128) {
    __syncthreads();
    for (int i = t; i < 128 * C; i += 256) {
      int mm = i / C, c = i % C;
      pts[mm * PAD + c] = src[(size_t)(b * 2048 + m0 + mm) * C + c];
    }
    __syncthreads();
    if (t < 128) {
      float s2 = 0.f;
      #pragma unroll
      for (int c = 0; c < C; ++c) s2 = fmaf(pts[t * PAD + c], pts[t * PAD + c], s2);
      ss[t] = s2;
    }
    __syncthreads();
    for (int mm = ch; mm < 128; mm += 8) {
      float dot = 0.f;
      #pragma unroll
      for (int c = 0; c < C; ++c) dot = fmaf(own[c], pts[mm * PAD + c], dot);
      ins10k(L, mkkey(2.f * dot - sown - ss[mm], m0 + mm));
    }
  }
  __syncthreads();
  #pragma unroll
  for (int j = 0; j < 10; ++j) {
    mH[t * 10 + j] = (unsigned)(L[j] >> 32);
    mL[t * 10 + j] = (unsigned)L[j];
  }
  __syncthreads();
  if (t < 32) {
    u64 F[10];
    #pragma unroll
    for (int j = 0; j < 10; ++j) F[j] = KSENT;
    for (int c2 = 0; c2 < 8; ++c2)
      for (int j = 0; j < 10; ++j) {
        int s = (t * 8 + c2) * 10 + j;
        ins10k(F, ((u64)mH[s] << 32) | mL[s]);
      }
    #pragma unroll
    for (int j = 0; j < 10; ++j)
      idxout[(size_t)(b * 2048 + p0 + t) * 10 + j] = keyidx(F[j]);
  }
}

// ---------- knn C=64 partial, MFMA bf16x3: 64 rows x 512 cands/block ----------
// S = (2A)·B^T via 3-term bf16 MFMA; frag-packed LDS (conflict-free reads).
__global__ __launch_bounds__(256)
void k_knn2p(const float* __restrict__ src, int stride, int off,
             const float* __restrict__ sq, u64* __restrict__ pk){
  __shared__ unsigned short AP[2][4096];  // [hi/lo][((strip*2+half)*64+lane)*8+j]
  __shared__ unsigned short BP[2][4096];  // [hi/lo][((tile*2+half)*64+lane)*8+j]
  __shared__ float Sc[64 * 65];
  __shared__ float ssB[64];
  const int t  = threadIdx.x;
  const int bx = blockIdx.x;
  const int cc = bx & 3;
  const int rg = (bx >> 2) & 31;
  const int b  = bx >> 7;
  const int p0 = rg * 64;
  const int c0 = cc * 512;
  const int lane = t & 63, w = t >> 6;
  const int row = t & 63, chk = t >> 6;

  // A staging (once), 2x folded into the split (exact)
  #pragma unroll
  for (int pass = 0; pass < 4; ++pass) {
    int i = pass * 256 + t;
    int r_ = i >> 4, c4 = (i & 15) * 4;
    float4 v = *(const float4*)&src[(size_t)(b * 2048 + p0 + r_) * stride + off + c4];
    float vv[4] = {v.x, v.y, v.z, v.w};
    #pragma unroll
    for (int q = 0; q < 4; ++q) {
      int ch = c4 + q;
      unsigned short h, lo;
      bfsplit(2.f * vv[q], h, lo);
      int s = r_ >> 4, m = r_ & 15, hh = ch >> 5, kk = ch & 31;
      int pos = (((s * 2 + hh) * 64) + ((kk >> 3) * 16 + m)) * 8 + (kk & 7);
      AP[0][pos] = h; AP[1][pos] = lo;
    }
  }
  float sqA = sq[b * 2048 + p0 + row];
  u64 L[10];
  #pragma unroll
  for (int j = 0; j < 10; ++j) L[j] = KSENT;

  for (int m0 = c0; m0 < c0 + 512; m0 += 64) {
    #pragma unroll
    for (int pass = 0; pass < 4; ++pass) {
      int i = pass * 256 + t;
      int j_ = i >> 4, c4 = (i & 15) * 4;
      float4 v = *(const float4*)&src[(size_t)(b * 2048 + m0 + j_) * stride + off + c4];
      float vv[4] = {v.x, v.y, v.z, v.w};
      #pragma unroll
      for (int q = 0; q < 4; ++q) {
        int ch = c4 + q;
        unsigned short h, lo;
        bfsplit(vv[q], h, lo);
        int tile = j_ >> 4, n = j_ & 15, hh = ch >> 5, kk = ch & 31;
        int pos = (((tile * 2 + hh) * 64) + ((kk >> 3) * 16 + n)) * 8 + (kk & 7);
        BP[0][pos] = h; BP[1][pos] = lo;
      }
    }
    if (t < 64) ssB[t] = sq[b * 2048 + m0 + t];
    __syncthreads();

    // MFMA: wave w owns rows [16w, 16w+16)
    bf16x8 aH0 = *(const bf16x8*)&AP[0][((w * 2 + 0) * 64 + lane) * 8];
    bf16x8 aH1 = *(const bf16x8*)&AP[0][((w * 2 + 1) * 64 + lane) * 8];
    bf16x8 aL0 = *(const bf16x8*)&AP[1][((w * 2 + 0) * 64 + lane) * 8];
    bf16x8 aL1 = *(const bf16x8*)&AP[1][((w * 2 + 1) * 64 + lane) * 8];
    #pragma unroll
    for (int tile = 0; tile < 4; ++tile) {
      bf16x8 bH0 = *(const bf16x8*)&BP[0][((tile * 2 + 0) * 64 + lane) * 8];
      bf16x8 bH1 = *(const bf16x8*)&BP[0][((tile * 2 + 1) * 64 + lane) * 8];
      bf16x8 bL0 = *(const bf16x8*)&BP[1][((tile * 2 + 0) * 64 + lane) * 8];
      bf16x8 bL1 = *(const bf16x8*)&BP[1][((tile * 2 + 1) * 64 + lane) * 8];
      f32x4 acc = {0.f, 0.f, 0.f, 0.f};
      acc = __builtin_amdgcn_mfma_f32_16x16x32_bf16(aL0, bH0, acc, 0, 0, 0);
      acc = __builtin_amdgcn_mfma_f32_16x16x32_bf16(aH0, bL0, acc, 0, 0, 0);
      acc = __builtin_amdgcn_mfma_f32_16x16x32_bf16(aH0, bH0, acc, 0, 0, 0);
      acc = __builtin_amdgcn_mfma_f32_16x16x32_bf16(aL1, bH1, acc, 0, 0, 0);
      acc = __builtin_amdgcn_mfma_f32_16x16x32_bf16(aH1, bL1, acc, 0, 0, 0);
      acc = __builtin_amdgcn_mfma_f32_16x16x32_bf16(aH1, bH1, acc, 0, 0, 0);
      int col = tile * 16 + (lane & 15);
      int rb  = w * 16 + ((lane >> 4) << 2);   // C/D: row=(lane>>4)*4+reg, col=lane&15
      #pragma unroll
      for (int r = 0; r < 4; ++r)
        Sc[(rb + r) * 65 + col] = acc[r];
    }
    __syncthreads();

    #pragma unroll
    for (int m2 = 0; m2 < 16; ++m2) {
      int mm = chk * 16 + m2;
      float key = Sc[row * 65 + mm] - sqA - ssB[mm];
      ins10k(L, mkkey(key, m0 + mm));
    }
    __syncthreads();
  }

  unsigned* mgH = (unsigned*)Sc;               // 10240 B <= 16640
  unsigned* mgL = (unsigned*)&AP[0][0];        // 10240 B <= 16384
  #pragma unroll
  for (int j = 0; j < 10; ++j) {
    mgH[(row * 4 + chk) * 10 + j] = (unsigned)(L[j] >> 32);
    mgL[(row * 4 + chk) * 10 + j] = (unsigned)L[j];
  }
  __syncthreads();
  if (t < 64) {
    u64 F[10];
    #pragma unroll
    for (int j = 0; j < 10; ++j) F[j] = KSENT;
    for (int c2 = 0; c2 < 4; ++c2)
      for (int j = 0; j < 10; ++j) {
        int s = (t * 4 + c2) * 10 + j;
        ins10k(F, ((u64)mgH[s] << 32) | mgL[s]);
      }
    size_t base = (size_t)(b * 2048 + p0 + t) * 40 + cc * 10;
    #pragma unroll
    for (int j = 0; j < 10; ++j) pk[base + j] = F[j];
  }
}

// ---------- merge 4 partial top-10 key lists -> final idx ----------
__global__ __launch_bounds__(256)
void k_kmerge(const u64* __restrict__ pk, int* __restrict__ idxout){
  int row = blockIdx.x * 256 + threadIdx.x;    // 16384
  u64 F[10];
  #pragma unroll
  for (int j = 0; j < 10; ++j) F[j] = KSENT;
  size_t base = (size_t)row * 40;
  for (int e = 0; e < 40; ++e) ins10k(F, pk[base + e]);
  #pragma unroll
  for (int j = 0; j < 10; ++j) idxout[(size_t)row * 10 + j] = keyidx(F[j]);
}

// ---------- UV for stage 1 (C=3): elementwise ----------
__global__ __launch_bounds__(256)
void k_uv3(const float* __restrict__ xf, const float* __restrict__ w1,
           const float* __restrict__ gg, const float* __restrict__ vv,
           float* __restrict__ UV){
  int i = blockIdx.x * 256 + threadIdx.x;      // 4096 blocks
  int p = i >> 6, o = i & 63;
  float s = gg[o] / sqrtf(vv[o] + BN_EPS);
  float x0 = xf[(size_t)p * 3], x1 = xf[(size_t)p * 3 + 1], x2 = xf[(size_t)p * 3 + 2];
  const float* wr = w1 + o * 6;
  float u = s * (wr[0] * x0 + wr[1] * x1 + wr[2] * x2);
  float v = s * ((wr[3] - wr[0]) * x0 + (wr[4] - wr[1]) * x1 + (wr[5] - wr[2]) * x2);
  UV[(size_t)p * 128 + o] = u;
  UV[(size_t)p * 128 + 64 + o] = v;
}

// ---------- UV for stages 2/3 (C=64): tiled GEMM, s1 folded ----------
__global__ __launch_bounds__(256)
void k_uv(const float* __restrict__ A, int lda, int aoff,
          const float* __restrict__ w,       // [64][128]
          const float* __restrict__ gg, const float* __restrict__ vv,
          float* __restrict__ UV){
  __shared__ float As[16][68];
  __shared__ float Bs[16][68];
  __shared__ float ss[64];
  const int t = threadIdx.x;
  const int tx = t & 15, ty = t >> 4;
  const int m0 = blockIdx.x * 64;
  const int half = blockIdx.y;
  if (t < 64) ss[t] = gg[t] / sqrtf(vv[t] + BN_EPS);
  __syncthreads();
  float acc[4][4] = {};
  for (int k0 = 0; k0 < 64; k0 += 16) {
    for (int i = t; i < 1024; i += 256) {
      int m = i >> 4, k = i & 15;
      As[k][m] = A[(size_t)(m0 + m) * lda + aoff + k0 + k];
    }
    for (int i = t; i < 1024; i += 256) {
      int n = i >> 4, k = i & 15;
      int kk = k0 + k;
      float wv = half ? (w[n * 128 + 64 + kk] - w[n * 128 + kk]) : w[n * 128 + kk];
      Bs[k][n] = wv * ss[n];
    }
    __syncthreads();
    #pragma unroll
    for (int k = 0; k < 16; ++k) {
      float4 a4 = *(const float4*)&As[k][tx * 4];
      float4 b4 = *(const float4*)&Bs[k][ty * 4];
      float am[4] = {a4.x, a4.y, a4.z, a4.w};
      float bm[4] = {b4.x, b4.y, b4.z, b4.w};
      #pragma unroll
      for (int q = 0; q < 4; ++q)
        #pragma unroll
        for (int r = 0; r < 4; ++r)
          acc[q][r] = fmaf(am[q], bm[r], acc[q][r]);
    }
    __syncthreads();
  }
  #pragma unroll
  for (int q = 0; q < 4; ++q)
    #pragma unroll
    for (int r = 0; r < 4; ++r)
      UV[(size_t)(m0 + tx * 4 + q) * 128 + half * 64 + ty * 4 + r] = acc[q][r];
}

// ---------- edge stage with conv2: 8 points/block, grid 2048 ----------
__global__ __launch_bounds__(256)
void k_edge2(const float* __restrict__ UV, const int* __restrict__ idx,
             const float* __restrict__ w2,   // [64][64]
             const float* __restrict__ g1, const float* __restrict__ b1,
             const float* __restrict__ m1, const float* __restrict__ v1,
             const float* __restrict__ g2, const float* __restrict__ b2,
             const float* __restrict__ m2, const float* __restrict__ v2,
             float* __restrict__ cat, int coff){
  __shared__ float Ha[64][81];
  __shared__ float Ws[64][68];
  __shared__ float o1s[64], s2s[64], o2s[64];
  __shared__ int   ejs[80];
  const int t = threadIdx.x;
  const int p0 = blockIdx.x * 8;  // 2048 blocks
  const int batch = p0 >> 11;
  if (t < 80) ejs[t] = batch * 2048 + (idx[p0 * 10 + t] & 2047);
  if (t < 64) {
    float s1 = g1[t] / sqrtf(v1[t] + BN_EPS);
    o1s[t] = b1[t] - m1[t] * s1;
    float s2 = g2[t] / sqrtf(v2[t] + BN_EPS);
    s2s[t] = s2;
    o2s[t] = b2[t] - m2[t] * s2;
  }
  for (int i = t; i < 4096; i += 256) {
    int k = i & 63, n = i >> 6;
    Ws[k][n] = w2[n * 64 + k];
  }
  __syncthreads();

  for (int i = t; i < 5120; i += 256) {
    int e = i >> 6, c = i & 63;
    int p = p0 + e / 10;
    float hv = UV[(size_t)ejs[e] * 128 + c] + UV[(size_t)p * 128 + 64 + c] + o1s[c];
    Ha[c][e] = mishf(hv);
  }
  __syncthreads();

  const int tx = t & 15, ty = t >> 4;
  float acc[5][4] = {};
  #pragma unroll 8
  for (int k = 0; k < 64; ++k) {
    float av[5];
    #pragma unroll
    for (int i2 = 0; i2 < 5; ++i2) av[i2] = Ha[k][tx * 5 + i2];
    float4 b4 = *(const float4*)&Ws[k][ty * 4];
    float bv[4] = {b4.x, b4.y, b4.z, b4.w};
    #pragma unroll
    for (int i2 = 0; i2 < 5; ++i2)
      #pragma unroll
      for (int r = 0; r < 4; ++r)
        acc[i2][r] = fmaf(av[i2], bv[r], acc[i2][r]);
  }
  __syncthreads();
  #pragma unroll
  for (int i2 = 0; i2 < 5; ++i2)
    #pragma unroll
    for (int r = 0; r < 4; ++r) {
      int o = ty * 4 + r;
      Ha[o][tx * 5 + i2] = mishf(acc[i2][r] * s2s[o] + o2s[o]);
    }
  __syncthreads();

  for (int i = t; i < 512; i += 256) {
    int p = i >> 6, o = i & 63;
    float mx = Ha[o][p * 10];
    #pragma unroll
    for (int k = 1; k < 10; ++k) mx = fmaxf(mx, Ha[o][p * 10 + k]);
    cat[(size_t)(p0 + p) * 192 + coff + o] = mx;
  }
}

// ---------- edge stage 3 (no conv2) ----------
__global__ __launch_bounds__(256)
void k_edge3(const float* __restrict__ UV, const int* __restrict__ idx,
             const float* __restrict__ gg, const float* __restrict__ bb,
             const float* __restrict__ mn, const float* __restrict__ vv,
             float* __restrict__ cat){
  int i = blockIdx.x * 256 + threadIdx.x;      // 4096 blocks
  int p = i >> 6, o = i & 63;
  int batch = p >> 11;
  float s = gg[o] / sqrtf(vv[o] + BN_EPS);
  float of = bb[o] - mn[o] * s;
  float v_ = UV[(size_t)p * 128 + 64 + o] + of;
  float mx = -INFINITY;
  #pragma unroll
  for (int k = 0; k < 10; ++k) {
    int j = batch * 2048 + (idx[p * 10 + k] & 2047);
    mx = fmaxf(mx, mishf(UV[(size_t)j * 128 + o] + v_));
  }
  cat[(size_t)p * 192 + 128 + o] = mx;
}

// ---------- tiled fp32 GEMM head ----------
#define EP_BNMISH      0
#define EP_MAXGLOB     1
#define EP_BIAS_BNMISH 2

template<int EPI>
__global__ __launch_bounds__(256)
void k_gemm(const float* __restrict__ A, int lda,
            const float* __restrict__ W, int ldw, int K,
            const float* __restrict__ gg, const float* __restrict__ bb,
            const float* __restrict__ mn, const float* __restrict__ vv,
            const float* __restrict__ bias,
            float* __restrict__ out, int ldo,
            unsigned* __restrict__ glob)
{
  __shared__ float As[16][68];
  __shared__ float Bs[16][68];
  const int t  = threadIdx.x;
  const int tx = t & 15, ty = t >> 4;
  const int m0 = blockIdx.x * 64, n0 = blockIdx.y * 64;
  const int lm = t >> 2, lk = (t & 3) * 4;
  float acc[4][4] = {};

  for (int k0 = 0; k0 < K; k0 += 16) {
    float4 a4 = *(const float4*)&A[(size_t)(m0 + lm) * lda + k0 + lk];
    float4 b4 = *(const float4*)&W[(size_t)(n0 + lm) * ldw + k0 + lk];
    As[lk][lm] = a4.x; As[lk+1][lm] = a4.y; As[lk+2][lm] = a4.z; As[lk+3][lm] = a4.w;
    Bs[lk][lm] = b4.x; Bs[lk+1][lm] = b4.y; Bs[lk+2][lm] = b4.z; Bs[lk+3][lm] = b4.w;
    __syncthreads();
    #pragma unroll
    for (int k = 0; k < 16; ++k) {
      float4 av4 = *(const float4*)&As[k][tx * 4];
      float4 bv4 = *(const float4*)&Bs[k][ty * 4];
      float am[4] = {av4.x, av4.y, av4.z, av4.w};
      float bm[4] = {bv4.x, bv4.y, bv4.z, bv4.w};
      #pragma unroll
      for (int i2 = 0; i2 < 4; ++i2)
        #pragma unroll
        for (int j = 0; j < 4; ++j)
          acc[i2][j] = fmaf(am[i2], bm[j], acc[i2][j]);
    }
    __syncthreads();
  }

  float sc[4], of[4];
  #pragma unroll
  for (int j = 0; j < 4; ++j) {
    int nn = n0 + ty * 4 + j;
    float s = gg[nn] / sqrtf(vv[nn] + BN_EPS);
    sc[j] = s;
    of[j] = bb[nn] - mn[nn] * s;
  }

  if (EPI == EP_MAXGLOB) {
    float mx[4] = {-INFINITY, -INFINITY, -INFINITY, -INFINITY};
    #pragma unroll
    for (int i2 = 0; i2 < 4; ++i2)
      #pragma unroll
      for (int j = 0; j < 4; ++j)
        mx[j] = fmaxf(mx[j], mishf(acc[i2][j] * sc[j] + of[j]));
    __syncthreads();
    float* red = &As[0][0];
    #pragma unroll
    for (int j = 0; j < 4; ++j) red[(ty * 4 + j) * 16 + tx] = mx[j];
    __syncthreads();
    if (t < 64) {
      float v = red[t * 16];
      #pragma unroll
      for (int r = 1; r < 16; ++r) v = fmaxf(v, red[t * 16 + r]);
      atomicMax(&glob[(m0 >> 11) * 1024 + n0 + t], fenc(v));
    }
  } else {
    #pragma unroll
    for (int i2 = 0; i2 < 4; ++i2) {
      int m = m0 + tx * 4 + i2;
      #pragma unroll
      for (int j = 0; j < 4; ++j) {
        int nn = n0 + ty * 4 + j;
        float v = acc[i2][j];
        if (EPI == EP_BIAS_BNMISH) v += bias[(m >> 11) * 512 + nn];
        out[(size_t)m * ldo + nn] = mishf(v * sc[j] + of[j]);
      }
    }
  }
}

// ---------- t7[b][o] = w7[o, :1024] . glob[b] ----------
__global__ __launch_bounds__(256)
void k_t7(const unsigned* __restrict__ glob, const float* __restrict__ w7,
          float* __restrict__ t7){
  int i = blockIdx.x * 256 + threadIdx.x;      // 4096
  int b = i >> 9, o = i & 511;
  float acc = 0.f;
  for (int c = 0; c < 1024; ++c)
    acc = fmaf(w7[(size_t)o * 1216 + c], fdec(glob[b * 1024 + c]), acc);
  t7[i] = acc;
}

// ---------- final conv ----------
__global__ __launch_bounds__(256)
void k_out(const float* __restrict__ h8, const float* __restrict__ w9,
           float* __restrict__ out)
{
  __shared__ float row[4][256];
  const int t = threadIdx.x;
  const int g = t >> 6, l = t & 63;
  const int p = blockIdx.x * 4 + g;            // 4096 blocks
  for (int c = l; c < 256; c += 64)
    row[g][c] = h8[(size_t)p * 256 + c];
  __syncthreads();
  if (l < 18) {
    float acc = 0.f;
    for (int c = 0; c < 256; ++c)
      acc = fmaf(row[g][c], w9[l * 256 + c], acc);
    int b = p >> 11, n = p & 2047;
    out[(size_t)b * 36864 + l * 2048 + n] = acc;
  }
}

extern "C" void kernel_launch(void* const* d_in, const int* in_sizes, int n_in,
                              void* d_out, int out_size, void* d_ws, size_t ws_size,
                              hipStream_t stream)
{
  const size_t OFF_XF   = 0;
  const size_t OFF_IDX  = 262144;
  const size_t OFF_CAT  = 917504;
  const size_t OFF_GLOB = 13500416;
  const size_t OFF_T7   = 13533184;
  const size_t OFF_H7   = 13549568;            // h7; UV aliases first 8.4MB
  const size_t OFF_H8   = 47104000;            // h8; sq/pk alias (knn phase)
  const size_t NEED     = 63881216;

  static const int EXP[26] = {
    49152, 384, 4096, 8192, 4096, 8192, 196608, 622592, 131072, 4608,
    320, 320, 320, 320, 1024, 1024, 1024, 1024,
    512, 512, 512, 512, 256, 256, 256, 256 };
  if (n_in < 26) { k_diag<<<1,1,0,stream>>>((float*)d_out, 16384.f); return; }
  for (int i = 0; i < 26; ++i)
    if (in_sizes[i] != EXP[i]) {
      k_diag<<<1,1,0,stream>>>((float*)d_out, 4096.f + 128.f * i); return;
    }
  if (out_size != 294912) { k_diag<<<1,1,0,stream>>>((float*)d_out, 20480.f); return; }
  if (ws_size < NEED) {
    k_diag<<<1,1,0,stream>>>((float*)d_out, 24576.f + (float)(ws_size >> 20)); return;
  }

  const float* x  = (const float*)d_in[0];
  const float* w1 = (const float*)d_in[1];
  const float* w2 = (const float*)d_in[2];
  const float* w3 = (const float*)d_in[3];
  const float* w4 = (const float*)d_in[4];
  const float* w5 = (const float*)d_in[5];
  const float* w6 = (const float*)d_in[6];
  const float* w7 = (const float*)d_in[7];
  const float* w8 = (const float*)d_in[8];
  const float* w9 = (const float*)d_in[9];
  const float* g15 = (const float*)d_in[10];
  const float* b15 = (const float*)d_in[11];
  const float* m15 = (const float*)d_in[12];
  const float* v15 = (const float*)d_in[13];
  const float* g6 = (const float*)d_in[14];
  const float* b6 = (const float*)d_in[15];
  const float* m6 = (const float*)d_in[16];
  const float* v6 = (const float*)d_in[17];
  const float* g7 = (const float*)d_in[18];
  const float* b7 = (const float*)d_in[19];
  const float* m7 = (const float*)d_in[20];
  const float* v7 = (const float*)d_in[21];
  const float* g8 = (const float*)d_in[22];
  const float* b8 = (const float*)d_in[23];
  const float* m8 = (const float*)d_in[24];
  const float* v8 = (const float*)d_in[25];

  char* ws = (char*)d_ws;
  float*    xf   = (float*)(ws + OFF_XF);
  int*      idx  = (int*)(ws + OFF_IDX);
  float*    cat  = (float*)(ws + OFF_CAT);
  unsigned* glob = (unsigned*)(ws + OFF_GLOB);
  float*    t7   = (float*)(ws + OFF_T7);
  float*    h7   = (float*)(ws + OFF_H7);
  float*    UV   = (float*)(ws + OFF_H7);
  float*    h8   = (float*)(ws + OFF_H8);
  float*    sq   = (float*)(ws + OFF_H8);              //    65,536 [16384]
  u64*      pk   = (u64*)(ws + OFF_H8 + 65536);        // 5,242,880 [16384][40]

  k_cast<<<192, 256, 0, stream>>>(x, xf);

  // ---- stage 1 ----
  k_knn3<<<512, 256, 0, stream>>>(xf, idx);
  k_uv3<<<4096, 256, 0, stream>>>(xf, w1, g15 + 0, v15 + 0, UV);
  k_edge2<<<2048, 256, 0, stream>>>(UV, idx, w2,
      g15 + 0,  b15 + 0,  m15 + 0,  v15 + 0,
      g15 + 64, b15 + 64, m15 + 64, v15 + 64, cat, 0);

  // ---- stage 2 ----
  k_norm<64><<<64, 256, 0, stream>>>(cat, 192, 0, sq);
  k_knn2p<<<1024, 256, 0, stream>>>(cat, 192, 0, sq, pk);
  k_kmerge<<<64, 256, 0, stream>>>(pk, idx);
  dim3 guv(256, 2);
  k_uv<<<guv, 256, 0, stream>>>(cat, 192, 0, w3, g15 + 128, v15 + 128, UV);
  k_edge2<<<2048, 256, 0, stream>>>(UV, idx, w4,
      g15 + 128, b15 + 128, m15 + 128, v15 + 128,
      g15 + 192, b15 + 192, m15 + 192, v15 + 192, cat, 64);

  // ---- stage 3 ----
  k_norm<64><<<64, 256, 0, stream>>>(cat, 192, 64, sq);
  k_knn2p<<<1024, 256, 0, stream>>>(cat, 192, 64, sq, pk);
  k_kmerge<<<64, 256, 0, stream>>>(pk, idx);
  k_uv<<<guv, 256, 0, stream>>>(cat, 192, 64, w5, g15 + 256, v15 + 256, UV);
  k_edge3<<<4096, 256, 0, stream>>>(UV, idx,
      g15 + 256, b15 + 256, m15 + 256, v15 + 256, cat);

  // ---- head ----
  k_zero<<<32, 256, 0, stream>>>(glob);
  dim3 g6g(256, 16);
  k_gemm<EP_MAXGLOB><<<g6g, 256, 0, stream>>>(
      cat, 192, w6, 192, 192, g6, b6, m6, v6, nullptr, nullptr, 0, glob);
  k_t7<<<16, 256, 0, stream>>>(glob, w7, t7);
  dim3 g7g(256, 8);
  k_gemm<EP_BIAS_BNMISH><<<g7g, 256, 0, stream>>>(
      cat, 192, w7 + 1024, 1216, 192, g7, b7, m7, v7, t7, h7, 512, nullptr);
  dim3 g8g(256, 4);
  k_gemm<EP_BNMISH><<<g8g, 256, 0, stream>>>(
      h7, 512, w8, 512, 512, g8, b8, m8, v8, nullptr, h8, 256, nullptr);
  k_out<<<4096, 256, 0, stream>>>(h8, w9, (float*)d_out);
}

// Round 14
// 763.371 us; speedup vs baseline: 2.6153x; 1.1396x over previous
//
#include <hip/hip_runtime.h>
#include <math.h>

#define BN_EPS 1e-5f
typedef unsigned long long u64;
typedef __attribute__((ext_vector_type(8))) short bf16x8;
typedef __attribute__((ext_vector_type(4))) float f32x4;

// mish(x) = x*tanh(ln(1+e^x)) = x*w/(w+2), w = u(u+2), u = e^x (clamped).
__device__ __forceinline__ float mishf(float x){
  float u = __expf(fminf(x, 20.f));
  float w = u * (u + 2.f);
  return x * w / (w + 2.f);
}

__device__ __forceinline__ unsigned fenc(float f){
  unsigned u = __float_as_uint(f);
  return (u & 0x80000000u) ? ~u : (u | 0x80000000u);
}
__device__ __forceinline__ float fdec(unsigned e){
  unsigned u = (e & 0x80000000u) ? (e & 0x7fffffffu) : ~e;
  return __uint_as_float(u);
}

// bf16x3 split: a = hi + lo (+O(2^-17 a)); rne via bit trick
__device__ __forceinline__ void bfsplit(float a, unsigned short &h, unsigned short &l){
  unsigned u = __float_as_uint(a);
  unsigned hb = (u + 0x7FFFu + ((u >> 16) & 1u)) >> 16;
  h = (unsigned short)hb;
  float hf = __uint_as_float(hb << 16);
  float r = a - hf;
  unsigned v = __float_as_uint(r);
  l = (unsigned short)((v + 0x7FFFu + ((v >> 16) & 1u)) >> 16);
}

// packed key: (value desc, index asc) == lax.top_k order as single u64 compare
__device__ __forceinline__ u64 mkkey(float v, int i){
  return ((u64)fenc(v) << 32) | (unsigned)(~i);
}
__device__ __forceinline__ int keyidx(u64 k){ return (int)(~(unsigned)k); }

__device__ __forceinline__ void ins10k(u64 (&L)[10], u64 k){
  if (k <= L[9]) return;
  #pragma unroll
  for (int p = 9; p >= 1; --p)
    L[p] = (k > L[p-1]) ? L[p-1] : ((k > L[p]) ? k : L[p]);
  L[0] = (k > L[0]) ? k : L[0];
}
#define KSENT mkkey(-INFINITY, 0x7fffffff)

__global__ void k_diag(float* __restrict__ out, float v){ out[0] = v; }

// ---------- transpose x [B,3,N] -> xf [B*N,3] ----------
__global__ __launch_bounds__(256)
void k_cast(const float* __restrict__ x, float* __restrict__ xf){
  int i = blockIdx.x * 256 + threadIdx.x;      // 49152
  int n = i & 2047, c = (i >> 11) % 3, b = i / (3 * 2048);
  xf[(size_t)(b * 2048 + n) * 3 + c] = x[i];
}

__global__ __launch_bounds__(256)
void k_zero(unsigned* __restrict__ p){
  p[blockIdx.x * 256 + threadIdx.x] = 0u;      // 32 blocks -> 8192
}

// ---------- squared norm per point ----------
template<int C>
__global__ __launch_bounds__(256)
void k_norm(const float* __restrict__ src, int stride, int off,
            float* __restrict__ sq){
  int i = blockIdx.x * 256 + threadIdx.x;      // 16384
  const float* r = src + (size_t)i * stride + off;
  float s = 0.f;
  #pragma unroll
  for (int c = 0; c < C; ++c) s = fmaf(r[c], r[c], s);
  sq[i] = s;
}

// ---------- knn C=3: 32 points/block, 8 chunk-threads/point ----------
__global__ __launch_bounds__(256)
void k_knn3(const float* __restrict__ src, int* __restrict__ idxout){
  constexpr int C = 3, PAD = 4;
  __shared__ float pts[128 * PAD];
  __shared__ float ss[128];
  __shared__ unsigned mH[32 * 8 * 10];
  __shared__ unsigned mL[32 * 8 * 10];
  const int t  = threadIdx.x;
  const int b  = blockIdx.x >> 6;
  const int p0 = (blockIdx.x & 63) * 32;
  const int p  = t >> 3, ch = t & 7;
  const float* srow = src + (size_t)(b * 2048 + p0 + p) * C;
  float own[C];
  #pragma unroll
  for (int c = 0; c < C; ++c) own[c] = srow[c];
  float sown = 0.f;
  #pragma unroll
  for (int c = 0; c < C; ++c) sown = fmaf(own[c], own[c], sown);
  u64 L[10];
  #pragma unroll
  for (int j = 0; j < 10; ++j) L[j] = KSENT;

  for (int m0 = 0; m0 < 2048; m0 += 128) {
    __syncthreads();
    for (int i = t; i < 128 * C; i += 256) {
      int mm = i / C, c = i % C;
      pts[mm * PAD + c] = src[(size_t)(b * 2048 + m0 + mm) * C + c];
    }
    __syncthreads();
    if (t < 128) {
      float s2 = 0.f;
      #pragma unroll
      for (int c = 0; c < C; ++c) s2 = fmaf(pts[t * PAD + c], pts[t * PAD + c], s2);
      ss[t] = s2;
    }
    __syncthreads();
    for (int mm = ch; mm < 128; mm += 8) {
      float dot = 0.f;
      #pragma unroll
      for (int c = 0; c < C; ++c) dot = fmaf(own[c], pts[mm * PAD + c], dot);
      ins10k(L, mkkey(2.f * dot - sown - ss[mm], m0 + mm));
    }
  }
  __syncthreads();
  #pragma unroll
  for (int j = 0; j < 10; ++j) {
    mH[t * 10 + j] = (unsigned)(L[j] >> 32);
    mL[t * 10 + j] = (unsigned)L[j];
  }
  __syncthreads();
  if (t < 32) {
    u64 F[10];
    #pragma unroll
    for (int j = 0; j < 10; ++j) F[j] = KSENT;
    for (int c2 = 0; c2 < 8; ++c2)
      for (int j = 0; j < 10; ++j) {
        int s = (t * 8 + c2) * 10 + j;
        ins10k(F, ((u64)mH[s] << 32) | mL[s]);
      }
    #pragma unroll
    for (int j = 0; j < 10; ++j)
      idxout[(size_t)(b * 2048 + p0 + t) * 10 + j] = keyidx(F[j]);
  }
}

// ---------- knn C=64 partial, MFMA bf16x3: 64 rows x 512 cands/block ----------
__global__ __launch_bounds__(256)
void k_knn2p(const float* __restrict__ src, int stride, int off,
             const float* __restrict__ sq, u64* __restrict__ pk){
  __shared__ unsigned short AP[2][4096];
  __shared__ unsigned short BP[2][4096];
  __shared__ float Sc[64 * 65];
  __shared__ float ssB[64];
  const int t  = threadIdx.x;
  const int bx = blockIdx.x;
  const int cc = bx & 3;
  const int rg = (bx >> 2) & 31;
  const int b  = bx >> 7;
  const int p0 = rg * 64;
  const int c0 = cc * 512;
  const int lane = t & 63, w = t >> 6;
  const int row = t & 63, chk = t >> 6;

  #pragma unroll
  for (int pass = 0; pass < 4; ++pass) {
    int i = pass * 256 + t;
    int r_ = i >> 4, c4 = (i & 15) * 4;
    float4 v = *(const float4*)&src[(size_t)(b * 2048 + p0 + r_) * stride + off + c4];
    float vv[4] = {v.x, v.y, v.z, v.w};
    #pragma unroll
    for (int q = 0; q < 4; ++q) {
      int ch = c4 + q;
      unsigned short h, lo;
      bfsplit(2.f * vv[q], h, lo);
      int s = r_ >> 4, m = r_ & 15, hh = ch >> 5, kk = ch & 31;
      int pos = (((s * 2 + hh) * 64) + ((kk >> 3) * 16 + m)) * 8 + (kk & 7);
      AP[0][pos] = h; AP[1][pos] = lo;
    }
  }
  float sqA = sq[b * 2048 + p0 + row];
  u64 L[10];
  #pragma unroll
  for (int j = 0; j < 10; ++j) L[j] = KSENT;

  for (int m0 = c0; m0 < c0 + 512; m0 += 64) {
    #pragma unroll
    for (int pass = 0; pass < 4; ++pass) {
      int i = pass * 256 + t;
      int j_ = i >> 4, c4 = (i & 15) * 4;
      float4 v = *(const float4*)&src[(size_t)(b * 2048 + m0 + j_) * stride + off + c4];
      float vv[4] = {v.x, v.y, v.z, v.w};
      #pragma unroll
      for (int q = 0; q < 4; ++q) {
        int ch = c4 + q;
        unsigned short h, lo;
        bfsplit(vv[q], h, lo);
        int tile = j_ >> 4, n = j_ & 15, hh = ch >> 5, kk = ch & 31;
        int pos = (((tile * 2 + hh) * 64) + ((kk >> 3) * 16 + n)) * 8 + (kk & 7);
        BP[0][pos] = h; BP[1][pos] = lo;
      }
    }
    if (t < 64) ssB[t] = sq[b * 2048 + m0 + t];
    __syncthreads();

    bf16x8 aH0 = *(const bf16x8*)&AP[0][((w * 2 + 0) * 64 + lane) * 8];
    bf16x8 aH1 = *(const bf16x8*)&AP[0][((w * 2 + 1) * 64 + lane) * 8];
    bf16x8 aL0 = *(const bf16x8*)&AP[1][((w * 2 + 0) * 64 + lane) * 8];
    bf16x8 aL1 = *(const bf16x8*)&AP[1][((w * 2 + 1) * 64 + lane) * 8];
    #pragma unroll
    for (int tile = 0; tile < 4; ++tile) {
      bf16x8 bH0 = *(const bf16x8*)&BP[0][((tile * 2 + 0) * 64 + lane) * 8];
      bf16x8 bH1 = *(const bf16x8*)&BP[0][((tile * 2 + 1) * 64 + lane) * 8];
      bf16x8 bL0 = *(const bf16x8*)&BP[1][((tile * 2 + 0) * 64 + lane) * 8];
      bf16x8 bL1 = *(const bf16x8*)&BP[1][((tile * 2 + 1) * 64 + lane) * 8];
      f32x4 acc = {0.f, 0.f, 0.f, 0.f};
      acc = __builtin_amdgcn_mfma_f32_16x16x32_bf16(aL0, bH0, acc, 0, 0, 0);
      acc = __builtin_amdgcn_mfma_f32_16x16x32_bf16(aH0, bL0, acc, 0, 0, 0);
      acc = __builtin_amdgcn_mfma_f32_16x16x32_bf16(aH0, bH0, acc, 0, 0, 0);
      acc = __builtin_amdgcn_mfma_f32_16x16x32_bf16(aL1, bH1, acc, 0, 0, 0);
      acc = __builtin_amdgcn_mfma_f32_16x16x32_bf16(aH1, bL1, acc, 0, 0, 0);
      acc = __builtin_amdgcn_mfma_f32_16x16x32_bf16(aH1, bH1, acc, 0, 0, 0);
      int col = tile * 16 + (lane & 15);
      int rb  = w * 16 + ((lane >> 4) << 2);
      #pragma unroll
      for (int r = 0; r < 4; ++r)
        Sc[(rb + r) * 65 + col] = acc[r];
    }
    __syncthreads();

    #pragma unroll
    for (int m2 = 0; m2 < 16; ++m2) {
      int mm = chk * 16 + m2;
      float key = Sc[row * 65 + mm] - sqA - ssB[mm];
      ins10k(L, mkkey(key, m0 + mm));
    }
    __syncthreads();
  }

  unsigned* mgH = (unsigned*)Sc;
  unsigned* mgL = (unsigned*)&AP[0][0];
  #pragma unroll
  for (int j = 0; j < 10; ++j) {
    mgH[(row * 4 + chk) * 10 + j] = (unsigned)(L[j] >> 32);
    mgL[(row * 4 + chk) * 10 + j] = (unsigned)L[j];
  }
  __syncthreads();
  if (t < 64) {
    u64 F[10];
    #pragma unroll
    for (int j = 0; j < 10; ++j) F[j] = KSENT;
    for (int c2 = 0; c2 < 4; ++c2)
      for (int j = 0; j < 10; ++j) {
        int s = (t * 4 + c2) * 10 + j;
        ins10k(F, ((u64)mgH[s] << 32) | mgL[s]);
      }
    size_t base = (size_t)(b * 2048 + p0 + t) * 40 + cc * 10;
    #pragma unroll
    for (int j = 0; j < 10; ++j) pk[base + j] = F[j];
  }
}

// ---------- merge 4 partial top-10 key lists -> final idx ----------
__global__ __launch_bounds__(256)
void k_kmerge(const u64* __restrict__ pk, int* __restrict__ idxout){
  int row = blockIdx.x * 256 + threadIdx.x;    // 16384
  u64 F[10];
  #pragma unroll
  for (int j = 0; j < 10; ++j) F[j] = KSENT;
  size_t base = (size_t)row * 40;
  for (int e = 0; e < 40; ++e) ins10k(F, pk[base + e]);
  #pragma unroll
  for (int j = 0; j < 10; ++j) idxout[(size_t)row * 10 + j] = keyidx(F[j]);
}

// ---------- UV for stage 1 (C=3): elementwise ----------
__global__ __launch_bounds__(256)
void k_uv3(const float* __restrict__ xf, const float* __restrict__ w1,
           const float* __restrict__ gg, const float* __restrict__ vv,
           float* __restrict__ UV){
  int i = blockIdx.x * 256 + threadIdx.x;      // 4096 blocks
  int p = i >> 6, o = i & 63;
  float s = gg[o] / sqrtf(vv[o] + BN_EPS);
  float x0 = xf[(size_t)p * 3], x1 = xf[(size_t)p * 3 + 1], x2 = xf[(size_t)p * 3 + 2];
  const float* wr = w1 + o * 6;
  float u = s * (wr[0] * x0 + wr[1] * x1 + wr[2] * x2);
  float v = s * ((wr[3] - wr[0]) * x0 + (wr[4] - wr[1]) * x1 + (wr[5] - wr[2]) * x2);
  UV[(size_t)p * 128 + o] = u;
  UV[(size_t)p * 128 + 64 + o] = v;
}

// ---------- UV for stages 2/3 (C=64): tiled GEMM, s1 folded ----------
__global__ __launch_bounds__(256)
void k_uv(const float* __restrict__ A, int lda, int aoff,
          const float* __restrict__ w,       // [64][128]
          const float* __restrict__ gg, const float* __restrict__ vv,
          float* __restrict__ UV){
  __shared__ float As[16][68];
  __shared__ float Bs[16][68];
  __shared__ float ss[64];
  const int t = threadIdx.x;
  const int tx = t & 15, ty = t >> 4;
  const int m0 = blockIdx.x * 64;
  const int half = blockIdx.y;
  if (t < 64) ss[t] = gg[t] / sqrtf(vv[t] + BN_EPS);
  __syncthreads();
  float acc[4][4] = {};
  for (int k0 = 0; k0 < 64; k0 += 16) {
    for (int i = t; i < 1024; i += 256) {
      int m = i >> 4, k = i & 15;
      As[k][m] = A[(size_t)(m0 + m) * lda + aoff + k0 + k];
    }
    for (int i = t; i < 1024; i += 256) {
      int n = i >> 4, k = i & 15;
      int kk = k0 + k;
      float wv = half ? (w[n * 128 + 64 + kk] - w[n * 128 + kk]) : w[n * 128 + kk];
      Bs[k][n] = wv * ss[n];
    }
    __syncthreads();
    #pragma unroll
    for (int k = 0; k < 16; ++k) {
      float4 a4 = *(const float4*)&As[k][tx * 4];
      float4 b4 = *(const float4*)&Bs[k][ty * 4];
      float am[4] = {a4.x, a4.y, a4.z, a4.w};
      float bm[4] = {b4.x, b4.y, b4.z, b4.w};
      #pragma unroll
      for (int q = 0; q < 4; ++q)
        #pragma unroll
        for (int r = 0; r < 4; ++r)
          acc[q][r] = fmaf(am[q], bm[r], acc[q][r]);
    }
    __syncthreads();
  }
  #pragma unroll
  for (int q = 0; q < 4; ++q)
    #pragma unroll
    for (int r = 0; r < 4; ++r)
      UV[(size_t)(m0 + tx * 4 + q) * 128 + half * 64 + ty * 4 + r] = acc[q][r];
}

// ---------- edge stage with conv2: 8 points/block, grid 2048 ----------
__global__ __launch_bounds__(256)
void k_edge2(const float* __restrict__ UV, const int* __restrict__ idx,
             const float* __restrict__ w2,   // [64][64]
             const float* __restrict__ g1, const float* __restrict__ b1,
             const float* __restrict__ m1, const float* __restrict__ v1,
             const float* __restrict__ g2, const float* __restrict__ b2,
             const float* __restrict__ m2, const float* __restrict__ v2,
             float* __restrict__ cat, int coff){
  __shared__ float Ha[64][81];
  __shared__ float Ws[64][68];
  __shared__ float o1s[64], s2s[64], o2s[64];
  __shared__ int   ejs[80];
  const int t = threadIdx.x;
  const int p0 = blockIdx.x * 8;  // 2048 blocks
  const int batch = p0 >> 11;
  if (t < 80) ejs[t] = batch * 2048 + (idx[p0 * 10 + t] & 2047);
  if (t < 64) {
    float s1 = g1[t] / sqrtf(v1[t] + BN_EPS);
    o1s[t] = b1[t] - m1[t] * s1;
    float s2 = g2[t] / sqrtf(v2[t] + BN_EPS);
    s2s[t] = s2;
    o2s[t] = b2[t] - m2[t] * s2;
  }
  for (int i = t; i < 4096; i += 256) {
    int k = i & 63, n = i >> 6;
    Ws[k][n] = w2[n * 64 + k];
  }
  __syncthreads();

  for (int i = t; i < 5120; i += 256) {
    int e = i >> 6, c = i & 63;
    int p = p0 + e / 10;
    float hv = UV[(size_t)ejs[e] * 128 + c] + UV[(size_t)p * 128 + 64 + c] + o1s[c];
    Ha[c][e] = mishf(hv);
  }
  __syncthreads();

  const int tx = t & 15, ty = t >> 4;
  float acc[5][4] = {};
  #pragma unroll 8
  for (int k = 0; k < 64; ++k) {
    float av[5];
    #pragma unroll
    for (int i2 = 0; i2 < 5; ++i2) av[i2] = Ha[k][tx * 5 + i2];
    float4 b4 = *(const float4*)&Ws[k][ty * 4];
    float bv[4] = {b4.x, b4.y, b4.z, b4.w};
    #pragma unroll
    for (int i2 = 0; i2 < 5; ++i2)
      #pragma unroll
      for (int r = 0; r < 4; ++r)
        acc[i2][r] = fmaf(av[i2], bv[r], acc[i2][r]);
  }
  __syncthreads();
  #pragma unroll
  for (int i2 = 0; i2 < 5; ++i2)
    #pragma unroll
    for (int r = 0; r < 4; ++r) {
      int o = ty * 4 + r;
      Ha[o][tx * 5 + i2] = mishf(acc[i2][r] * s2s[o] + o2s[o]);
    }
  __syncthreads();

  for (int i = t; i < 512; i += 256) {
    int p = i >> 6, o = i & 63;
    float mx = Ha[o][p * 10];
    #pragma unroll
    for (int k = 1; k < 10; ++k) mx = fmaxf(mx, Ha[o][p * 10 + k]);
    cat[(size_t)(p0 + p) * 192 + coff + o] = mx;
  }
}

// ---------- edge stage 3 (no conv2) ----------
__global__ __launch_bounds__(256)
void k_edge3(const float* __restrict__ UV, const int* __restrict__ idx,
             const float* __restrict__ gg, const float* __restrict__ bb,
             const float* __restrict__ mn, const float* __restrict__ vv,
             float* __restrict__ cat){
  int i = blockIdx.x * 256 + threadIdx.x;      // 4096 blocks
  int p = i >> 6, o = i & 63;
  int batch = p >> 11;
  float s = gg[o] / sqrtf(vv[o] + BN_EPS);
  float of = bb[o] - mn[o] * s;
  float v_ = UV[(size_t)p * 128 + 64 + o] + of;
  float mx = -INFINITY;
  #pragma unroll
  for (int k = 0; k < 10; ++k) {
    int j = batch * 2048 + (idx[p * 10 + k] & 2047);
    mx = fmaxf(mx, mishf(UV[(size_t)j * 128 + o] + v_));
  }
  cat[(size_t)p * 192 + 128 + o] = mx;
}

// ---------- split src[N][K] (row base n*ld+koff) -> frag-packed bf16 hi/lo ----------
// pos = ((n>>4)*(K/8) + (k>>3))*128 + (n&15)*8 + (k&7)
__global__ __launch_bounds__(256)
void k_split(const float* __restrict__ src, int ld, int koff, int K,
             unsigned short* __restrict__ H, unsigned short* __restrict__ L){
  int i = blockIdx.x * 256 + threadIdx.x;
  int n = i / K, k = i - n * K;
  float v = src[(size_t)n * ld + koff + k];
  unsigned short h, lo;
  bfsplit(v, h, lo);
  size_t pos = ((size_t)(n >> 4) * (K >> 3) + (k >> 3)) * 128 + (n & 15) * 8 + (k & 7);
  H[pos] = h; L[pos] = lo;
}

// ---------- MFMA bf16x3 head GEMM: 64x64 tile, frags direct from global ----------
#define EP_BNMISH      0
#define EP_MAXGLOB     1
#define EP_BIAS_BNMISH 2

template<int EPI>
__global__ __launch_bounds__(256)
void k_gemm(const unsigned short* __restrict__ APH, const unsigned short* __restrict__ APL,
            const unsigned short* __restrict__ WPH, const unsigned short* __restrict__ WPL,
            int K,
            const float* __restrict__ gg, const float* __restrict__ bb,
            const float* __restrict__ mn, const float* __restrict__ vv,
            const float* __restrict__ bias,
            float* __restrict__ out, int ldo,
            unsigned short* __restrict__ oH, unsigned short* __restrict__ oL, int oldo,
            unsigned* __restrict__ glob)
{
  __shared__ float red[64][17];
  const int t = threadIdx.x;
  const int lane = t & 63, w = t >> 6;
  const int m0 = blockIdx.x * 64, n0 = blockIdx.y * 64;
  const int kg = K >> 3;
  const int la = (lane & 15) * 8;
  f32x4 acc[4] = {{0,0,0,0},{0,0,0,0},{0,0,0,0},{0,0,0,0}};
  const size_t abase = ((size_t)((m0 >> 4) + w) * kg + (lane >> 4)) * 128 + la;

  for (int k0 = 0; k0 < K; k0 += 32) {
    size_t ao = abase + (size_t)(k0 >> 3) * 128;
    bf16x8 aH = *(const bf16x8*)&APH[ao];
    bf16x8 aL = *(const bf16x8*)&APL[ao];
    #pragma unroll
    for (int tt = 0; tt < 4; ++tt) {
      size_t wo = ((size_t)((n0 >> 4) + tt) * kg + (k0 >> 3) + (lane >> 4)) * 128 + la;
      bf16x8 bH = *(const bf16x8*)&WPH[wo];
      bf16x8 bL = *(const bf16x8*)&WPL[wo];
      acc[tt] = __builtin_amdgcn_mfma_f32_16x16x32_bf16(aL, bH, acc[tt], 0, 0, 0);
      acc[tt] = __builtin_amdgcn_mfma_f32_16x16x32_bf16(aH, bL, acc[tt], 0, 0, 0);
      acc[tt] = __builtin_amdgcn_mfma_f32_16x16x32_bf16(aH, bH, acc[tt], 0, 0, 0);
    }
  }

  const int mrow = m0 + w * 16 + ((lane >> 4) << 2);   // C/D: row=(lane>>4)*4+reg
  const int batch = m0 >> 11;

  if (EPI == EP_MAXGLOB) {
    #pragma unroll
    for (int tt = 0; tt < 4; ++tt) {
      int nn = n0 + tt * 16 + (lane & 15);
      float s = gg[nn] / sqrtf(vv[nn] + BN_EPS);
      float f = bb[nn] - mn[nn] * s;
      float mx = -INFINITY;
      #pragma unroll
      for (int r = 0; r < 4; ++r) mx = fmaxf(mx, mishf(acc[tt][r] * s + f));
      red[tt * 16 + (lane & 15)][w * 4 + (lane >> 4)] = mx;
    }
    __syncthreads();
    if (t < 64) {
      float v = red[t][0];
      #pragma unroll
      for (int q = 1; q < 16; ++q) v = fmaxf(v, red[t][q]);
      atomicMax(&glob[batch * 1024 + n0 + t], fenc(v));
    }
  } else {
    #pragma unroll
    for (int tt = 0; tt < 4; ++tt) {
      int nn = n0 + tt * 16 + (lane & 15);
      float s = gg[nn] / sqrtf(vv[nn] + BN_EPS);
      float f = bb[nn] - mn[nn] * s;
      float bv = (EPI == EP_BIAS_BNMISH) ? bias[batch * 512 + nn] : 0.f;
      #pragma unroll
      for (int r = 0; r < 4; ++r) {
        int m = mrow + r;
        float h = mishf((acc[tt][r] + bv) * s + f);
        if (EPI == EP_BIAS_BNMISH) {
          unsigned short hh, ll;
          bfsplit(h, hh, ll);
          size_t pos = ((size_t)(m >> 4) * (oldo >> 3) + (nn >> 3)) * 128
                       + (m & 15) * 8 + (nn & 7);
          oH[pos] = hh; oL[pos] = ll;
        } else {
          out[(size_t)m * ldo + nn] = h;
        }
      }
    }
  }
}

// ---------- t7[b][o] = w7[o, :1024] . glob[b] ----------
__global__ __launch_bounds__(256)
void k_t7(const unsigned* __restrict__ glob, const float* __restrict__ w7,
          float* __restrict__ t7){
  int i = blockIdx.x * 256 + threadIdx.x;      // 4096
  int b = i >> 9, o = i & 511;
  float acc = 0.f;
  for (int c = 0; c < 1024; ++c)
    acc = fmaf(w7[(size_t)o * 1216 + c], fdec(glob[b * 1024 + c]), acc);
  t7[i] = acc;
}

// ---------- final conv ----------
__global__ __launch_bounds__(256)
void k_out(const float* __restrict__ h8, const float* __restrict__ w9,
           float* __restrict__ out)
{
  __shared__ float row[4][256];
  const int t = threadIdx.x;
  const int g = t >> 6, l = t & 63;
  const int p = blockIdx.x * 4 + g;            // 4096 blocks
  for (int c = l; c < 256; c += 64)
    row[g][c] = h8[(size_t)p * 256 + c];
  __syncthreads();
  if (l < 18) {
    float acc = 0.f;
    for (int c = 0; c < 256; ++c)
      acc = fmaf(row[g][c], w9[l * 256 + c], acc);
    int b = p >> 11, n = p & 2047;
    out[(size_t)b * 36864 + l * 2048 + n] = acc;
  }
}

extern "C" void kernel_launch(void* const* d_in, const int* in_sizes, int n_in,
                              void* d_out, int out_size, void* d_ws, size_t ws_size,
                              hipStream_t stream)
{
  const size_t OFF_XF   = 0;
  const size_t OFF_IDX  = 262144;
  const size_t OFF_CAT  = 917504;              // cat f32; W-splits alias after k_split
  const size_t OFF_GLOB = 13500416;
  const size_t OFF_T7   = 13533184;
  const size_t OFF_H7   = 13549568;            // UV (stages) -> h7P hi/lo (head)
  const size_t OFF_H8   = 47104000;            // sq/pk (stages) -> catP (head) -> h8
  const size_t NEED     = 63881216;

  static const int EXP[26] = {
    49152, 384, 4096, 8192, 4096, 8192, 196608, 622592, 131072, 4608,
    320, 320, 320, 320, 1024, 1024, 1024, 1024,
    512, 512, 512, 512, 256, 256, 256, 256 };
  if (n_in < 26) { k_diag<<<1,1,0,stream>>>((float*)d_out, 16384.f); return; }
  for (int i = 0; i < 26; ++i)
    if (in_sizes[i] != EXP[i]) {
      k_diag<<<1,1,0,stream>>>((float*)d_out, 4096.f + 128.f * i); return;
    }
  if (out_size != 294912) { k_diag<<<1,1,0,stream>>>((float*)d_out, 20480.f); return; }
  if (ws_size < NEED) {
    k_diag<<<1,1,0,stream>>>((float*)d_out, 24576.f + (float)(ws_size >> 20)); return;
  }

  const float* x  = (const float*)d_in[0];
  const float* w1 = (const float*)d_in[1];
  const float* w2 = (const float*)d_in[2];
  const float* w3 = (const float*)d_in[3];
  const float* w4 = (const float*)d_in[4];
  const float* w5 = (const float*)d_in[5];
  const float* w6 = (const float*)d_in[6];
  const float* w7 = (const float*)d_in[7];
  const float* w8 = (const float*)d_in[8];
  const float* w9 = (const float*)d_in[9];
  const float* g15 = (const float*)d_in[10];
  const float* b15 = (const float*)d_in[11];
  const float* m15 = (const float*)d_in[12];
  const float* v15 = (const float*)d_in[13];
  const float* g6 = (const float*)d_in[14];
  const float* b6 = (const float*)d_in[15];
  const float* m6 = (const float*)d_in[16];
  const float* v6 = (const float*)d_in[17];
  const float* g7 = (const float*)d_in[18];
  const float* b7 = (const float*)d_in[19];
  const float* m7 = (const float*)d_in[20];
  const float* v7 = (const float*)d_in[21];
  const float* g8 = (const float*)d_in[22];
  const float* b8 = (const float*)d_in[23];
  const float* m8 = (const float*)d_in[24];
  const float* v8 = (const float*)d_in[25];

  char* ws = (char*)d_ws;
  float*    xf   = (float*)(ws + OFF_XF);
  int*      idx  = (int*)(ws + OFF_IDX);
  float*    cat  = (float*)(ws + OFF_CAT);
  unsigned* glob = (unsigned*)(ws + OFF_GLOB);
  float*    t7   = (float*)(ws + OFF_T7);
  float*    UV   = (float*)(ws + OFF_H7);
  float*    h8   = (float*)(ws + OFF_H8);
  float*    sq   = (float*)(ws + OFF_H8);              //    65,536 [16384] (stages)
  u64*      pk   = (u64*)(ws + OFF_H8 + 65536);        // 5,242,880 (stages)

  // head-phase aliases (lifetimes disjoint from above):
  unsigned short* catH = (unsigned short*)(ws + OFF_H8);             // 6,291,456
  unsigned short* catL = (unsigned short*)(ws + OFF_H8 + 6291456);   // 6,291,456
  unsigned short* h7H  = (unsigned short*)(ws + OFF_H7);             // 16,777,216
  unsigned short* h7L  = (unsigned short*)(ws + OFF_H7 + 16777216);  // 16,777,216
  unsigned short* w6H  = (unsigned short*)(ws + OFF_CAT);            //   393,216
  unsigned short* w6L  = (unsigned short*)(ws + OFF_CAT + 393216);
  unsigned short* w7H  = (unsigned short*)(ws + OFF_CAT + 786432);   //   196,608
  unsigned short* w7L  = (unsigned short*)(ws + OFF_CAT + 983040);
  unsigned short* w8H  = (unsigned short*)(ws + OFF_CAT + 1179648);  //   262,144
  unsigned short* w8L  = (unsigned short*)(ws + OFF_CAT + 1441792);

  k_cast<<<192, 256, 0, stream>>>(x, xf);

  // ---- stage 1 ----
  k_knn3<<<512, 256, 0, stream>>>(xf, idx);
  k_uv3<<<4096, 256, 0, stream>>>(xf, w1, g15 + 0, v15 + 0, UV);
  k_edge2<<<2048, 256, 0, stream>>>(UV, idx, w2,
      g15 + 0,  b15 + 0,  m15 + 0,  v15 + 0,
      g15 + 64, b15 + 64, m15 + 64, v15 + 64, cat, 0);

  // ---- stage 2 ----
  k_norm<64><<<64, 256, 0, stream>>>(cat, 192, 0, sq);
  k_knn2p<<<1024, 256, 0, stream>>>(cat, 192, 0, sq, pk);
  k_kmerge<<<64, 256, 0, stream>>>(pk, idx);
  dim3 guv(256, 2);
  k_uv<<<guv, 256, 0, stream>>>(cat, 192, 0, w3, g15 + 128, v15 + 128, UV);
  k_edge2<<<2048, 256, 0, stream>>>(UV, idx, w4,
      g15 + 128, b15 + 128, m15 + 128, v15 + 128,
      g15 + 192, b15 + 192, m15 + 192, v15 + 192, cat, 64);

  // ---- stage 3 ----
  k_norm<64><<<64, 256, 0, stream>>>(cat, 192, 64, sq);
  k_knn2p<<<1024, 256, 0, stream>>>(cat, 192, 64, sq, pk);
  k_kmerge<<<64, 256, 0, stream>>>(pk, idx);
  k_uv<<<guv, 256, 0, stream>>>(cat, 192, 64, w5, g15 + 256, v15 + 256, UV);
  k_edge3<<<4096, 256, 0, stream>>>(UV, idx,
      g15 + 256, b15 + 256, m15 + 256, v15 + 256, cat);

  // ---- presplit to frag-packed bf16 (cat first: frees cat region for W splits) ----
  k_split<<<12288, 256, 0, stream>>>(cat, 192, 0, 192, catH, catL);
  k_split<<<768, 256, 0, stream>>>(w6, 192, 0, 192, w6H, w6L);
  k_split<<<384, 256, 0, stream>>>(w7, 1216, 1024, 192, w7H, w7L);
  k_split<<<512, 256, 0, stream>>>(w8, 512, 0, 512, w8H, w8L);

  // ---- head (MFMA bf16x3, no-LDS K-loop) ----
  k_zero<<<32, 256, 0, stream>>>(glob);
  dim3 g6g(256, 16);
  k_gemm<EP_MAXGLOB><<<g6g, 256, 0, stream>>>(
      catH, catL, w6H, w6L, 192, g6, b6, m6, v6,
      nullptr, nullptr, 0, nullptr, nullptr, 0, glob);
  k_t7<<<16, 256, 0, stream>>>(glob, w7, t7);
  dim3 g7g(256, 8);
  k_gemm<EP_BIAS_BNMISH><<<g7g, 256, 0, stream>>>(
      catH, catL, w7H, w7L, 192, g7, b7, m7, v7,
      t7, nullptr, 0, h7H, h7L, 512, nullptr);
  dim3 g8g(256, 4);
  k_gemm<EP_BNMISH><<<g8g, 256, 0, stream>>>(
      h7H, h7L, w8H, w8L, 512, g8, b8, m8, v8,
      nullptr, h8, 256, nullptr, nullptr, 0, nullptr);
  k_out<<<4096, 256, 0, stream>>>(h8, w9, (float*)d_out);
}